// Round 1
// 224.570 us; speedup vs baseline: 1.0455x; 1.0455x over previous
//
#include <hip/hip_runtime.h>
#include <hip/hip_bf16.h>

typedef unsigned short u16;
typedef unsigned int u32;
typedef __bf16 bf16x8 __attribute__((ext_vector_type(8)));
typedef float f32x4 __attribute__((ext_vector_type(4)));

__device__ __forceinline__ float bfu(u16 u) { return __uint_as_float(((u32)u) << 16); }
__device__ __forceinline__ u16 fbf(float f) {
  __hip_bfloat16 h = __float2bfloat16(f);
  return *reinterpret_cast<u16*>(&h);
}
__device__ __forceinline__ float softplusf(float z) {
  float t = __expf(z);
  return (z > 20.f) ? z : __logf(1.f + t);
}
__device__ __forceinline__ float lo16(u32 p) { return __uint_as_float(p << 16); }
__device__ __forceinline__ float hi16(u32 p) { return __uint_as_float(p & 0xffff0000u); }
__device__ __forceinline__ bf16x8 ld_bf8(const u16* p) {
  union { uint4 u; bf16x8 v; } c;
  c.u = *(const uint4*)p;
  return c.v;
}

// ---- K1: in_proj MFMA GEMM: out_cl[b,l,o] = sum_c W[o,c] * X[b,c,l] --------
__global__ __launch_bounds__(256) void k_inproj(const float* __restrict__ X,
                                                const float* __restrict__ W,
                                                u16* __restrict__ out) {
  __shared__ __align__(16) u16 Ws[128 * 136];  // [o][c] bf16
  __shared__ __align__(16) u16 Xs[64 * 136];   // [l][c] bf16 (X^T tile)
  int tid = threadIdx.x;
  int b = blockIdx.x >> 8;
  int l0 = (blockIdx.x & 255) << 6;
  for (int i = 0; i < 16; ++i) {
    int idx = (i << 8) + tid;
    int o = idx >> 5, c4 = (idx & 31) << 2;
    float4 w4 = *(const float4*)&W[(o << 7) + c4];
    ushort4 s;
    s.x = fbf(w4.x); s.y = fbf(w4.y); s.z = fbf(w4.z); s.w = fbf(w4.w);
    *(ushort4*)&Ws[o * 136 + c4] = s;
  }
  for (int i = 0; i < 8; ++i) {
    int idx = (i << 8) + tid;
    int c = idx >> 4, lq = (idx & 15) << 2;
    float4 x4 = *(const float4*)&X[(((long)(b << 7) + c) << 14) + l0 + lq];
    Xs[(lq + 0) * 136 + c] = fbf(x4.x);
    Xs[(lq + 1) * 136 + c] = fbf(x4.y);
    Xs[(lq + 2) * 136 + c] = fbf(x4.z);
    Xs[(lq + 3) * 136 + c] = fbf(x4.w);
  }
  __syncthreads();
  int w = tid >> 6, lane = tid & 63;
  int mrow = lane & 15, quad = lane >> 4;
  f32x4 acc[2][4];
#pragma unroll
  for (int ot = 0; ot < 2; ++ot)
#pragma unroll
    for (int lt = 0; lt < 4; ++lt) acc[ot][lt] = (f32x4){0.f, 0.f, 0.f, 0.f};
#pragma unroll
  for (int kb = 0; kb < 4; ++kb) {
    int c0 = (kb << 5) + (quad << 3);
    bf16x8 af[2], bfr[4];
#pragma unroll
    for (int ot = 0; ot < 2; ++ot)
      af[ot] = ld_bf8(&Ws[((w << 5) + (ot << 4) + mrow) * 136 + c0]);
#pragma unroll
    for (int lt = 0; lt < 4; ++lt)
      bfr[lt] = ld_bf8(&Xs[((lt << 4) + mrow) * 136 + c0]);
#pragma unroll
    for (int ot = 0; ot < 2; ++ot)
#pragma unroll
      for (int lt = 0; lt < 4; ++lt)
        acc[ot][lt] = __builtin_amdgcn_mfma_f32_16x16x32_bf16(af[ot], bfr[lt], acc[ot][lt], 0, 0, 0);
  }
#pragma unroll
  for (int ot = 0; ot < 2; ++ot)
#pragma unroll
    for (int lt = 0; lt < 4; ++lt) {
      int l = l0 + (lt << 4) + mrow;
      int o = (w << 5) + (ot << 4) + (quad << 2);
      ushort4 s;
      s.x = fbf(acc[ot][lt][0]); s.y = fbf(acc[ot][lt][1]);
      s.z = fbf(acc[ot][lt][2]); s.w = fbf(acc[ot][lt][3]);
      *(ushort4*)&out[(((long)(b << 14) + l) << 7) + o] = s;
    }
}

// ---- K2/K3a: depthwise 3x3 conv, channels-last, optional SiLU --------------
__global__ __launch_bounds__(256) void k_dwconv(const u16* __restrict__ in,
                                                const float* __restrict__ w9,
                                                const float* __restrict__ bias,
                                                u16* __restrict__ out, int act) {
  __shared__ float wsT[9][128];
  __shared__ float bs[128];
  int tid = threadIdx.x;
  for (int i = 0; i < 5; ++i) {
    int lin = (i << 8) + tid;
    if (lin < 1152) { int c = lin / 9, k = lin - 9 * c; wsT[k][c] = w9[lin]; }
  }
  if (tid < 128) bs[tid] = bias[tid];
  __syncthreads();
  int blk = blockIdx.x;
  int b = blk >> 10;
  int s = blk & 1023;
  int h = s >> 3;
  int w = ((s & 7) << 4) + (tid >> 4);
  int c0 = (tid & 15) << 3;
  const u16* bbase = in + ((long)b << 21);
  float acc[8];
  {
    float4 b0 = *(const float4*)&bs[c0];
    float4 b1 = *(const float4*)&bs[c0 + 4];
    acc[0] = b0.x; acc[1] = b0.y; acc[2] = b0.z; acc[3] = b0.w;
    acc[4] = b1.x; acc[5] = b1.y; acc[6] = b1.z; acc[7] = b1.w;
  }
#pragma unroll
  for (int ky = -1; ky <= 1; ++ky) {
    int y = h + ky;
    if ((unsigned)y >= 128u) continue;
#pragma unroll
    for (int kx = -1; kx <= 1; ++kx) {
      int x = w + kx;
      if ((unsigned)x >= 128u) continue;
      int k = (ky + 1) * 3 + (kx + 1);
      uint4 v = *(const uint4*)(bbase + ((((y << 7) + x)) << 7) + c0);
      float4 w0 = *(const float4*)&wsT[k][c0];
      float4 w1 = *(const float4*)&wsT[k][c0 + 4];
      u32 vv[4] = {v.x, v.y, v.z, v.w};
      float wf[8] = {w0.x, w0.y, w0.z, w0.w, w1.x, w1.y, w1.z, w1.w};
#pragma unroll
      for (int cc = 0; cc < 8; ++cc) {
        float xv = (cc & 1) ? hi16(vv[cc >> 1]) : lo16(vv[cc >> 1]);
        acc[cc] = fmaf(wf[cc], xv, acc[cc]);
      }
    }
  }
  if (act) {
#pragma unroll
    for (int cc = 0; cc < 8; ++cc) acc[cc] = acc[cc] / (1.f + __expf(-acc[cc]));
  }
  ushort4 s0, s1;
  s0.x = fbf(acc[0]); s0.y = fbf(acc[1]); s0.z = fbf(acc[2]); s0.w = fbf(acc[3]);
  s1.x = fbf(acc[4]); s1.y = fbf(acc[5]); s1.z = fbf(acc[6]); s1.w = fbf(acc[7]);
  u16* po = out + ((long)b << 21) + ((((h << 7) + w)) << 7) + c0;
  *(ushort4*)po = s0;
  *(ushort4*)(po + 4) = s1;
}

// ---- K3b: LN + GELU + MFMA offset projection; 64-pixel tile ----------------
// offs layout [b][g][l] float2
__global__ __launch_bounds__(256) void k_offset(const u16* __restrict__ x1,
                                                const float* __restrict__ g,
                                                const float* __restrict__ bt,
                                                const float* __restrict__ offw,
                                                const float* __restrict__ offb,
                                                float* __restrict__ offs) {
  __shared__ __align__(16) u16 Ge[64 * 136];   // [l][c] bf16: x1 then gelu
  __shared__ __align__(16) u16 Wos[16 * 136];  // [o][c] bf16
  __shared__ float ps[4][64], pss[4][64];
  __shared__ float mean_s[64], rstd_s[64];
  __shared__ float gs[128], bsh[128];
  int tid = threadIdx.x;
  int pg0 = blockIdx.x << 6;
  int b = pg0 >> 14;
  if (tid < 128) { gs[tid] = g[tid]; bsh[tid] = bt[tid]; }
  for (int i = 0; i < 8; ++i) {
    int idx = (i << 8) + tid;  // 2048 = 16o x 128c
    int o = idx >> 7, c = idx & 127;
    Wos[o * 136 + c] = fbf(offw[idx]);
  }
  int l = tid >> 2, cq = (tid & 3) << 5;
  {
    const u16* px = x1 + (((long)(pg0 + l)) << 7) + cq;
    float s = 0.f, ss = 0.f;
#pragma unroll
    for (int i2 = 0; i2 < 4; ++i2) {
      uint4 v = *(const uint4*)(px + (i2 << 3));
      *(uint4*)&Ge[l * 136 + cq + (i2 << 3)] = v;
      u32 vv[4] = {v.x, v.y, v.z, v.w};
#pragma unroll
      for (int cc = 0; cc < 8; ++cc) {
        float xv = (cc & 1) ? hi16(vv[cc >> 1]) : lo16(vv[cc >> 1]);
        s += xv; ss = fmaf(xv, xv, ss);
      }
    }
    ps[tid & 3][l] = s; pss[tid & 3][l] = ss;
  }
  __syncthreads();
  if (tid < 64) {
    float s = ps[0][tid] + ps[1][tid] + ps[2][tid] + ps[3][tid];
    float ss = pss[0][tid] + pss[1][tid] + pss[2][tid] + pss[3][tid];
    float m = s * (1.f / 128.f);
    mean_s[tid] = m;
    rstd_s[tid] = rsqrtf(ss * (1.f / 128.f) - m * m + 1e-6f);
  }
  __syncthreads();
  {
    float m = mean_s[l], r = rstd_s[l];
    u16* row = &Ge[l * 136 + cq];
#pragma unroll 8
    for (int cc = 0; cc < 32; ++cc) {
      int c = cq + cc;
      float v = bfu(row[cc]);
      float xn = fmaf((v - m) * r, gs[c], bsh[c]);
      row[cc] = fbf(0.5f * xn * (1.f + erff(xn * 0.70710678118f)));
    }
  }
  __syncthreads();
  int w = tid >> 6, lane = tid & 63;
  int mrow = lane & 15, quad = lane >> 4;
  f32x4 acc0 = (f32x4){0.f, 0.f, 0.f, 0.f};
#pragma unroll
  for (int kb = 0; kb < 4; ++kb) {
    int c0 = (kb << 5) + (quad << 3);
    bf16x8 af = ld_bf8(&Wos[mrow * 136 + c0]);
    bf16x8 bfr = ld_bf8(&Ge[((w << 4) + mrow) * 136 + c0]);
    acc0 = __builtin_amdgcn_mfma_f32_16x16x32_bf16(af, bfr, acc0, 0, 0, 0);
  }
  // D: col(lane&15)=l, row(quad*4+reg)=o.  o pairs (2g,2g+1): g0=2*quad, g1=2*quad+1
  int lg = (pg0 & 16383) + (w << 4) + mrow;
  float2* po = (float2*)offs;
  int o0 = quad << 2;
  po[(((long)((b << 3) + (quad << 1))) << 14) + lg] =
      make_float2(acc0[0] + offb[o0], acc0[1] + offb[o0 + 1]);
  po[(((long)((b << 3) + (quad << 1) + 1)) << 14) + lg] =
      make_float2(acc0[2] + offb[o0 + 2], acc0[3] + offb[o0 + 3]);
}

// ---- K4: DCN gather + x_proj + dt_w; 64-pixel tile, 512 thr ----------------
// Rework vs previous version: x_proj partial dot-products are computed from
// the gather accumulator REGISTERS with wave-uniform (s_load) weight reads,
// then reduced across the 8 channel-group waves via a small LDS buffer.
// The transpose tile is bf16 (bit-identical to xs output), and dts uses
// register-held weights + float4 reads of a transposed xdblT.  This removes
// the ~10-way bank-conflicted scalar-LDS inner loops that dominated k_dcn
// (SQ_LDS_BANK_CONFLICT 1.1e7 ~= 40% of kernel cycles).
__global__ __launch_bounds__(512, 6) void k_dcn(const u16* __restrict__ xc,
                                                const float* __restrict__ offs,
                                                const float* __restrict__ xpw,
                                                const float* __restrict__ dtw,
                                                u16* __restrict__ xs,
                                                u16* __restrict__ dts,
                                                float* __restrict__ Bsb,
                                                float* __restrict__ Csb) {
  __shared__ __align__(16) u16 xds_bf[64 * 132];  // [p][c] bf16, stride 132
  __shared__ float part[64 * 81];                 // [p][8r+gg], stride 81 (17p mod 32: conflict-free)
  __shared__ __align__(16) float xdblT[8 * 64];   // [r][p] (dt ranks only)
  __shared__ float dtwsT[8 * 128];                // [r][d]
  int tid = threadIdx.x;
  // stage dt_w transposed: dtw is [d][r] (128x8)
  for (int i = 0; i < 2; ++i) {
    int idx = (i << 9) + tid;
    int dd2 = idx >> 3, r = idx & 7;
    dtwsT[(r << 7) + dd2] = dtw[idx];
  }
  int blk = blockIdx.x;
  int b = blk >> 8;
  int l0 = (blk & 255) << 6;
  int p = tid & 63, gg = tid >> 6;
  int l = l0 + p, hh = l >> 7, ww = l & 127;
  float2 off = ((const float2*)offs)[(((long)((b << 3) + gg)) << 14) + l];
  float px = (float)ww + off.x, py = (float)hh + off.y;
  float x0f = floorf(px), y0f = floorf(py);
  float wx = px - x0f, wy = py - y0f;
  int ix = (int)x0f, iy = (int)y0f;
  float acc[16];
#pragma unroll
  for (int ch = 0; ch < 16; ++ch) acc[ch] = 0.f;
  const u16* bbase = xc + ((long)b << 21) + (gg << 4);
  int xi[4] = {ix, ix + 1, ix, ix + 1};
  int yi[4] = {iy, iy, iy + 1, iy + 1};
  float wt4[4] = {(1.f - wy) * (1.f - wx), (1.f - wy) * wx, wy * (1.f - wx), wy * wx};
#pragma unroll
  for (int t = 0; t < 4; ++t) {
    if (wt4[t] != 0.f && (unsigned)yi[t] < 128u && (unsigned)xi[t] < 128u) {
      const u16* pp = bbase + ((((yi[t] << 7) + xi[t])) << 7);
      uint4 v0 = *(const uint4*)pp;
      uint4 v1 = *(const uint4*)(pp + 8);
      float wv = wt4[t];
      u32 vv[8] = {v0.x, v0.y, v0.z, v0.w, v1.x, v1.y, v1.z, v1.w};
#pragma unroll
      for (int ch = 0; ch < 16; ++ch) {
        float xv = (ch & 1) ? hi16(vv[ch >> 1]) : lo16(vv[ch >> 1]);
        acc[ch] = fmaf(wv, xv, acc[ch]);
      }
    }
  }
  // write the bf16 transpose tile (bit-identical to the xs output values)
  {
    u32 pk[8];
#pragma unroll
    for (int j = 0; j < 8; ++j)
      pk[j] = (u32)fbf(acc[2 * j]) | ((u32)fbf(acc[2 * j + 1]) << 16);
    u16* row = &xds_bf[p * 132 + (gg << 4)];
#pragma unroll
    for (int q = 0; q < 4; ++q)
      *(uint2*)(row + (q << 2)) = make_uint2(pk[2 * q], pk[2 * q + 1]);
  }
  // x_proj partials from registers; weights via wave-uniform s_load path
  {
    int ggu = __builtin_amdgcn_readfirstlane(gg);
    const float* wb = xpw + (ggu << 4);
    int pbase = p * 81 + gg;
#pragma unroll
    for (int r = 0; r < 10; ++r) {
      const float* wr = wb + (r << 7);
      float s = 0.f;
#pragma unroll
      for (int ch = 0; ch < 16; ++ch) s = fmaf(wr[ch], acc[ch], s);
      part[pbase + (r << 3)] = s;
    }
  }
  __syncthreads();
  // reduce partials over the 8 channel groups: 640 tasks (r, p2),
  // wave-uniform r -> reads at stride 81 are conflict-free
  {
    int task = tid;
#pragma unroll
    for (int pass = 0; pass < 2; ++pass, task += 512) {
      if (task < 640) {
        int r = task >> 6, p2 = task & 63;
        const float* pp = &part[p2 * 81 + (r << 3)];
        float s = ((pp[0] + pp[1]) + (pp[2] + pp[3])) + ((pp[4] + pp[5]) + (pp[6] + pp[7]));
        if (r < 8) xdblT[(r << 6) + p2] = s;
        else if (r == 8) Bsb[((long)b << 14) + l0 + p2] = s;
        else Csb[((long)b << 14) + l0 + p2] = s;
      }
    }
  }
  // xs pack/store: 1024 tasks (128 c x 8 l-octets); 16B stores, full lines
#pragma unroll
  for (int it = 0; it < 2; ++it) {
    int task = (it << 9) + tid;
    int cc = task >> 3, t = task & 7;
    u32 pk[4];
#pragma unroll
    for (int jj = 0; jj < 4; ++jj) {
      u16 a0 = xds_bf[((t << 3) + 2 * jj + 0) * 132 + cc];
      u16 a1 = xds_bf[((t << 3) + 2 * jj + 1) * 132 + cc];
      pk[jj] = (u32)a0 | ((u32)a1 << 16);
    }
    *(uint4*)&xs[(((long)(b << 7) + cc) << 14) + l0 + (t << 3)] =
        make_uint4(pk[0], pk[1], pk[2], pk[3]);
  }
  __syncthreads();
  // dts: thread handles (dd, t) and (dd+64, t); weights broadcast from dtwsT,
  // xdblT read as float4 (aligned, 2-way max)
  {
    int dd = tid >> 3, t = tid & 7;
    float y0[8], y1[8];
#pragma unroll
    for (int j = 0; j < 8; ++j) { y0[j] = 0.f; y1[j] = 0.f; }
#pragma unroll
    for (int r = 0; r < 8; ++r) {
      float w0 = dtwsT[(r << 7) + dd];
      float w1 = dtwsT[(r << 7) + dd + 64];
      const float* xr = &xdblT[(r << 6) + (t << 3)];
      float4 xa = *(const float4*)xr;
      float4 xb = *(const float4*)(xr + 4);
      float xv[8] = {xa.x, xa.y, xa.z, xa.w, xb.x, xb.y, xb.z, xb.w};
#pragma unroll
      for (int j = 0; j < 8; ++j) {
        y0[j] = fmaf(w0, xv[j], y0[j]);
        y1[j] = fmaf(w1, xv[j], y1[j]);
      }
    }
    u32 pk0[4], pk1[4];
#pragma unroll
    for (int jj = 0; jj < 4; ++jj) {
      pk0[jj] = (u32)fbf(y0[2 * jj]) | ((u32)fbf(y0[2 * jj + 1]) << 16);
      pk1[jj] = (u32)fbf(y1[2 * jj]) | ((u32)fbf(y1[2 * jj + 1]) << 16);
    }
    *(uint4*)&dts[(((long)(b << 7) + dd) << 14) + l0 + (t << 3)] =
        make_uint4(pk0[0], pk0[1], pk0[2], pk0[3]);
    *(uint4*)&dts[(((long)(b << 7) + dd + 64) << 14) + l0 + (t << 3)] =
        make_uint4(pk1[0], pk1[1], pk1[2], pk1[3]);
  }
}

// ---- K5: selective scan, shfl-based block scan, cheap softplus -------------
__global__ __launch_bounds__(1024) void k_scan(u16* __restrict__ xy,
                                               const u16* __restrict__ dts16,
                                               const float* __restrict__ Bsb,
                                               const float* __restrict__ Csb,
                                               const float* __restrict__ A_logs,
                                               const float* __restrict__ Dsv,
                                               const float* __restrict__ dtbv) {
  __shared__ float swp[16], swe[16];
  int bd = blockIdx.x;
  int b = bd >> 7, d = bd & 127;
  float Ad = -__expf(A_logs[d]);
  float dtb = dtbv[d];
  float Dd = Dsv[d];
  int t = threadIdx.x;
  int lane = t & 63, wid = t >> 6;
  long base = ((long)bd << 14) + (t << 4);
  long bb = ((long)b << 14) + (t << 4);
  const uint4* pz4 = (const uint4*)(dts16 + base);
  const uint4* px4 = (const uint4*)(xy + base);
  const float4* pB = (const float4*)(Bsb + bb);
  const float4* pC = (const float4*)(Csb + bb);
  uint4 zA = pz4[0], zB = pz4[1];
  uint4 xA = px4[0], xB = px4[1];
  u32 zw[8] = {zA.x, zA.y, zA.z, zA.w, zB.x, zB.y, zB.z, zB.w};
  u32 xw[8] = {xA.x, xA.y, xA.z, xA.w, xB.x, xB.y, xB.z, xB.w};
  float E = 0.f, P = 1.f;
#pragma unroll
  for (int q = 0; q < 4; ++q) {
    float4 B4 = pB[q];
    float Bq[4] = {B4.x, B4.y, B4.z, B4.w};
#pragma unroll
    for (int j = 0; j < 4; ++j) {
      int k = (q << 2) + j;
      float z = (k & 1) ? hi16(zw[k >> 1]) : lo16(zw[k >> 1]);
      float xv = (k & 1) ? hi16(xw[k >> 1]) : lo16(xw[k >> 1]);
      float delta = softplusf(z + dtb);
      float a = __expf(delta * Ad);
      E = fmaf(a, E, delta * Bq[j] * xv);
      P *= a;
    }
  }
#pragma unroll
  for (int off = 1; off < 64; off <<= 1) {
    float Pp = __shfl_up(P, off);
    float Ep = __shfl_up(E, off);
    if (lane >= off) { E = fmaf(P, Ep, E); P *= Pp; }
  }
  if (lane == 63) { swp[wid] = P; swe[wid] = E; }
  __syncthreads();
  if (t < 16) {
    float p2 = swp[t], e2 = swe[t];
#pragma unroll
    for (int off = 1; off < 16; off <<= 1) {
      float pp = __shfl_up(p2, off);
      float ee = __shfl_up(e2, off);
      if (t >= off) { e2 = fmaf(p2, ee, e2); p2 *= pp; }
    }
    swp[t] = p2; swe[t] = e2;
  }
  __syncthreads();
  float hw = (wid == 0) ? 0.f : swe[wid - 1];
  float Pex = __shfl_up(P, 1);
  float Eex = __shfl_up(E, 1);
  if (lane == 0) { Pex = 1.f; Eex = 0.f; }
  float h = fmaf(Pex, hw, Eex);
  u32 ypk[8];
#pragma unroll
  for (int q = 0; q < 4; ++q) {
    float4 B4 = pB[q];
    float4 C4 = pC[q];
    float Bq[4] = {B4.x, B4.y, B4.z, B4.w};
    float Cq[4] = {C4.x, C4.y, C4.z, C4.w};
#pragma unroll
    for (int j = 0; j < 4; ++j) {
      int k = (q << 2) + j;
      float z = (k & 1) ? hi16(zw[k >> 1]) : lo16(zw[k >> 1]);
      float xv = (k & 1) ? hi16(xw[k >> 1]) : lo16(xw[k >> 1]);
      float delta = softplusf(z + dtb);
      float a = __expf(delta * Ad);
      h = fmaf(a, h, delta * Bq[j] * xv);
      u16 yb = fbf(fmaf(Dd, xv, h * Cq[j]));
      if ((k & 1) == 0) ypk[k >> 1] = yb; else ypk[k >> 1] |= (u32)yb << 16;
    }
  }
  uint4* py = (uint4*)(xy + base);
  py[0] = make_uint4(ypk[0], ypk[1], ypk[2], ypk[3]);
  py[1] = make_uint4(ypk[4], ypk[5], ypk[6], ypk[7]);
}

// ---- K6b: s1[o]=sum W2*beta, s2[o]=sum W2*gamma ----------------------------
__global__ void k_sums(const float* __restrict__ W2, const float* __restrict__ g,
                       const float* __restrict__ bln, float* __restrict__ s12) {
  int o = threadIdx.x;
  float s1 = 0.f, s2 = 0.f;
  for (int c = 0; c < 128; ++c) {
    float w = W2[(o << 7) + c];
    s1 = fmaf(w, bln[c], s1);
    s2 = fmaf(w, g[c], s2);
  }
  s12[o] = s1;
  s12[128 + o] = s2;
}

// ---- K7: out_proj MFMA GEMM + fused LN epilogue (f32 out, [b,o,l]) ---------
__global__ __launch_bounds__(256) void k_outproj(const u16* __restrict__ y,
                                                 const float* __restrict__ W2,
                                                 const float* __restrict__ g,
                                                 const float* __restrict__ s12,
                                                 float* __restrict__ out) {
  __shared__ __align__(16) u16 Ws[128 * 136];  // [o][c] bf16 of W2*gamma
  __shared__ __align__(16) u16 Ys[64 * 136];   // [l][c] bf16 (y^T tile)
  __shared__ float ps[4][64], pss[4][64];
  __shared__ float mean_s[64], rstd_s[64];
  int tid = threadIdx.x;
  int b = blockIdx.x >> 8;
  int l0 = (blockIdx.x & 255) << 6;
  for (int i = 0; i < 16; ++i) {
    int idx = (i << 8) + tid;
    int o = idx >> 5, c4 = (idx & 31) << 2;
    float4 w4 = *(const float4*)&W2[(o << 7) + c4];
    ushort4 s;
    s.x = fbf(w4.x * g[c4]);     s.y = fbf(w4.y * g[c4 + 1]);
    s.z = fbf(w4.z * g[c4 + 2]); s.w = fbf(w4.w * g[c4 + 3]);
    *(ushort4*)&Ws[o * 136 + c4] = s;
  }
  for (int i = 0; i < 4; ++i) {
    int idx = (i << 8) + tid;
    int c = idx >> 3, lq = (idx & 7) << 3;
    uint4 v = *(const uint4*)&y[(((long)(b << 7) + c) << 14) + l0 + lq];
    u32 vv[4] = {v.x, v.y, v.z, v.w};
#pragma unroll
    for (int r = 0; r < 8; ++r)
      Ys[(lq + r) * 136 + c] = (u16)((r & 1) ? (vv[r >> 1] >> 16) : (vv[r >> 1] & 0xffffu));
  }
  __syncthreads();
  {
    int l = tid & 63, q = tid >> 6;
    const u16* row = &Ys[l * 136 + (q << 5)];
    float s = 0.f, ss = 0.f;
#pragma unroll 8
    for (int c = 0; c < 32; ++c) { float v = bfu(row[c]); s += v; ss = fmaf(v, v, ss); }
    ps[q][l] = s; pss[q][l] = ss;
  }
  __syncthreads();
  if (tid < 64) {
    float s = ps[0][tid] + ps[1][tid] + ps[2][tid] + ps[3][tid];
    float ss = pss[0][tid] + pss[1][tid] + pss[2][tid] + pss[3][tid];
    float m = s * (1.f / 128.f);
    mean_s[tid] = m;
    rstd_s[tid] = rsqrtf(ss * (1.f / 128.f) - m * m + 1e-6f);
  }
  __syncthreads();
  int w = tid >> 6, lane = tid & 63;
  int mrow = lane & 15, quad = lane >> 4;
  f32x4 acc[2][4];
#pragma unroll
  for (int ot = 0; ot < 2; ++ot)
#pragma unroll
    for (int lt = 0; lt < 4; ++lt) acc[ot][lt] = (f32x4){0.f, 0.f, 0.f, 0.f};
#pragma unroll
  for (int kb = 0; kb < 4; ++kb) {
    int c0 = (kb << 5) + (quad << 3);
    bf16x8 af[2], bfr[4];
#pragma unroll
    for (int ot = 0; ot < 2; ++ot)
      af[ot] = ld_bf8(&Ws[((w << 5) + (ot << 4) + mrow) * 136 + c0]);
#pragma unroll
    for (int lt = 0; lt < 4; ++lt)
      bfr[lt] = ld_bf8(&Ys[((lt << 4) + mrow) * 136 + c0]);
#pragma unroll
    for (int ot = 0; ot < 2; ++ot)
#pragma unroll
      for (int lt = 0; lt < 4; ++lt)
        acc[ot][lt] = __builtin_amdgcn_mfma_f32_16x16x32_bf16(af[ot], bfr[lt], acc[ot][lt], 0, 0, 0);
  }
  float s1r[2][4], s2r[2][4];
#pragma unroll
  for (int ot = 0; ot < 2; ++ot)
#pragma unroll
    for (int r = 0; r < 4; ++r) {
      int o = (w << 5) + (ot << 4) + (quad << 2) + r;
      s1r[ot][r] = s12[o];
      s2r[ot][r] = s12[128 + o];
    }
#pragma unroll
  for (int ot = 0; ot < 2; ++ot)
#pragma unroll
    for (int lt = 0; lt < 4; ++lt) {
      int lcol = (lt << 4) + mrow;
      float mv = mean_s[lcol], rv = rstd_s[lcol];
      int obase = (w << 5) + (ot << 4) + (quad << 2);
#pragma unroll
      for (int r = 0; r < 4; ++r) {
        float v = fmaf(rv, acc[ot][lt][r] - mv * s2r[ot][r], s1r[ot][r]);
        out[(((long)(b << 7) + obase + r) << 14) + l0 + lcol] = v;
      }
    }
}

extern "C" void kernel_launch(void* const* d_in, const int* in_sizes, int n_in,
                              void* d_out, int out_size, void* d_ws, size_t ws_size,
                              hipStream_t stream) {
  const float* x         = (const float*)d_in[0];
  const float* in_proj_w = (const float*)d_in[1];
  const float* conv2d_w  = (const float*)d_in[2];
  const float* conv2d_b  = (const float*)d_in[3];
  const float* dw_w      = (const float*)d_in[4];
  const float* dw_b      = (const float*)d_in[5];
  const float* dw_ln_g   = (const float*)d_in[6];
  const float* dw_ln_b   = (const float*)d_in[7];
  const float* off_w     = (const float*)d_in[8];
  const float* off_b     = (const float*)d_in[9];
  const float* x_proj_w  = (const float*)d_in[10];
  const float* dt_w      = (const float*)d_in[11];
  const float* dt_b      = (const float*)d_in[12];
  const float* A_logs    = (const float*)d_in[13];
  const float* Ds        = (const float*)d_in[14];
  const float* out_ln_g  = (const float*)d_in[15];
  const float* out_ln_b  = (const float*)d_in[16];
  const float* out_proj_w= (const float*)d_in[17];
  float* out = (float*)d_out;

  u16* A  = (u16*)d_ws;            // xin_cl -> x1_cl -> xs[b,c,l] -> y[b,c,l]
  u16* Bx = A + 8388608;           // xc_cl
  u16* Dd = Bx + 8388608;          // dts[b,c,l]
  float* offs  = (float*)(Dd + 8388608);  // [b][g][l] float2
  float* Bsb   = offs + 1048576;
  float* Csb   = Bsb + 65536;
  float* s12   = Csb + 65536;

  hipLaunchKernelGGL(k_inproj, dim3(1024), dim3(256), 0, stream, x, in_proj_w, A);
  hipLaunchKernelGGL(k_dwconv, dim3(4096), dim3(256), 0, stream, A, conv2d_w, conv2d_b, Bx, 1);
  hipLaunchKernelGGL(k_dwconv, dim3(4096), dim3(256), 0, stream, Bx, dw_w, dw_b, A, 0);
  hipLaunchKernelGGL(k_offset, dim3(1024), dim3(256), 0, stream, A, dw_ln_g, dw_ln_b, off_w, off_b, offs);
  hipLaunchKernelGGL(k_dcn, dim3(1024), dim3(512), 0, stream, Bx, offs, x_proj_w, dt_w, A, Dd, Bsb, Csb);
  hipLaunchKernelGGL(k_scan, dim3(512), dim3(1024), 0, stream, A, Dd, Bsb, Csb, A_logs, Ds, dt_b);
  hipLaunchKernelGGL(k_sums, dim3(1), dim3(128), 0, stream, out_proj_w, out_ln_g, out_ln_b, s12);
  hipLaunchKernelGGL(k_outproj, dim3(1024), dim3(256), 0, stream, A, out_proj_w, out_ln_g, s12, out);
}

// Round 2
// 224.452 us; speedup vs baseline: 1.0461x; 1.0005x over previous
//
#include <hip/hip_runtime.h>
#include <hip/hip_bf16.h>

typedef unsigned short u16;
typedef unsigned int u32;
typedef __bf16 bf16x8 __attribute__((ext_vector_type(8)));
typedef float f32x4 __attribute__((ext_vector_type(4)));

__device__ __forceinline__ float bfu(u16 u) { return __uint_as_float(((u32)u) << 16); }
__device__ __forceinline__ u16 fbf(float f) {
  __hip_bfloat16 h = __float2bfloat16(f);
  return *reinterpret_cast<u16*>(&h);
}
__device__ __forceinline__ float softplusf(float z) {
  float t = __expf(z);
  return (z > 20.f) ? z : __logf(1.f + t);
}
__device__ __forceinline__ float lo16(u32 p) { return __uint_as_float(p << 16); }
__device__ __forceinline__ float hi16(u32 p) { return __uint_as_float(p & 0xffff0000u); }
__device__ __forceinline__ bf16x8 ld_bf8(const u16* p) {
  union { uint4 u; bf16x8 v; } c;
  c.u = *(const uint4*)p;
  return c.v;
}

// ---- K1: in_proj MFMA GEMM + (block 1024) k_sums fold ----------------------
__global__ __launch_bounds__(256) void k_inproj(const float* __restrict__ X,
                                                const float* __restrict__ W,
                                                u16* __restrict__ out,
                                                const float* __restrict__ W2,
                                                const float* __restrict__ gO,
                                                const float* __restrict__ bO,
                                                float* __restrict__ s12) {
  __shared__ __align__(16) u16 Ws[128 * 136];  // [o][c] bf16
  __shared__ __align__(16) u16 Xs[64 * 136];   // [l][c] bf16 (X^T tile)
  int tid = threadIdx.x;
  if (blockIdx.x == 1024) {  // folded k_sums: s1[o]=sum W2*beta, s2[o]=sum W2*gamma
    if (tid < 128) {
      int o = tid;
      float s1 = 0.f, s2 = 0.f;
      for (int c = 0; c < 128; ++c) {
        float w = W2[(o << 7) + c];
        s1 = fmaf(w, bO[c], s1);
        s2 = fmaf(w, gO[c], s2);
      }
      s12[o] = s1;
      s12[128 + o] = s2;
    }
    return;
  }
  int b = blockIdx.x >> 8;
  int l0 = (blockIdx.x & 255) << 6;
  for (int i = 0; i < 16; ++i) {
    int idx = (i << 8) + tid;
    int o = idx >> 5, c4 = (idx & 31) << 2;
    float4 w4 = *(const float4*)&W[(o << 7) + c4];
    ushort4 s;
    s.x = fbf(w4.x); s.y = fbf(w4.y); s.z = fbf(w4.z); s.w = fbf(w4.w);
    *(ushort4*)&Ws[o * 136 + c4] = s;
  }
  for (int i = 0; i < 8; ++i) {
    int idx = (i << 8) + tid;
    int c = idx >> 4, lq = (idx & 15) << 2;
    float4 x4 = *(const float4*)&X[(((long)(b << 7) + c) << 14) + l0 + lq];
    Xs[(lq + 0) * 136 + c] = fbf(x4.x);
    Xs[(lq + 1) * 136 + c] = fbf(x4.y);
    Xs[(lq + 2) * 136 + c] = fbf(x4.z);
    Xs[(lq + 3) * 136 + c] = fbf(x4.w);
  }
  __syncthreads();
  int w = tid >> 6, lane = tid & 63;
  int mrow = lane & 15, quad = lane >> 4;
  f32x4 acc[2][4];
#pragma unroll
  for (int ot = 0; ot < 2; ++ot)
#pragma unroll
    for (int lt = 0; lt < 4; ++lt) acc[ot][lt] = (f32x4){0.f, 0.f, 0.f, 0.f};
#pragma unroll
  for (int kb = 0; kb < 4; ++kb) {
    int c0 = (kb << 5) + (quad << 3);
    bf16x8 af[2], bfr[4];
#pragma unroll
    for (int ot = 0; ot < 2; ++ot)
      af[ot] = ld_bf8(&Ws[((w << 5) + (ot << 4) + mrow) * 136 + c0]);
#pragma unroll
    for (int lt = 0; lt < 4; ++lt)
      bfr[lt] = ld_bf8(&Xs[((lt << 4) + mrow) * 136 + c0]);
#pragma unroll
    for (int ot = 0; ot < 2; ++ot)
#pragma unroll
      for (int lt = 0; lt < 4; ++lt)
        acc[ot][lt] = __builtin_amdgcn_mfma_f32_16x16x32_bf16(af[ot], bfr[lt], acc[ot][lt], 0, 0, 0);
  }
#pragma unroll
  for (int ot = 0; ot < 2; ++ot)
#pragma unroll
    for (int lt = 0; lt < 4; ++lt) {
      int l = l0 + (lt << 4) + mrow;
      int o = (w << 5) + (ot << 4) + (quad << 2);
      ushort4 s;
      s.x = fbf(acc[ot][lt][0]); s.y = fbf(acc[ot][lt][1]);
      s.z = fbf(acc[ot][lt][2]); s.w = fbf(acc[ot][lt][3]);
      *(ushort4*)&out[(((long)(b << 14) + l) << 7) + o] = s;
    }
}

// ---- K2: depthwise 3x3 conv + SiLU (first conv), channels-last -------------
__global__ __launch_bounds__(256) void k_dwconv(const u16* __restrict__ in,
                                                const float* __restrict__ w9,
                                                const float* __restrict__ bias,
                                                u16* __restrict__ out) {
  __shared__ float wsT[9][128];
  __shared__ float bs[128];
  int tid = threadIdx.x;
  for (int i = 0; i < 5; ++i) {
    int lin = (i << 8) + tid;
    if (lin < 1152) { int c = lin / 9, k = lin - 9 * c; wsT[k][c] = w9[lin]; }
  }
  if (tid < 128) bs[tid] = bias[tid];
  __syncthreads();
  int blk = blockIdx.x;
  int b = blk >> 10;
  int s = blk & 1023;
  int h = s >> 3;
  int w = ((s & 7) << 4) + (tid >> 4);
  int c0 = (tid & 15) << 3;
  const u16* bbase = in + ((long)b << 21);
  float acc[8];
  {
    float4 b0 = *(const float4*)&bs[c0];
    float4 b1 = *(const float4*)&bs[c0 + 4];
    acc[0] = b0.x; acc[1] = b0.y; acc[2] = b0.z; acc[3] = b0.w;
    acc[4] = b1.x; acc[5] = b1.y; acc[6] = b1.z; acc[7] = b1.w;
  }
#pragma unroll
  for (int ky = -1; ky <= 1; ++ky) {
    int y = h + ky;
    if ((unsigned)y >= 128u) continue;
#pragma unroll
    for (int kx = -1; kx <= 1; ++kx) {
      int x = w + kx;
      if ((unsigned)x >= 128u) continue;
      int k = (ky + 1) * 3 + (kx + 1);
      uint4 v = *(const uint4*)(bbase + ((((y << 7) + x)) << 7) + c0);
      float4 w0 = *(const float4*)&wsT[k][c0];
      float4 w1 = *(const float4*)&wsT[k][c0 + 4];
      u32 vv[4] = {v.x, v.y, v.z, v.w};
      float wf[8] = {w0.x, w0.y, w0.z, w0.w, w1.x, w1.y, w1.z, w1.w};
#pragma unroll
      for (int cc = 0; cc < 8; ++cc) {
        float xv = (cc & 1) ? hi16(vv[cc >> 1]) : lo16(vv[cc >> 1]);
        acc[cc] = fmaf(wf[cc], xv, acc[cc]);
      }
    }
  }
#pragma unroll
  for (int cc = 0; cc < 8; ++cc) acc[cc] = acc[cc] / (1.f + __expf(-acc[cc]));
  ushort4 s0, s1;
  s0.x = fbf(acc[0]); s0.y = fbf(acc[1]); s0.z = fbf(acc[2]); s0.w = fbf(acc[3]);
  s1.x = fbf(acc[4]); s1.y = fbf(acc[5]); s1.z = fbf(acc[6]); s1.w = fbf(acc[7]);
  u16* po = out + ((long)b << 21) + ((((h << 7) + w)) << 7) + c0;
  *(ushort4*)po = s0;
  *(ushort4*)(po + 4) = s1;
}

// ---- K3: FUSED dwconv#2 + LN + GELU + offset MFMA projection ---------------
// Block = 16 pixels x 128 ch (same mapping as k_dwconv). x1 is never
// materialized: LN reduces across the 16 lanes sharing a pixel via shfl_xor,
// GELU'd values are packed bf16 into a 16x128 LDS tile, and wave 0 runs the
// 16x16x128 offset projection with the verified k_offset MFMA fragment code.
__global__ __launch_bounds__(256) void k_dwoff(const u16* __restrict__ in,
                                               const float* __restrict__ w9,
                                               const float* __restrict__ bias,
                                               const float* __restrict__ g,
                                               const float* __restrict__ bt,
                                               const float* __restrict__ offw,
                                               const float* __restrict__ offb,
                                               float* __restrict__ offs) {
  __shared__ float wsT[9][128];
  __shared__ float bs[128], gs[128], bsh[128];
  __shared__ __align__(16) u16 Ge[16 * 136];   // [pixel][c] bf16 gelu output
  __shared__ __align__(16) u16 Wos[16 * 136];  // [o][c] bf16
  int tid = threadIdx.x;
  for (int i = 0; i < 5; ++i) {
    int lin = (i << 8) + tid;
    if (lin < 1152) { int c = lin / 9, k = lin - 9 * c; wsT[k][c] = w9[lin]; }
  }
  if (tid < 128) { bs[tid] = bias[tid]; gs[tid] = g[tid]; bsh[tid] = bt[tid]; }
  for (int i = 0; i < 8; ++i) {
    int idx = (i << 8) + tid;  // 2048 = 16o x 128c
    int o = idx >> 7, c = idx & 127;
    Wos[o * 136 + c] = fbf(offw[idx]);
  }
  __syncthreads();
  int blk = blockIdx.x;
  int b = blk >> 10;
  int s = blk & 1023;
  int h = s >> 3;
  int p = tid >> 4;                 // pixel within block
  int w = ((s & 7) << 4) + p;
  int c0 = (tid & 15) << 3;
  const u16* bbase = in + ((long)b << 21);
  float acc[8];
  {
    float4 b0 = *(const float4*)&bs[c0];
    float4 b1 = *(const float4*)&bs[c0 + 4];
    acc[0] = b0.x; acc[1] = b0.y; acc[2] = b0.z; acc[3] = b0.w;
    acc[4] = b1.x; acc[5] = b1.y; acc[6] = b1.z; acc[7] = b1.w;
  }
#pragma unroll
  for (int ky = -1; ky <= 1; ++ky) {
    int y = h + ky;
    if ((unsigned)y >= 128u) continue;
#pragma unroll
    for (int kx = -1; kx <= 1; ++kx) {
      int x = w + kx;
      if ((unsigned)x >= 128u) continue;
      int k = (ky + 1) * 3 + (kx + 1);
      uint4 v = *(const uint4*)(bbase + ((((y << 7) + x)) << 7) + c0);
      float4 w0 = *(const float4*)&wsT[k][c0];
      float4 w1 = *(const float4*)&wsT[k][c0 + 4];
      u32 vv[4] = {v.x, v.y, v.z, v.w};
      float wf[8] = {w0.x, w0.y, w0.z, w0.w, w1.x, w1.y, w1.z, w1.w};
#pragma unroll
      for (int cc = 0; cc < 8; ++cc) {
        float xv = (cc & 1) ? hi16(vv[cc >> 1]) : lo16(vv[cc >> 1]);
        acc[cc] = fmaf(wf[cc], xv, acc[cc]);
      }
    }
  }
  // LN stats over 128 c: per-thread partial (8 ch) + reduce across the 16
  // contiguous lanes sharing this pixel
  float sum = 0.f, ssum = 0.f;
#pragma unroll
  for (int cc = 0; cc < 8; ++cc) { sum += acc[cc]; ssum = fmaf(acc[cc], acc[cc], ssum); }
#pragma unroll
  for (int off = 1; off < 16; off <<= 1) {
    sum += __shfl_xor(sum, off);
    ssum += __shfl_xor(ssum, off);
  }
  float m = sum * (1.f / 128.f);
  float r = rsqrtf(ssum * (1.f / 128.f) - m * m + 1e-6f);
  // LN + GELU -> bf16 pack into Ge[p][c0..c0+7]
  {
    u32 pk[4];
#pragma unroll
    for (int jj = 0; jj < 4; ++jj) {
      u16 h2[2];
#pragma unroll
      for (int e = 0; e < 2; ++e) {
        int cc = 2 * jj + e;
        float xn = fmaf((acc[cc] - m) * r, gs[c0 + cc], bsh[c0 + cc]);
        h2[e] = fbf(0.5f * xn * (1.f + erff(xn * 0.70710678118f)));
      }
      pk[jj] = (u32)h2[0] | ((u32)h2[1] << 16);
    }
    *(uint4*)&Ge[p * 136 + c0] = make_uint4(pk[0], pk[1], pk[2], pk[3]);
  }
  __syncthreads();
  // wave 0: 16x16x128 offset projection (4 MFMA) + store
  if (tid < 64) {
    int lane = tid;
    int mrow = lane & 15, quad = lane >> 4;
    f32x4 acc0 = (f32x4){0.f, 0.f, 0.f, 0.f};
#pragma unroll
    for (int kb = 0; kb < 4; ++kb) {
      int cb = (kb << 5) + (quad << 3);
      bf16x8 af = ld_bf8(&Wos[mrow * 136 + cb]);
      bf16x8 bfr = ld_bf8(&Ge[mrow * 136 + cb]);
      acc0 = __builtin_amdgcn_mfma_f32_16x16x32_bf16(af, bfr, acc0, 0, 0, 0);
    }
    // D: col(lane&15)=pixel, row(quad*4+reg)=o; o pairs (2g,2g+1)
    int l = (h << 7) + ((s & 7) << 4) + mrow;
    float2* po = (float2*)offs;
    int o0 = quad << 2;
    po[(((long)((b << 3) + (quad << 1))) << 14) + l] =
        make_float2(acc0[0] + offb[o0], acc0[1] + offb[o0 + 1]);
    po[(((long)((b << 3) + (quad << 1) + 1)) << 14) + l] =
        make_float2(acc0[2] + offb[o0 + 2], acc0[3] + offb[o0 + 3]);
  }
}

// ---- K4: DCN gather + x_proj + dt_w; 64-pixel tile, 512 thr ----------------
// Layout: one pixel's 8 groups live in one wave (gg = tid&7), so the x_proj
// cross-group reduction is 3 shfl_xor steps (same pairwise tree as before)
// and the 20.7KB 'part' LDS buffer is gone.  dtw is read directly from
// global (L1/L2-resident).  LDS ~25KB -> 4 blocks/CU (32 waves, was 24).
__global__ __launch_bounds__(512, 8) void k_dcn(const u16* __restrict__ xc,
                                                const float* __restrict__ offs,
                                                const float* __restrict__ xpw,
                                                const float* __restrict__ dtw,
                                                u16* __restrict__ xs,
                                                u16* __restrict__ dts,
                                                float* __restrict__ Bsb,
                                                float* __restrict__ Csb) {
  __shared__ __align__(16) u16 xds_bf[64 * 132];   // [p][c] bf16, stride 132
  __shared__ __align__(16) float xdblT[8 * 64];    // [r][p] (dt ranks only)
  __shared__ __align__(16) float xpwS[10 * 8 * 20];// [r][gg][ch], row stride 20 (b128 conflict-free)
  int tid = threadIdx.x;
  for (int i = 0; i < 3; ++i) {
    int idx = (i << 9) + tid;
    if (idx < 1280) {
      int rr = idx >> 7, rem = idx & 127;
      xpwS[((rr << 3) + (rem >> 4)) * 20 + (rem & 15)] = xpw[idx];
    }
  }
  int blk = blockIdx.x;
  int b = blk >> 8;
  int l0 = (blk & 255) << 6;
  int gg = tid & 7, p = tid >> 3;
  int l = l0 + p, hh = l >> 7, ww = l & 127;
  float2 off = ((const float2*)offs)[(((long)((b << 3) + gg)) << 14) + l];
  float px = (float)ww + off.x, py = (float)hh + off.y;
  float x0f = floorf(px), y0f = floorf(py);
  float wx = px - x0f, wy = py - y0f;
  int ix = (int)x0f, iy = (int)y0f;
  float acc[16];
#pragma unroll
  for (int ch = 0; ch < 16; ++ch) acc[ch] = 0.f;
  const u16* bbase = xc + ((long)b << 21) + (gg << 4);
  int xi[4] = {ix, ix + 1, ix, ix + 1};
  int yi[4] = {iy, iy, iy + 1, iy + 1};
  float wt4[4] = {(1.f - wy) * (1.f - wx), (1.f - wy) * wx, wy * (1.f - wx), wy * wx};
#pragma unroll
  for (int t = 0; t < 4; ++t) {
    if (wt4[t] != 0.f && (unsigned)yi[t] < 128u && (unsigned)xi[t] < 128u) {
      const u16* pp = bbase + ((((yi[t] << 7) + xi[t])) << 7);
      uint4 v0 = *(const uint4*)pp;
      uint4 v1 = *(const uint4*)(pp + 8);
      float wv = wt4[t];
      u32 vv[8] = {v0.x, v0.y, v0.z, v0.w, v1.x, v1.y, v1.z, v1.w};
#pragma unroll
      for (int ch = 0; ch < 16; ++ch) {
        float xv = (ch & 1) ? hi16(vv[ch >> 1]) : lo16(vv[ch >> 1]);
        acc[ch] = fmaf(wv, xv, acc[ch]);
      }
    }
  }
  // bf16 transpose tile (bit-identical to xs output values)
  {
    u32 pk[8];
#pragma unroll
    for (int j = 0; j < 8; ++j)
      pk[j] = (u32)fbf(acc[2 * j]) | ((u32)fbf(acc[2 * j + 1]) << 16);
    u16* row = &xds_bf[p * 132 + (gg << 4)];
#pragma unroll
    for (int q = 0; q < 4; ++q)
      *(uint2*)(row + (q << 2)) = make_uint2(pk[2 * q], pk[2 * q + 1]);
  }
  __syncthreads();  // xpwS visible
  // x_proj partials from registers + in-wave reduce over the 8 groups
  {
    float pr[10];
#pragma unroll
    for (int rr = 0; rr < 10; ++rr) {
      const float* wr = &xpwS[((rr << 3) + gg) * 20];
      float4 w0 = *(const float4*)wr;
      float4 w1 = *(const float4*)(wr + 4);
      float4 w2 = *(const float4*)(wr + 8);
      float4 w3 = *(const float4*)(wr + 12);
      float sv = 0.f;
      sv = fmaf(w0.x, acc[0], sv);  sv = fmaf(w0.y, acc[1], sv);
      sv = fmaf(w0.z, acc[2], sv);  sv = fmaf(w0.w, acc[3], sv);
      sv = fmaf(w1.x, acc[4], sv);  sv = fmaf(w1.y, acc[5], sv);
      sv = fmaf(w1.z, acc[6], sv);  sv = fmaf(w1.w, acc[7], sv);
      sv = fmaf(w2.x, acc[8], sv);  sv = fmaf(w2.y, acc[9], sv);
      sv = fmaf(w2.z, acc[10], sv); sv = fmaf(w2.w, acc[11], sv);
      sv = fmaf(w3.x, acc[12], sv); sv = fmaf(w3.y, acc[13], sv);
      sv = fmaf(w3.z, acc[14], sv); sv = fmaf(w3.w, acc[15], sv);
      pr[rr] = sv;
    }
#pragma unroll
    for (int rr = 0; rr < 10; ++rr) {
      float v = pr[rr];
      v += __shfl_xor(v, 1);
      v += __shfl_xor(v, 2);
      v += __shfl_xor(v, 4);
      pr[rr] = v;
    }
    if (gg == 0) {
#pragma unroll
      for (int rr = 0; rr < 8; ++rr) xdblT[(rr << 6) + p] = pr[rr];
      Bsb[((long)b << 14) + l0 + p] = pr[8];
      Csb[((long)b << 14) + l0 + p] = pr[9];
    }
  }
  __syncthreads();  // xdblT visible
  // xs pack/store: 1024 tasks (128 c x 8 l-octets); 16B stores, full lines
#pragma unroll
  for (int it = 0; it < 2; ++it) {
    int task = (it << 9) + tid;
    int cc = task >> 3, t = task & 7;
    u32 pk[4];
#pragma unroll
    for (int jj = 0; jj < 4; ++jj) {
      u16 a0 = xds_bf[((t << 3) + 2 * jj + 0) * 132 + cc];
      u16 a1 = xds_bf[((t << 3) + 2 * jj + 1) * 132 + cc];
      pk[jj] = (u32)a0 | ((u32)a1 << 16);
    }
    *(uint4*)&xs[(((long)(b << 7) + cc) << 14) + l0 + (t << 3)] =
        make_uint4(pk[0], pk[1], pk[2], pk[3]);
  }
  // dts: thread handles (dd, t) and (dd+64, t); dtw rows from global (cached)
  {
    int dd = tid >> 3, t = tid & 7;
    float4 a0 = *(const float4*)&dtw[dd << 3];
    float4 a1 = *(const float4*)&dtw[(dd << 3) + 4];
    float4 b0 = *(const float4*)&dtw[(dd + 64) << 3];
    float4 b1 = *(const float4*)&dtw[((dd + 64) << 3) + 4];
    float wr0[8] = {a0.x, a0.y, a0.z, a0.w, a1.x, a1.y, a1.z, a1.w};
    float wr1[8] = {b0.x, b0.y, b0.z, b0.w, b1.x, b1.y, b1.z, b1.w};
    float y0[8], y1[8];
#pragma unroll
    for (int j = 0; j < 8; ++j) { y0[j] = 0.f; y1[j] = 0.f; }
#pragma unroll
    for (int rr = 0; rr < 8; ++rr) {
      float w0 = wr0[rr], w1 = wr1[rr];
      const float* xr = &xdblT[(rr << 6) + (t << 3)];
      float4 xa = *(const float4*)xr;
      float4 xb = *(const float4*)(xr + 4);
      float xv[8] = {xa.x, xa.y, xa.z, xa.w, xb.x, xb.y, xb.z, xb.w};
#pragma unroll
      for (int j = 0; j < 8; ++j) {
        y0[j] = fmaf(w0, xv[j], y0[j]);
        y1[j] = fmaf(w1, xv[j], y1[j]);
      }
    }
    u32 pk0[4], pk1[4];
#pragma unroll
    for (int jj = 0; jj < 4; ++jj) {
      pk0[jj] = (u32)fbf(y0[2 * jj]) | ((u32)fbf(y0[2 * jj + 1]) << 16);
      pk1[jj] = (u32)fbf(y1[2 * jj]) | ((u32)fbf(y1[2 * jj + 1]) << 16);
    }
    *(uint4*)&dts[(((long)(b << 7) + dd) << 14) + l0 + (t << 3)] =
        make_uint4(pk0[0], pk0[1], pk0[2], pk0[3]);
    *(uint4*)&dts[(((long)(b << 7) + dd + 64) << 14) + l0 + (t << 3)] =
        make_uint4(pk1[0], pk1[1], pk1[2], pk1[3]);
  }
}

// ---- K5: selective scan, shfl-based block scan, cheap softplus -------------
__global__ __launch_bounds__(1024) void k_scan(u16* __restrict__ xy,
                                               const u16* __restrict__ dts16,
                                               const float* __restrict__ Bsb,
                                               const float* __restrict__ Csb,
                                               const float* __restrict__ A_logs,
                                               const float* __restrict__ Dsv,
                                               const float* __restrict__ dtbv) {
  __shared__ float swp[16], swe[16];
  int bd = blockIdx.x;
  int b = bd >> 7, d = bd & 127;
  float Ad = -__expf(A_logs[d]);
  float dtb = dtbv[d];
  float Dd = Dsv[d];
  int t = threadIdx.x;
  int lane = t & 63, wid = t >> 6;
  long base = ((long)bd << 14) + (t << 4);
  long bb = ((long)b << 14) + (t << 4);
  const uint4* pz4 = (const uint4*)(dts16 + base);
  const uint4* px4 = (const uint4*)(xy + base);
  const float4* pB = (const float4*)(Bsb + bb);
  const float4* pC = (const float4*)(Csb + bb);
  uint4 zA = pz4[0], zB = pz4[1];
  uint4 xA = px4[0], xB = px4[1];
  u32 zw[8] = {zA.x, zA.y, zA.z, zA.w, zB.x, zB.y, zB.z, zB.w};
  u32 xw[8] = {xA.x, xA.y, xA.z, xA.w, xB.x, xB.y, xB.z, xB.w};
  float E = 0.f, P = 1.f;
#pragma unroll
  for (int q = 0; q < 4; ++q) {
    float4 B4 = pB[q];
    float Bq[4] = {B4.x, B4.y, B4.z, B4.w};
#pragma unroll
    for (int j = 0; j < 4; ++j) {
      int k = (q << 2) + j;
      float z = (k & 1) ? hi16(zw[k >> 1]) : lo16(zw[k >> 1]);
      float xv = (k & 1) ? hi16(xw[k >> 1]) : lo16(xw[k >> 1]);
      float delta = softplusf(z + dtb);
      float a = __expf(delta * Ad);
      E = fmaf(a, E, delta * Bq[j] * xv);
      P *= a;
    }
  }
#pragma unroll
  for (int off = 1; off < 64; off <<= 1) {
    float Pp = __shfl_up(P, off);
    float Ep = __shfl_up(E, off);
    if (lane >= off) { E = fmaf(P, Ep, E); P *= Pp; }
  }
  if (lane == 63) { swp[wid] = P; swe[wid] = E; }
  __syncthreads();
  if (t < 16) {
    float p2 = swp[t], e2 = swe[t];
#pragma unroll
    for (int off = 1; off < 16; off <<= 1) {
      float pp = __shfl_up(p2, off);
      float ee = __shfl_up(e2, off);
      if (t >= off) { e2 = fmaf(p2, ee, e2); p2 *= pp; }
    }
    swp[t] = p2; swe[t] = e2;
  }
  __syncthreads();
  float hw = (wid == 0) ? 0.f : swe[wid - 1];
  float Pex = __shfl_up(P, 1);
  float Eex = __shfl_up(E, 1);
  if (lane == 0) { Pex = 1.f; Eex = 0.f; }
  float h = fmaf(Pex, hw, Eex);
  u32 ypk[8];
#pragma unroll
  for (int q = 0; q < 4; ++q) {
    float4 B4 = pB[q];
    float4 C4 = pC[q];
    float Bq[4] = {B4.x, B4.y, B4.z, B4.w};
    float Cq[4] = {C4.x, C4.y, C4.z, C4.w};
#pragma unroll
    for (int j = 0; j < 4; ++j) {
      int k = (q << 2) + j;
      float z = (k & 1) ? hi16(zw[k >> 1]) : lo16(zw[k >> 1]);
      float xv = (k & 1) ? hi16(xw[k >> 1]) : lo16(xw[k >> 1]);
      float delta = softplusf(z + dtb);
      float a = __expf(delta * Ad);
      h = fmaf(a, h, delta * Bq[j] * xv);
      u16 yb = fbf(fmaf(Dd, xv, h * Cq[j]));
      if ((k & 1) == 0) ypk[k >> 1] = yb; else ypk[k >> 1] |= (u32)yb << 16;
    }
  }
  uint4* py = (uint4*)(xy + base);
  py[0] = make_uint4(ypk[0], ypk[1], ypk[2], ypk[3]);
  py[1] = make_uint4(ypk[4], ypk[5], ypk[6], ypk[7]);
}

// ---- K7: out_proj MFMA GEMM + fused LN epilogue (f32 out, [b,o,l]) ---------
__global__ __launch_bounds__(256) void k_outproj(const u16* __restrict__ y,
                                                 const float* __restrict__ W2,
                                                 const float* __restrict__ g,
                                                 const float* __restrict__ s12,
                                                 float* __restrict__ out) {
  __shared__ __align__(16) u16 Ws[128 * 136];  // [o][c] bf16 of W2*gamma
  __shared__ __align__(16) u16 Ys[64 * 136];   // [l][c] bf16 (y^T tile)
  __shared__ float ps[4][64], pss[4][64];
  __shared__ float mean_s[64], rstd_s[64];
  int tid = threadIdx.x;
  int b = blockIdx.x >> 8;
  int l0 = (blockIdx.x & 255) << 6;
  for (int i = 0; i < 16; ++i) {
    int idx = (i << 8) + tid;
    int o = idx >> 5, c4 = (idx & 31) << 2;
    float4 w4 = *(const float4*)&W2[(o << 7) + c4];
    ushort4 s;
    s.x = fbf(w4.x * g[c4]);     s.y = fbf(w4.y * g[c4 + 1]);
    s.z = fbf(w4.z * g[c4 + 2]); s.w = fbf(w4.w * g[c4 + 3]);
    *(ushort4*)&Ws[o * 136 + c4] = s;
  }
  for (int i = 0; i < 4; ++i) {
    int idx = (i << 8) + tid;
    int c = idx >> 3, lq = (idx & 7) << 3;
    uint4 v = *(const uint4*)&y[(((long)(b << 7) + c) << 14) + l0 + lq];
    u32 vv[4] = {v.x, v.y, v.z, v.w};
#pragma unroll
    for (int r = 0; r < 8; ++r)
      Ys[(lq + r) * 136 + c] = (u16)((r & 1) ? (vv[r >> 1] >> 16) : (vv[r >> 1] & 0xffffu));
  }
  __syncthreads();
  {
    int l = tid & 63, q = tid >> 6;
    const u16* row = &Ys[l * 136 + (q << 5)];
    float s = 0.f, ss = 0.f;
#pragma unroll 8
    for (int c = 0; c < 32; ++c) { float v = bfu(row[c]); s += v; ss = fmaf(v, v, ss); }
    ps[q][l] = s; pss[q][l] = ss;
  }
  __syncthreads();
  if (tid < 64) {
    float s = ps[0][tid] + ps[1][tid] + ps[2][tid] + ps[3][tid];
    float ss = pss[0][tid] + pss[1][tid] + pss[2][tid] + pss[3][tid];
    float m = s * (1.f / 128.f);
    mean_s[tid] = m;
    rstd_s[tid] = rsqrtf(ss * (1.f / 128.f) - m * m + 1e-6f);
  }
  __syncthreads();
  int w = tid >> 6, lane = tid & 63;
  int mrow = lane & 15, quad = lane >> 4;
  f32x4 acc[2][4];
#pragma unroll
  for (int ot = 0; ot < 2; ++ot)
#pragma unroll
    for (int lt = 0; lt < 4; ++lt) acc[ot][lt] = (f32x4){0.f, 0.f, 0.f, 0.f};
#pragma unroll
  for (int kb = 0; kb < 4; ++kb) {
    int c0 = (kb << 5) + (quad << 3);
    bf16x8 af[2], bfr[4];
#pragma unroll
    for (int ot = 0; ot < 2; ++ot)
      af[ot] = ld_bf8(&Ws[((w << 5) + (ot << 4) + mrow) * 136 + c0]);
#pragma unroll
    for (int lt = 0; lt < 4; ++lt)
      bfr[lt] = ld_bf8(&Ys[((lt << 4) + mrow) * 136 + c0]);
#pragma unroll
    for (int ot = 0; ot < 2; ++ot)
#pragma unroll
      for (int lt = 0; lt < 4; ++lt)
        acc[ot][lt] = __builtin_amdgcn_mfma_f32_16x16x32_bf16(af[ot], bfr[lt], acc[ot][lt], 0, 0, 0);
  }
  float s1r[2][4], s2r[2][4];
#pragma unroll
  for (int ot = 0; ot < 2; ++ot)
#pragma unroll
    for (int r = 0; r < 4; ++r) {
      int o = (w << 5) + (ot << 4) + (quad << 2) + r;
      s1r[ot][r] = s12[o];
      s2r[ot][r] = s12[128 + o];
    }
#pragma unroll
  for (int ot = 0; ot < 2; ++ot)
#pragma unroll
    for (int lt = 0; lt < 4; ++lt) {
      int lcol = (lt << 4) + mrow;
      float mv = mean_s[lcol], rv = rstd_s[lcol];
      int obase = (w << 5) + (ot << 4) + (quad << 2);
#pragma unroll
      for (int r = 0; r < 4; ++r) {
        float v = fmaf(rv, acc[ot][lt][r] - mv * s2r[ot][r], s1r[ot][r]);
        out[(((long)(b << 7) + obase + r) << 14) + l0 + lcol] = v;
      }
    }
}

extern "C" void kernel_launch(void* const* d_in, const int* in_sizes, int n_in,
                              void* d_out, int out_size, void* d_ws, size_t ws_size,
                              hipStream_t stream) {
  const float* x         = (const float*)d_in[0];
  const float* in_proj_w = (const float*)d_in[1];
  const float* conv2d_w  = (const float*)d_in[2];
  const float* conv2d_b  = (const float*)d_in[3];
  const float* dw_w      = (const float*)d_in[4];
  const float* dw_b      = (const float*)d_in[5];
  const float* dw_ln_g   = (const float*)d_in[6];
  const float* dw_ln_b   = (const float*)d_in[7];
  const float* off_w     = (const float*)d_in[8];
  const float* off_b     = (const float*)d_in[9];
  const float* x_proj_w  = (const float*)d_in[10];
  const float* dt_w      = (const float*)d_in[11];
  const float* dt_b      = (const float*)d_in[12];
  const float* A_logs    = (const float*)d_in[13];
  const float* Ds        = (const float*)d_in[14];
  const float* out_ln_g  = (const float*)d_in[15];
  const float* out_ln_b  = (const float*)d_in[16];
  const float* out_proj_w= (const float*)d_in[17];
  float* out = (float*)d_out;

  u16* A  = (u16*)d_ws;            // xin_cl -> xs[b,c,l] -> y[b,c,l]
  u16* Bx = A + 8388608;           // xc_cl
  u16* Dd = Bx + 8388608;          // dts[b,c,l]
  float* offs  = (float*)(Dd + 8388608);  // [b][g][l] float2
  float* Bsb   = offs + 1048576;
  float* Csb   = Bsb + 65536;
  float* s12   = Csb + 65536;

  hipLaunchKernelGGL(k_inproj, dim3(1025), dim3(256), 0, stream, x, in_proj_w, A,
                     out_proj_w, out_ln_g, out_ln_b, s12);
  hipLaunchKernelGGL(k_dwconv, dim3(4096), dim3(256), 0, stream, A, conv2d_w, conv2d_b, Bx);
  hipLaunchKernelGGL(k_dwoff, dim3(4096), dim3(256), 0, stream, Bx, dw_w, dw_b,
                     dw_ln_g, dw_ln_b, off_w, off_b, offs);
  hipLaunchKernelGGL(k_dcn, dim3(1024), dim3(512), 0, stream, Bx, offs, x_proj_w, dt_w, A, Dd, Bsb, Csb);
  hipLaunchKernelGGL(k_scan, dim3(512), dim3(1024), 0, stream, A, Dd, Bsb, Csb, A_logs, Ds, dt_b);
  hipLaunchKernelGGL(k_outproj, dim3(1024), dim3(256), 0, stream, A, out_proj_w, out_ln_g, s12, out);
}

// Round 3
// 221.471 us; speedup vs baseline: 1.0601x; 1.0135x over previous
//
#include <hip/hip_runtime.h>
#include <hip/hip_bf16.h>

typedef unsigned short u16;
typedef unsigned int u32;
typedef __bf16 bf16x8 __attribute__((ext_vector_type(8)));
typedef float f32x4 __attribute__((ext_vector_type(4)));

__device__ __forceinline__ float bfu(u16 u) { return __uint_as_float(((u32)u) << 16); }
__device__ __forceinline__ u16 fbf(float f) {
  __hip_bfloat16 h = __float2bfloat16(f);
  return *reinterpret_cast<u16*>(&h);
}
__device__ __forceinline__ float softplusf(float z) {
  float t = __expf(z);
  return (z > 20.f) ? z : __logf(1.f + t);
}
__device__ __forceinline__ float lo16(u32 p) { return __uint_as_float(p << 16); }
__device__ __forceinline__ float hi16(u32 p) { return __uint_as_float(p & 0xffff0000u); }
__device__ __forceinline__ bf16x8 ld_bf8(const u16* p) {
  union { uint4 u; bf16x8 v; } c;
  c.u = *(const uint4*)p;
  return c.v;
}

// ---- K1: in_proj MFMA GEMM + (block 1024) k_sums fold ----------------------
__global__ __launch_bounds__(256) void k_inproj(const float* __restrict__ X,
                                                const float* __restrict__ W,
                                                u16* __restrict__ out,
                                                const float* __restrict__ W2,
                                                const float* __restrict__ gO,
                                                const float* __restrict__ bO,
                                                float* __restrict__ s12) {
  __shared__ __align__(16) u16 Ws[128 * 136];  // [o][c] bf16
  __shared__ __align__(16) u16 Xs[64 * 136];   // [l][c] bf16 (X^T tile)
  int tid = threadIdx.x;
  if (blockIdx.x == 1024) {  // folded k_sums: s1[o]=sum W2*beta, s2[o]=sum W2*gamma
    if (tid < 128) {
      int o = tid;
      float s1 = 0.f, s2 = 0.f;
      for (int c = 0; c < 128; ++c) {
        float w = W2[(o << 7) + c];
        s1 = fmaf(w, bO[c], s1);
        s2 = fmaf(w, gO[c], s2);
      }
      s12[o] = s1;
      s12[128 + o] = s2;
    }
    return;
  }
  int b = blockIdx.x >> 8;
  int l0 = (blockIdx.x & 255) << 6;
  for (int i = 0; i < 16; ++i) {
    int idx = (i << 8) + tid;
    int o = idx >> 5, c4 = (idx & 31) << 2;
    float4 w4 = *(const float4*)&W[(o << 7) + c4];
    ushort4 s;
    s.x = fbf(w4.x); s.y = fbf(w4.y); s.z = fbf(w4.z); s.w = fbf(w4.w);
    *(ushort4*)&Ws[o * 136 + c4] = s;
  }
  for (int i = 0; i < 8; ++i) {
    int idx = (i << 8) + tid;
    int c = idx >> 4, lq = (idx & 15) << 2;
    float4 x4 = *(const float4*)&X[(((long)(b << 7) + c) << 14) + l0 + lq];
    Xs[(lq + 0) * 136 + c] = fbf(x4.x);
    Xs[(lq + 1) * 136 + c] = fbf(x4.y);
    Xs[(lq + 2) * 136 + c] = fbf(x4.z);
    Xs[(lq + 3) * 136 + c] = fbf(x4.w);
  }
  __syncthreads();
  int w = tid >> 6, lane = tid & 63;
  int mrow = lane & 15, quad = lane >> 4;
  f32x4 acc[2][4];
#pragma unroll
  for (int ot = 0; ot < 2; ++ot)
#pragma unroll
    for (int lt = 0; lt < 4; ++lt) acc[ot][lt] = (f32x4){0.f, 0.f, 0.f, 0.f};
#pragma unroll
  for (int kb = 0; kb < 4; ++kb) {
    int c0 = (kb << 5) + (quad << 3);
    bf16x8 af[2], bfr[4];
#pragma unroll
    for (int ot = 0; ot < 2; ++ot)
      af[ot] = ld_bf8(&Ws[((w << 5) + (ot << 4) + mrow) * 136 + c0]);
#pragma unroll
    for (int lt = 0; lt < 4; ++lt)
      bfr[lt] = ld_bf8(&Xs[((lt << 4) + mrow) * 136 + c0]);
#pragma unroll
    for (int ot = 0; ot < 2; ++ot)
#pragma unroll
      for (int lt = 0; lt < 4; ++lt)
        acc[ot][lt] = __builtin_amdgcn_mfma_f32_16x16x32_bf16(af[ot], bfr[lt], acc[ot][lt], 0, 0, 0);
  }
#pragma unroll
  for (int ot = 0; ot < 2; ++ot)
#pragma unroll
    for (int lt = 0; lt < 4; ++lt) {
      int l = l0 + (lt << 4) + mrow;
      int o = (w << 5) + (ot << 4) + (quad << 2);
      ushort4 s;
      s.x = fbf(acc[ot][lt][0]); s.y = fbf(acc[ot][lt][1]);
      s.z = fbf(acc[ot][lt][2]); s.w = fbf(acc[ot][lt][3]);
      *(ushort4*)&out[(((long)(b << 14) + l) << 7) + o] = s;
    }
}

// ---- K2: depthwise 3x3 conv + SiLU (first conv), channels-last -------------
__global__ __launch_bounds__(256) void k_dwconv(const u16* __restrict__ in,
                                                const float* __restrict__ w9,
                                                const float* __restrict__ bias,
                                                u16* __restrict__ out) {
  __shared__ float wsT[9][128];
  __shared__ float bs[128];
  int tid = threadIdx.x;
  for (int i = 0; i < 5; ++i) {
    int lin = (i << 8) + tid;
    if (lin < 1152) { int c = lin / 9, k = lin - 9 * c; wsT[k][c] = w9[lin]; }
  }
  if (tid < 128) bs[tid] = bias[tid];
  __syncthreads();
  int blk = blockIdx.x;
  int b = blk >> 10;
  int s = blk & 1023;
  int h = s >> 3;
  int w = ((s & 7) << 4) + (tid >> 4);
  int c0 = (tid & 15) << 3;
  const u16* bbase = in + ((long)b << 21);
  float acc[8];
  {
    float4 b0 = *(const float4*)&bs[c0];
    float4 b1 = *(const float4*)&bs[c0 + 4];
    acc[0] = b0.x; acc[1] = b0.y; acc[2] = b0.z; acc[3] = b0.w;
    acc[4] = b1.x; acc[5] = b1.y; acc[6] = b1.z; acc[7] = b1.w;
  }
#pragma unroll
  for (int ky = -1; ky <= 1; ++ky) {
    int y = h + ky;
    if ((unsigned)y >= 128u) continue;
#pragma unroll
    for (int kx = -1; kx <= 1; ++kx) {
      int x = w + kx;
      if ((unsigned)x >= 128u) continue;
      int k = (ky + 1) * 3 + (kx + 1);
      uint4 v = *(const uint4*)(bbase + ((((y << 7) + x)) << 7) + c0);
      float4 w0 = *(const float4*)&wsT[k][c0];
      float4 w1 = *(const float4*)&wsT[k][c0 + 4];
      u32 vv[4] = {v.x, v.y, v.z, v.w};
      float wf[8] = {w0.x, w0.y, w0.z, w0.w, w1.x, w1.y, w1.z, w1.w};
#pragma unroll
      for (int cc = 0; cc < 8; ++cc) {
        float xv = (cc & 1) ? hi16(vv[cc >> 1]) : lo16(vv[cc >> 1]);
        acc[cc] = fmaf(wf[cc], xv, acc[cc]);
      }
    }
  }
#pragma unroll
  for (int cc = 0; cc < 8; ++cc) acc[cc] = acc[cc] / (1.f + __expf(-acc[cc]));
  ushort4 s0, s1;
  s0.x = fbf(acc[0]); s0.y = fbf(acc[1]); s0.z = fbf(acc[2]); s0.w = fbf(acc[3]);
  s1.x = fbf(acc[4]); s1.y = fbf(acc[5]); s1.z = fbf(acc[6]); s1.w = fbf(acc[7]);
  u16* po = out + ((long)b << 21) + ((((h << 7) + w)) << 7) + c0;
  *(ushort4*)po = s0;
  *(ushort4*)(po + 4) = s1;
}

// ---- K3: FUSED dwconv#2 + LN + GELU + offset MFMA projection ---------------
__global__ __launch_bounds__(256) void k_dwoff(const u16* __restrict__ in,
                                               const float* __restrict__ w9,
                                               const float* __restrict__ bias,
                                               const float* __restrict__ g,
                                               const float* __restrict__ bt,
                                               const float* __restrict__ offw,
                                               const float* __restrict__ offb,
                                               float* __restrict__ offs) {
  __shared__ float wsT[9][128];
  __shared__ float bs[128], gs[128], bsh[128];
  __shared__ __align__(16) u16 Ge[16 * 136];   // [pixel][c] bf16 gelu output
  __shared__ __align__(16) u16 Wos[16 * 136];  // [o][c] bf16
  int tid = threadIdx.x;
  for (int i = 0; i < 5; ++i) {
    int lin = (i << 8) + tid;
    if (lin < 1152) { int c = lin / 9, k = lin - 9 * c; wsT[k][c] = w9[lin]; }
  }
  if (tid < 128) { bs[tid] = bias[tid]; gs[tid] = g[tid]; bsh[tid] = bt[tid]; }
  for (int i = 0; i < 8; ++i) {
    int idx = (i << 8) + tid;  // 2048 = 16o x 128c
    int o = idx >> 7, c = idx & 127;
    Wos[o * 136 + c] = fbf(offw[idx]);
  }
  __syncthreads();
  int blk = blockIdx.x;
  int b = blk >> 10;
  int s = blk & 1023;
  int h = s >> 3;
  int p = tid >> 4;                 // pixel within block
  int w = ((s & 7) << 4) + p;
  int c0 = (tid & 15) << 3;
  const u16* bbase = in + ((long)b << 21);
  float acc[8];
  {
    float4 b0 = *(const float4*)&bs[c0];
    float4 b1 = *(const float4*)&bs[c0 + 4];
    acc[0] = b0.x; acc[1] = b0.y; acc[2] = b0.z; acc[3] = b0.w;
    acc[4] = b1.x; acc[5] = b1.y; acc[6] = b1.z; acc[7] = b1.w;
  }
#pragma unroll
  for (int ky = -1; ky <= 1; ++ky) {
    int y = h + ky;
    if ((unsigned)y >= 128u) continue;
#pragma unroll
    for (int kx = -1; kx <= 1; ++kx) {
      int x = w + kx;
      if ((unsigned)x >= 128u) continue;
      int k = (ky + 1) * 3 + (kx + 1);
      uint4 v = *(const uint4*)(bbase + ((((y << 7) + x)) << 7) + c0);
      float4 w0 = *(const float4*)&wsT[k][c0];
      float4 w1 = *(const float4*)&wsT[k][c0 + 4];
      u32 vv[4] = {v.x, v.y, v.z, v.w};
      float wf[8] = {w0.x, w0.y, w0.z, w0.w, w1.x, w1.y, w1.z, w1.w};
#pragma unroll
      for (int cc = 0; cc < 8; ++cc) {
        float xv = (cc & 1) ? hi16(vv[cc >> 1]) : lo16(vv[cc >> 1]);
        acc[cc] = fmaf(wf[cc], xv, acc[cc]);
      }
    }
  }
  // LN stats over 128 c: per-thread partial (8 ch) + reduce across the 16
  // contiguous lanes sharing this pixel
  float sum = 0.f, ssum = 0.f;
#pragma unroll
  for (int cc = 0; cc < 8; ++cc) { sum += acc[cc]; ssum = fmaf(acc[cc], acc[cc], ssum); }
#pragma unroll
  for (int off = 1; off < 16; off <<= 1) {
    sum += __shfl_xor(sum, off);
    ssum += __shfl_xor(ssum, off);
  }
  float m = sum * (1.f / 128.f);
  float r = rsqrtf(ssum * (1.f / 128.f) - m * m + 1e-6f);
  // LN + GELU -> bf16 pack into Ge[p][c0..c0+7]
  {
    u32 pk[4];
#pragma unroll
    for (int jj = 0; jj < 4; ++jj) {
      u16 h2[2];
#pragma unroll
      for (int e = 0; e < 2; ++e) {
        int cc = 2 * jj + e;
        float xn = fmaf((acc[cc] - m) * r, gs[c0 + cc], bsh[c0 + cc]);
        h2[e] = fbf(0.5f * xn * (1.f + erff(xn * 0.70710678118f)));
      }
      pk[jj] = (u32)h2[0] | ((u32)h2[1] << 16);
    }
    *(uint4*)&Ge[p * 136 + c0] = make_uint4(pk[0], pk[1], pk[2], pk[3]);
  }
  __syncthreads();
  // wave 0: 16x16x128 offset projection (4 MFMA) + store
  if (tid < 64) {
    int lane = tid;
    int mrow = lane & 15, quad = lane >> 4;
    f32x4 acc0 = (f32x4){0.f, 0.f, 0.f, 0.f};
#pragma unroll
    for (int kb = 0; kb < 4; ++kb) {
      int cb = (kb << 5) + (quad << 3);
      bf16x8 af = ld_bf8(&Wos[mrow * 136 + cb]);
      bf16x8 bfr = ld_bf8(&Ge[mrow * 136 + cb]);
      acc0 = __builtin_amdgcn_mfma_f32_16x16x32_bf16(af, bfr, acc0, 0, 0, 0);
    }
    // D: col(lane&15)=pixel, row(quad*4+reg)=o; o pairs (2g,2g+1)
    int l = (h << 7) + ((s & 7) << 4) + mrow;
    float2* po = (float2*)offs;
    int o0 = quad << 2;
    po[(((long)((b << 3) + (quad << 1))) << 14) + l] =
        make_float2(acc0[0] + offb[o0], acc0[1] + offb[o0 + 1]);
    po[(((long)((b << 3) + (quad << 1) + 1)) << 14) + l] =
        make_float2(acc0[2] + offb[o0 + 2], acc0[3] + offb[o0 + 3]);
  }
}

// ---- K4: DCN gather + x_proj + dt_w; 64-pixel tile, 512 thr ----------------
// v3: r1's wave-coherent gather layout (wave = 64 consecutive pixels of ONE
// group -> spatially clustered taps) + r1's conflict-free stride-81 LDS
// reduce, combined with r2's global-dtw dts phase (LDS 45.5->39.7KB => 4
// blocks/CU, 32 waves) and branchless clamped taps (validity folded into the
// weight, exactly the reference tap() semantics) so all 8 gather loads issue
// as straight-line independent loads.
__global__ __launch_bounds__(512, 8) void k_dcn(const u16* __restrict__ xc,
                                                const float* __restrict__ offs,
                                                const float* __restrict__ xpw,
                                                const float* __restrict__ dtw,
                                                u16* __restrict__ xs,
                                                u16* __restrict__ dts,
                                                float* __restrict__ Bsb,
                                                float* __restrict__ Csb) {
  __shared__ __align__(16) u16 xds_bf[64 * 132];  // [p][c] bf16, stride 132
  __shared__ float part[64 * 81];                 // [p][8r+gg], stride 81 (17p mod 32: 2-way max)
  __shared__ __align__(16) float xdblT[8 * 64];   // [r][p] (dt ranks only)
  int tid = threadIdx.x;
  int blk = blockIdx.x;
  int b = blk >> 8;
  int l0 = (blk & 255) << 6;
  int p = tid & 63, gg = tid >> 6;
  int l = l0 + p, hh = l >> 7, ww = l & 127;
  float2 off = ((const float2*)offs)[(((long)((b << 3) + gg)) << 14) + l];
  float px = (float)ww + off.x, py = (float)hh + off.y;
  float x0f = floorf(px), y0f = floorf(py);
  float wx = px - x0f, wy = py - y0f;
  int ix = (int)x0f, iy = (int)y0f;
  // clamped coords + validity folded into weights (branchless)
  int x0c = min(max(ix, 0), 127), x1c = min(max(ix + 1, 0), 127);
  int y0c = min(max(iy, 0), 127), y1c = min(max(iy + 1, 0), 127);
  float vx0 = ((unsigned)ix < 128u) ? 1.f : 0.f;
  float vx1 = ((unsigned)(ix + 1) < 128u) ? 1.f : 0.f;
  float vy0 = ((unsigned)iy < 128u) ? 1.f : 0.f;
  float vy1 = ((unsigned)(iy + 1) < 128u) ? 1.f : 0.f;
  float wt4[4] = {(1.f - wy) * (1.f - wx) * vy0 * vx0,
                  (1.f - wy) * wx * vy0 * vx1,
                  wy * (1.f - wx) * vy1 * vx0,
                  wy * wx * vy1 * vx1};
  const u16* bbase = xc + ((long)b << 21) + (gg << 4);
  const u16* tp[4];
  tp[0] = bbase + ((((y0c << 7) + x0c)) << 7);
  tp[1] = bbase + ((((y0c << 7) + x1c)) << 7);
  tp[2] = bbase + ((((y1c << 7) + x0c)) << 7);
  tp[3] = bbase + ((((y1c << 7) + x1c)) << 7);
  float acc[16];
#pragma unroll
  for (int ch = 0; ch < 16; ++ch) acc[ch] = 0.f;
#pragma unroll
  for (int t = 0; t < 4; ++t) {
    uint4 v0 = *(const uint4*)tp[t];
    uint4 v1 = *(const uint4*)(tp[t] + 8);
    float wv = wt4[t];
    u32 vv[8] = {v0.x, v0.y, v0.z, v0.w, v1.x, v1.y, v1.z, v1.w};
#pragma unroll
    for (int ch = 0; ch < 16; ++ch) {
      float xv = (ch & 1) ? hi16(vv[ch >> 1]) : lo16(vv[ch >> 1]);
      acc[ch] = fmaf(wv, xv, acc[ch]);
    }
  }
  // bf16 transpose tile (bit-identical to xs output values)
  {
    u32 pk[8];
#pragma unroll
    for (int j = 0; j < 8; ++j)
      pk[j] = (u32)fbf(acc[2 * j]) | ((u32)fbf(acc[2 * j + 1]) << 16);
    u16* row = &xds_bf[p * 132 + (gg << 4)];
#pragma unroll
    for (int q = 0; q < 4; ++q)
      *(uint2*)(row + (q << 2)) = make_uint2(pk[2 * q], pk[2 * q + 1]);
  }
  // x_proj partials from registers; weights via wave-uniform s_load path
  {
    int ggu = __builtin_amdgcn_readfirstlane(gg);
    const float* wb = xpw + (ggu << 4);
    int pbase = p * 81 + gg;
#pragma unroll
    for (int r = 0; r < 10; ++r) {
      const float* wr = wb + (r << 7);
      float s = 0.f;
#pragma unroll
      for (int ch = 0; ch < 16; ++ch) s = fmaf(wr[ch], acc[ch], s);
      part[pbase + (r << 3)] = s;
    }
  }
  __syncthreads();
  // reduce partials over the 8 channel groups: 640 tasks (r, p2),
  // wave-uniform r -> reads at stride 81 are conflict-free
  {
    int task = tid;
#pragma unroll
    for (int pass = 0; pass < 2; ++pass, task += 512) {
      if (task < 640) {
        int r = task >> 6, p2 = task & 63;
        const float* pp = &part[p2 * 81 + (r << 3)];
        float s = ((pp[0] + pp[1]) + (pp[2] + pp[3])) + ((pp[4] + pp[5]) + (pp[6] + pp[7]));
        if (r < 8) xdblT[(r << 6) + p2] = s;
        else if (r == 8) Bsb[((long)b << 14) + l0 + p2] = s;
        else Csb[((long)b << 14) + l0 + p2] = s;
      }
    }
  }
  // xs pack/store: 1024 tasks (128 c x 8 l-octets); 16B stores, full lines
  // (xds_bf was final before the first barrier; safe to read here)
#pragma unroll
  for (int it = 0; it < 2; ++it) {
    int task = (it << 9) + tid;
    int cc = task >> 3, t = task & 7;
    u32 pk[4];
#pragma unroll
    for (int jj = 0; jj < 4; ++jj) {
      u16 a0 = xds_bf[((t << 3) + 2 * jj + 0) * 132 + cc];
      u16 a1 = xds_bf[((t << 3) + 2 * jj + 1) * 132 + cc];
      pk[jj] = (u32)a0 | ((u32)a1 << 16);
    }
    *(uint4*)&xs[(((long)(b << 7) + cc) << 14) + l0 + (t << 3)] =
        make_uint4(pk[0], pk[1], pk[2], pk[3]);
  }
  __syncthreads();  // xdblT visible
  // dts: thread handles (dd, t) and (dd+64, t); dtw rows from global (cached)
  {
    int dd = tid >> 3, t = tid & 7;
    float4 a0 = *(const float4*)&dtw[dd << 3];
    float4 a1 = *(const float4*)&dtw[(dd << 3) + 4];
    float4 b0 = *(const float4*)&dtw[(dd + 64) << 3];
    float4 b1 = *(const float4*)&dtw[((dd + 64) << 3) + 4];
    float wr0[8] = {a0.x, a0.y, a0.z, a0.w, a1.x, a1.y, a1.z, a1.w};
    float wr1[8] = {b0.x, b0.y, b0.z, b0.w, b1.x, b1.y, b1.z, b1.w};
    float y0[8], y1[8];
#pragma unroll
    for (int j = 0; j < 8; ++j) { y0[j] = 0.f; y1[j] = 0.f; }
#pragma unroll
    for (int rr = 0; rr < 8; ++rr) {
      float w0 = wr0[rr], w1 = wr1[rr];
      const float* xr = &xdblT[(rr << 6) + (t << 3)];
      float4 xa = *(const float4*)xr;
      float4 xb = *(const float4*)(xr + 4);
      float xv[8] = {xa.x, xa.y, xa.z, xa.w, xb.x, xb.y, xb.z, xb.w};
#pragma unroll
      for (int j = 0; j < 8; ++j) {
        y0[j] = fmaf(w0, xv[j], y0[j]);
        y1[j] = fmaf(w1, xv[j], y1[j]);
      }
    }
    u32 pk0[4], pk1[4];
#pragma unroll
    for (int jj = 0; jj < 4; ++jj) {
      pk0[jj] = (u32)fbf(y0[2 * jj]) | ((u32)fbf(y0[2 * jj + 1]) << 16);
      pk1[jj] = (u32)fbf(y1[2 * jj]) | ((u32)fbf(y1[2 * jj + 1]) << 16);
    }
    *(uint4*)&dts[(((long)(b << 7) + dd) << 14) + l0 + (t << 3)] =
        make_uint4(pk0[0], pk0[1], pk0[2], pk0[3]);
    *(uint4*)&dts[(((long)(b << 7) + dd + 64) << 14) + l0 + (t << 3)] =
        make_uint4(pk1[0], pk1[1], pk1[2], pk1[3]);
  }
}

// ---- K5: selective scan, shfl-based block scan, cheap softplus -------------
__global__ __launch_bounds__(1024) void k_scan(u16* __restrict__ xy,
                                               const u16* __restrict__ dts16,
                                               const float* __restrict__ Bsb,
                                               const float* __restrict__ Csb,
                                               const float* __restrict__ A_logs,
                                               const float* __restrict__ Dsv,
                                               const float* __restrict__ dtbv) {
  __shared__ float swp[16], swe[16];
  int bd = blockIdx.x;
  int b = bd >> 7, d = bd & 127;
  float Ad = -__expf(A_logs[d]);
  float dtb = dtbv[d];
  float Dd = Dsv[d];
  int t = threadIdx.x;
  int lane = t & 63, wid = t >> 6;
  long base = ((long)bd << 14) + (t << 4);
  long bb = ((long)b << 14) + (t << 4);
  const uint4* pz4 = (const uint4*)(dts16 + base);
  const uint4* px4 = (const uint4*)(xy + base);
  const float4* pB = (const float4*)(Bsb + bb);
  const float4* pC = (const float4*)(Csb + bb);
  uint4 zA = pz4[0], zB = pz4[1];
  uint4 xA = px4[0], xB = px4[1];
  u32 zw[8] = {zA.x, zA.y, zA.z, zA.w, zB.x, zB.y, zB.z, zB.w};
  u32 xw[8] = {xA.x, xA.y, xA.z, xA.w, xB.x, xB.y, xB.z, xB.w};
  float E = 0.f, P = 1.f;
#pragma unroll
  for (int q = 0; q < 4; ++q) {
    float4 B4 = pB[q];
    float Bq[4] = {B4.x, B4.y, B4.z, B4.w};
#pragma unroll
    for (int j = 0; j < 4; ++j) {
      int k = (q << 2) + j;
      float z = (k & 1) ? hi16(zw[k >> 1]) : lo16(zw[k >> 1]);
      float xv = (k & 1) ? hi16(xw[k >> 1]) : lo16(xw[k >> 1]);
      float delta = softplusf(z + dtb);
      float a = __expf(delta * Ad);
      E = fmaf(a, E, delta * Bq[j] * xv);
      P *= a;
    }
  }
#pragma unroll
  for (int off = 1; off < 64; off <<= 1) {
    float Pp = __shfl_up(P, off);
    float Ep = __shfl_up(E, off);
    if (lane >= off) { E = fmaf(P, Ep, E); P *= Pp; }
  }
  if (lane == 63) { swp[wid] = P; swe[wid] = E; }
  __syncthreads();
  if (t < 16) {
    float p2 = swp[t], e2 = swe[t];
#pragma unroll
    for (int off = 1; off < 16; off <<= 1) {
      float pp = __shfl_up(p2, off);
      float ee = __shfl_up(e2, off);
      if (t >= off) { e2 = fmaf(p2, ee, e2); p2 *= pp; }
    }
    swp[t] = p2; swe[t] = e2;
  }
  __syncthreads();
  float hw = (wid == 0) ? 0.f : swe[wid - 1];
  float Pex = __shfl_up(P, 1);
  float Eex = __shfl_up(E, 1);
  if (lane == 0) { Pex = 1.f; Eex = 0.f; }
  float h = fmaf(Pex, hw, Eex);
  u32 ypk[8];
#pragma unroll
  for (int q = 0; q < 4; ++q) {
    float4 B4 = pB[q];
    float4 C4 = pC[q];
    float Bq[4] = {B4.x, B4.y, B4.z, B4.w};
    float Cq[4] = {C4.x, C4.y, C4.z, C4.w};
#pragma unroll
    for (int j = 0; j < 4; ++j) {
      int k = (q << 2) + j;
      float z = (k & 1) ? hi16(zw[k >> 1]) : lo16(zw[k >> 1]);
      float xv = (k & 1) ? hi16(xw[k >> 1]) : lo16(xw[k >> 1]);
      float delta = softplusf(z + dtb);
      float a = __expf(delta * Ad);
      h = fmaf(a, h, delta * Bq[j] * xv);
      u16 yb = fbf(fmaf(Dd, xv, h * Cq[j]));
      if ((k & 1) == 0) ypk[k >> 1] = yb; else ypk[k >> 1] |= (u32)yb << 16;
    }
  }
  uint4* py = (uint4*)(xy + base);
  py[0] = make_uint4(ypk[0], ypk[1], ypk[2], ypk[3]);
  py[1] = make_uint4(ypk[4], ypk[5], ypk[6], ypk[7]);
}

// ---- K7: out_proj MFMA GEMM + fused LN epilogue (f32 out, [b,o,l]) ---------
__global__ __launch_bounds__(256) void k_outproj(const u16* __restrict__ y,
                                                 const float* __restrict__ W2,
                                                 const float* __restrict__ g,
                                                 const float* __restrict__ s12,
                                                 float* __restrict__ out) {
  __shared__ __align__(16) u16 Ws[128 * 136];  // [o][c] bf16 of W2*gamma
  __shared__ __align__(16) u16 Ys[64 * 136];   // [l][c] bf16 (y^T tile)
  __shared__ float ps[4][64], pss[4][64];
  __shared__ float mean_s[64], rstd_s[64];
  int tid = threadIdx.x;
  int b = blockIdx.x >> 8;
  int l0 = (blockIdx.x & 255) << 6;
  for (int i = 0; i < 16; ++i) {
    int idx = (i << 8) + tid;
    int o = idx >> 5, c4 = (idx & 31) << 2;
    float4 w4 = *(const float4*)&W2[(o << 7) + c4];
    ushort4 s;
    s.x = fbf(w4.x * g[c4]);     s.y = fbf(w4.y * g[c4 + 1]);
    s.z = fbf(w4.z * g[c4 + 2]); s.w = fbf(w4.w * g[c4 + 3]);
    *(ushort4*)&Ws[o * 136 + c4] = s;
  }
  for (int i = 0; i < 4; ++i) {
    int idx = (i << 8) + tid;
    int c = idx >> 3, lq = (idx & 7) << 3;
    uint4 v = *(const uint4*)&y[(((long)(b << 7) + c) << 14) + l0 + lq];
    u32 vv[4] = {v.x, v.y, v.z, v.w};
#pragma unroll
    for (int r = 0; r < 8; ++r)
      Ys[(lq + r) * 136 + c] = (u16)((r & 1) ? (vv[r >> 1] >> 16) : (vv[r >> 1] & 0xffffu));
  }
  __syncthreads();
  {
    int l = tid & 63, q = tid >> 6;
    const u16* row = &Ys[l * 136 + (q << 5)];
    float s = 0.f, ss = 0.f;
#pragma unroll 8
    for (int c = 0; c < 32; ++c) { float v = bfu(row[c]); s += v; ss = fmaf(v, v, ss); }
    ps[q][l] = s; pss[q][l] = ss;
  }
  __syncthreads();
  if (tid < 64) {
    float s = ps[0][tid] + ps[1][tid] + ps[2][tid] + ps[3][tid];
    float ss = pss[0][tid] + pss[1][tid] + pss[2][tid] + pss[3][tid];
    float m = s * (1.f / 128.f);
    mean_s[tid] = m;
    rstd_s[tid] = rsqrtf(ss * (1.f / 128.f) - m * m + 1e-6f);
  }
  __syncthreads();
  int w = tid >> 6, lane = tid & 63;
  int mrow = lane & 15, quad = lane >> 4;
  f32x4 acc[2][4];
#pragma unroll
  for (int ot = 0; ot < 2; ++ot)
#pragma unroll
    for (int lt = 0; lt < 4; ++lt) acc[ot][lt] = (f32x4){0.f, 0.f, 0.f, 0.f};
#pragma unroll
  for (int kb = 0; kb < 4; ++kb) {
    int c0 = (kb << 5) + (quad << 3);
    bf16x8 af[2], bfr[4];
#pragma unroll
    for (int ot = 0; ot < 2; ++ot)
      af[ot] = ld_bf8(&Ws[((w << 5) + (ot << 4) + mrow) * 136 + c0]);
#pragma unroll
    for (int lt = 0; lt < 4; ++lt)
      bfr[lt] = ld_bf8(&Ys[((lt << 4) + mrow) * 136 + c0]);
#pragma unroll
    for (int ot = 0; ot < 2; ++ot)
#pragma unroll
      for (int lt = 0; lt < 4; ++lt)
        acc[ot][lt] = __builtin_amdgcn_mfma_f32_16x16x32_bf16(af[ot], bfr[lt], acc[ot][lt], 0, 0, 0);
  }
  float s1r[2][4], s2r[2][4];
#pragma unroll
  for (int ot = 0; ot < 2; ++ot)
#pragma unroll
    for (int r = 0; r < 4; ++r) {
      int o = (w << 5) + (ot << 4) + (quad << 2) + r;
      s1r[ot][r] = s12[o];
      s2r[ot][r] = s12[128 + o];
    }
#pragma unroll
  for (int ot = 0; ot < 2; ++ot)
#pragma unroll
    for (int lt = 0; lt < 4; ++lt) {
      int lcol = (lt << 4) + mrow;
      float mv = mean_s[lcol], rv = rstd_s[lcol];
      int obase = (w << 5) + (ot << 4) + (quad << 2);
#pragma unroll
      for (int r = 0; r < 4; ++r) {
        float v = fmaf(rv, acc[ot][lt][r] - mv * s2r[ot][r], s1r[ot][r]);
        out[(((long)(b << 7) + obase + r) << 14) + l0 + lcol] = v;
      }
    }
}

extern "C" void kernel_launch(void* const* d_in, const int* in_sizes, int n_in,
                              void* d_out, int out_size, void* d_ws, size_t ws_size,
                              hipStream_t stream) {
  const float* x         = (const float*)d_in[0];
  const float* in_proj_w = (const float*)d_in[1];
  const float* conv2d_w  = (const float*)d_in[2];
  const float* conv2d_b  = (const float*)d_in[3];
  const float* dw_w      = (const float*)d_in[4];
  const float* dw_b      = (const float*)d_in[5];
  const float* dw_ln_g   = (const float*)d_in[6];
  const float* dw_ln_b   = (const float*)d_in[7];
  const float* off_w     = (const float*)d_in[8];
  const float* off_b     = (const float*)d_in[9];
  const float* x_proj_w  = (const float*)d_in[10];
  const float* dt_w      = (const float*)d_in[11];
  const float* dt_b      = (const float*)d_in[12];
  const float* A_logs    = (const float*)d_in[13];
  const float* Ds        = (const float*)d_in[14];
  const float* out_ln_g  = (const float*)d_in[15];
  const float* out_ln_b  = (const float*)d_in[16];
  const float* out_proj_w= (const float*)d_in[17];
  float* out = (float*)d_out;

  u16* A  = (u16*)d_ws;            // xin_cl -> xs[b,c,l] -> y[b,c,l]
  u16* Bx = A + 8388608;           // xc_cl
  u16* Dd = Bx + 8388608;          // dts[b,c,l]
  float* offs  = (float*)(Dd + 8388608);  // [b][g][l] float2
  float* Bsb   = offs + 1048576;
  float* Csb   = Bsb + 65536;
  float* s12   = Csb + 65536;

  hipLaunchKernelGGL(k_inproj, dim3(1025), dim3(256), 0, stream, x, in_proj_w, A,
                     out_proj_w, out_ln_g, out_ln_b, s12);
  hipLaunchKernelGGL(k_dwconv, dim3(4096), dim3(256), 0, stream, A, conv2d_w, conv2d_b, Bx);
  hipLaunchKernelGGL(k_dwoff, dim3(4096), dim3(256), 0, stream, Bx, dw_w, dw_b,
                     dw_ln_g, dw_ln_b, off_w, off_b, offs);
  hipLaunchKernelGGL(k_dcn, dim3(1024), dim3(512), 0, stream, Bx, offs, x_proj_w, dt_w, A, Dd, Bsb, Csb);
  hipLaunchKernelGGL(k_scan, dim3(512), dim3(1024), 0, stream, A, Dd, Bsb, Csb, A_logs, Ds, dt_b);
  hipLaunchKernelGGL(k_outproj, dim3(1024), dim3(256), 0, stream, A, out_proj_w, out_ln_g, s12, out);
}

// Round 5
// 218.818 us; speedup vs baseline: 1.0730x; 1.0121x over previous
//
#include <hip/hip_runtime.h>
#include <hip/hip_bf16.h>

typedef unsigned short u16;
typedef unsigned int u32;
typedef __bf16 bf16x8 __attribute__((ext_vector_type(8)));
typedef float f32x4 __attribute__((ext_vector_type(4)));

__device__ __forceinline__ float bfu(u16 u) { return __uint_as_float(((u32)u) << 16); }
__device__ __forceinline__ u16 fbf(float f) {
  __hip_bfloat16 h = __float2bfloat16(f);
  return *reinterpret_cast<u16*>(&h);
}
__device__ __forceinline__ float softplusf(float z) {
  float t = __expf(z);
  return (z > 20.f) ? z : __logf(1.f + t);
}
__device__ __forceinline__ float lo16(u32 p) { return __uint_as_float(p << 16); }
__device__ __forceinline__ float hi16(u32 p) { return __uint_as_float(p & 0xffff0000u); }
__device__ __forceinline__ bf16x8 ld_bf8(const u16* p) {
  union { uint4 u; bf16x8 v; } c;
  c.u = *(const uint4*)p;
  return c.v;
}

// xc layout is GROUP-BLOCKED channels-last: [b][g][y][x][c16] (u16 units:
// base + ((b*8+g)<<18) + ((y*128+x)<<4) + c).  This makes a DCN bilinear
// tap pair (x0,x0+1) a contiguous 64B region -> half the L1 line
// transactions in the k_dcn gather vs the flat [y][x][c128] layout.

// ---- K1: in_proj MFMA GEMM + (block 1024) k_sums fold ----------------------
__global__ __launch_bounds__(256) void k_inproj(const float* __restrict__ X,
                                                const float* __restrict__ W,
                                                u16* __restrict__ out,
                                                const float* __restrict__ W2,
                                                const float* __restrict__ gO,
                                                const float* __restrict__ bO,
                                                float* __restrict__ s12) {
  __shared__ __align__(16) u16 Ws[128 * 136];  // [o][c] bf16
  __shared__ __align__(16) u16 Xs[64 * 136];   // [l][c] bf16 (X^T tile)
  int tid = threadIdx.x;
  if (blockIdx.x == 1024) {  // folded k_sums: s1[o]=sum W2*beta, s2[o]=sum W2*gamma
    if (tid < 128) {
      int o = tid;
      float s1 = 0.f, s2 = 0.f;
      for (int c = 0; c < 128; ++c) {
        float w = W2[(o << 7) + c];
        s1 = fmaf(w, bO[c], s1);
        s2 = fmaf(w, gO[c], s2);
      }
      s12[o] = s1;
      s12[128 + o] = s2;
    }
    return;
  }
  int b = blockIdx.x >> 8;
  int l0 = (blockIdx.x & 255) << 6;
  for (int i = 0; i < 16; ++i) {
    int idx = (i << 8) + tid;
    int o = idx >> 5, c4 = (idx & 31) << 2;
    float4 w4 = *(const float4*)&W[(o << 7) + c4];
    ushort4 s;
    s.x = fbf(w4.x); s.y = fbf(w4.y); s.z = fbf(w4.z); s.w = fbf(w4.w);
    *(ushort4*)&Ws[o * 136 + c4] = s;
  }
  for (int i = 0; i < 8; ++i) {
    int idx = (i << 8) + tid;
    int c = idx >> 4, lq = (idx & 15) << 2;
    float4 x4 = *(const float4*)&X[(((long)(b << 7) + c) << 14) + l0 + lq];
    Xs[(lq + 0) * 136 + c] = fbf(x4.x);
    Xs[(lq + 1) * 136 + c] = fbf(x4.y);
    Xs[(lq + 2) * 136 + c] = fbf(x4.z);
    Xs[(lq + 3) * 136 + c] = fbf(x4.w);
  }
  __syncthreads();
  int w = tid >> 6, lane = tid & 63;
  int mrow = lane & 15, quad = lane >> 4;
  f32x4 acc[2][4];
#pragma unroll
  for (int ot = 0; ot < 2; ++ot)
#pragma unroll
    for (int lt = 0; lt < 4; ++lt) acc[ot][lt] = (f32x4){0.f, 0.f, 0.f, 0.f};
#pragma unroll
  for (int kb = 0; kb < 4; ++kb) {
    int c0 = (kb << 5) + (quad << 3);
    bf16x8 af[2], bfr[4];
#pragma unroll
    for (int ot = 0; ot < 2; ++ot)
      af[ot] = ld_bf8(&Ws[((w << 5) + (ot << 4) + mrow) * 136 + c0]);
#pragma unroll
    for (int lt = 0; lt < 4; ++lt)
      bfr[lt] = ld_bf8(&Xs[((lt << 4) + mrow) * 136 + c0]);
#pragma unroll
    for (int ot = 0; ot < 2; ++ot)
#pragma unroll
      for (int lt = 0; lt < 4; ++lt)
        acc[ot][lt] = __builtin_amdgcn_mfma_f32_16x16x32_bf16(af[ot], bfr[lt], acc[ot][lt], 0, 0, 0);
  }
#pragma unroll
  for (int ot = 0; ot < 2; ++ot)
#pragma unroll
    for (int lt = 0; lt < 4; ++lt) {
      int l = l0 + (lt << 4) + mrow;
      int o = (w << 5) + (ot << 4) + (quad << 2);
      ushort4 s;
      s.x = fbf(acc[ot][lt][0]); s.y = fbf(acc[ot][lt][1]);
      s.z = fbf(acc[ot][lt][2]); s.w = fbf(acc[ot][lt][3]);
      *(ushort4*)&out[(((long)(b << 14) + l) << 7) + o] = s;
    }
}

// ---- K2: depthwise 3x3 conv + SiLU; in [l][c128], out group-blocked --------
__global__ __launch_bounds__(256) void k_dwconv(const u16* __restrict__ in,
                                                const float* __restrict__ w9,
                                                const float* __restrict__ bias,
                                                u16* __restrict__ out) {
  __shared__ float wsT[9][128];
  __shared__ float bs[128];
  int tid = threadIdx.x;
  for (int i = 0; i < 5; ++i) {
    int lin = (i << 8) + tid;
    if (lin < 1152) { int c = lin / 9, k = lin - 9 * c; wsT[k][c] = w9[lin]; }
  }
  if (tid < 128) bs[tid] = bias[tid];
  __syncthreads();
  int blk = blockIdx.x;
  int b = blk >> 10;
  int s = blk & 1023;
  int h = s >> 3;
  int w = ((s & 7) << 4) + (tid >> 4);
  int c0 = (tid & 15) << 3;
  const u16* bbase = in + ((long)b << 21);
  float acc[8];
  {
    float4 b0 = *(const float4*)&bs[c0];
    float4 b1 = *(const float4*)&bs[c0 + 4];
    acc[0] = b0.x; acc[1] = b0.y; acc[2] = b0.z; acc[3] = b0.w;
    acc[4] = b1.x; acc[5] = b1.y; acc[6] = b1.z; acc[7] = b1.w;
  }
#pragma unroll
  for (int ky = -1; ky <= 1; ++ky) {
    int y = h + ky;
    if ((unsigned)y >= 128u) continue;
#pragma unroll
    for (int kx = -1; kx <= 1; ++kx) {
      int x = w + kx;
      if ((unsigned)x >= 128u) continue;
      int k = (ky + 1) * 3 + (kx + 1);
      uint4 v = *(const uint4*)(bbase + ((((y << 7) + x)) << 7) + c0);
      float4 w0 = *(const float4*)&wsT[k][c0];
      float4 w1 = *(const float4*)&wsT[k][c0 + 4];
      u32 vv[4] = {v.x, v.y, v.z, v.w};
      float wf[8] = {w0.x, w0.y, w0.z, w0.w, w1.x, w1.y, w1.z, w1.w};
#pragma unroll
      for (int cc = 0; cc < 8; ++cc) {
        float xv = (cc & 1) ? hi16(vv[cc >> 1]) : lo16(vv[cc >> 1]);
        acc[cc] = fmaf(wf[cc], xv, acc[cc]);
      }
    }
  }
#pragma unroll
  for (int cc = 0; cc < 8; ++cc) acc[cc] = acc[cc] / (1.f + __expf(-acc[cc]));
  // group-blocked store: [b][g][y][x][c16], this thread covers sub..sub+7
  int g4 = c0 >> 4, sub = c0 & 15;
  uint4 pkst;
  pkst.x = (u32)fbf(acc[0]) | ((u32)fbf(acc[1]) << 16);
  pkst.y = (u32)fbf(acc[2]) | ((u32)fbf(acc[3]) << 16);
  pkst.z = (u32)fbf(acc[4]) | ((u32)fbf(acc[5]) << 16);
  pkst.w = (u32)fbf(acc[6]) | ((u32)fbf(acc[7]) << 16);
  u16* po = out + (((long)(b << 3) + g4) << 18) + ((((h << 7) + w)) << 4) + sub;
  *(uint4*)po = pkst;
}

// ---- K3: FUSED dwconv#2 + LN + GELU + offset MFMA projection ---------------
// Input xc is group-blocked [b][g][y][x][c16].
__global__ __launch_bounds__(256) void k_dwoff(const u16* __restrict__ in,
                                               const float* __restrict__ w9,
                                               const float* __restrict__ bias,
                                               const float* __restrict__ g,
                                               const float* __restrict__ bt,
                                               const float* __restrict__ offw,
                                               const float* __restrict__ offb,
                                               float* __restrict__ offs) {
  __shared__ float wsT[9][128];
  __shared__ float bs[128], gs[128], bsh[128];
  __shared__ __align__(16) u16 Ge[16 * 136];   // [pixel][c] bf16 gelu output
  __shared__ __align__(16) u16 Wos[16 * 136];  // [o][c] bf16
  int tid = threadIdx.x;
  for (int i = 0; i < 5; ++i) {
    int lin = (i << 8) + tid;
    if (lin < 1152) { int c = lin / 9, k = lin - 9 * c; wsT[k][c] = w9[lin]; }
  }
  if (tid < 128) { bs[tid] = bias[tid]; gs[tid] = g[tid]; bsh[tid] = bt[tid]; }
  for (int i = 0; i < 8; ++i) {
    int idx = (i << 8) + tid;  // 2048 = 16o x 128c
    int o = idx >> 7, c = idx & 127;
    Wos[o * 136 + c] = fbf(offw[idx]);
  }
  __syncthreads();
  int blk = blockIdx.x;
  int b = blk >> 10;
  int s = blk & 1023;
  int h = s >> 3;
  int p = tid >> 4;                 // pixel within block
  int w = ((s & 7) << 4) + p;
  int c0 = (tid & 15) << 3;
  int g4 = c0 >> 4, sub = c0 & 15;
  const u16* bbase = in + (((long)(b << 3) + g4) << 18) + sub;
  float acc[8];
  {
    float4 b0 = *(const float4*)&bs[c0];
    float4 b1 = *(const float4*)&bs[c0 + 4];
    acc[0] = b0.x; acc[1] = b0.y; acc[2] = b0.z; acc[3] = b0.w;
    acc[4] = b1.x; acc[5] = b1.y; acc[6] = b1.z; acc[7] = b1.w;
  }
#pragma unroll
  for (int ky = -1; ky <= 1; ++ky) {
    int y = h + ky;
    if ((unsigned)y >= 128u) continue;
#pragma unroll
    for (int kx = -1; kx <= 1; ++kx) {
      int x = w + kx;
      if ((unsigned)x >= 128u) continue;
      int k = (ky + 1) * 3 + (kx + 1);
      uint4 v = *(const uint4*)(bbase + ((((y << 7) + x)) << 4));
      float4 w0 = *(const float4*)&wsT[k][c0];
      float4 w1 = *(const float4*)&wsT[k][c0 + 4];
      u32 vv[4] = {v.x, v.y, v.z, v.w};
      float wf[8] = {w0.x, w0.y, w0.z, w0.w, w1.x, w1.y, w1.z, w1.w};
#pragma unroll
      for (int cc = 0; cc < 8; ++cc) {
        float xv = (cc & 1) ? hi16(vv[cc >> 1]) : lo16(vv[cc >> 1]);
        acc[cc] = fmaf(wf[cc], xv, acc[cc]);
      }
    }
  }
  // LN stats over 128 c: per-thread partial (8 ch) + reduce across the 16
  // contiguous lanes sharing this pixel
  float sum = 0.f, ssum = 0.f;
#pragma unroll
  for (int cc = 0; cc < 8; ++cc) { sum += acc[cc]; ssum = fmaf(acc[cc], acc[cc], ssum); }
#pragma unroll
  for (int off = 1; off < 16; off <<= 1) {
    sum += __shfl_xor(sum, off);
    ssum += __shfl_xor(ssum, off);
  }
  float m = sum * (1.f / 128.f);
  float r = rsqrtf(ssum * (1.f / 128.f) - m * m + 1e-6f);
  // LN + GELU -> bf16 pack into Ge[p][c0..c0+7]
  {
    u32 pk[4];
#pragma unroll
    for (int jj = 0; jj < 4; ++jj) {
      u16 h2[2];
#pragma unroll
      for (int e = 0; e < 2; ++e) {
        int cc = 2 * jj + e;
        float xn = fmaf((acc[cc] - m) * r, gs[c0 + cc], bsh[c0 + cc]);
        h2[e] = fbf(0.5f * xn * (1.f + erff(xn * 0.70710678118f)));
      }
      pk[jj] = (u32)h2[0] | ((u32)h2[1] << 16);
    }
    *(uint4*)&Ge[p * 136 + c0] = make_uint4(pk[0], pk[1], pk[2], pk[3]);
  }
  __syncthreads();
  // wave 0: 16x16x128 offset projection (4 MFMA) + store
  if (tid < 64) {
    int lane = tid;
    int mrow = lane & 15, quad = lane >> 4;
    f32x4 acc0 = (f32x4){0.f, 0.f, 0.f, 0.f};
#pragma unroll
    for (int kb = 0; kb < 4; ++kb) {
      int cb = (kb << 5) + (quad << 3);
      bf16x8 af = ld_bf8(&Wos[mrow * 136 + cb]);
      bf16x8 bfr = ld_bf8(&Ge[mrow * 136 + cb]);
      acc0 = __builtin_amdgcn_mfma_f32_16x16x32_bf16(af, bfr, acc0, 0, 0, 0);
    }
    // D: col(lane&15)=pixel, row(quad*4+reg)=o; o pairs (2g,2g+1)
    int l = (h << 7) + ((s & 7) << 4) + mrow;
    float2* po = (float2*)offs;
    int o0 = quad << 2;
    po[(((long)((b << 3) + (quad << 1))) << 14) + l] =
        make_float2(acc0[0] + offb[o0], acc0[1] + offb[o0 + 1]);
    po[(((long)((b << 3) + (quad << 1) + 1)) << 14) + l] =
        make_float2(acc0[2] + offb[o0 + 2], acc0[3] + offb[o0 + 3]);
  }
}

// ---- K4: DCN gather + x_proj + dt_w; 64-pixel tile, 512 thr ----------------
// v4: group-blocked xc layout -> each bilinear x-pair is one contiguous 64B
// region (4 uint4 loads covering 2 line-regions instead of 4).  Boundary
// clamp handled by register select: when x1c==x0c the second tap reuses the
// first 32B (weight already encodes validity; every consumed byte is valid
// xc data, so no NaN exposure from the speculative +32B read; the read stays
// inside the workspace).
__global__ __launch_bounds__(512, 8) void k_dcn(const u16* __restrict__ xc,
                                                const float* __restrict__ offs,
                                                const float* __restrict__ xpw,
                                                const float* __restrict__ dtw,
                                                u16* __restrict__ xs,
                                                u16* __restrict__ dts,
                                                float* __restrict__ Bsb,
                                                float* __restrict__ Csb) {
  __shared__ __align__(16) u16 xds_bf[64 * 132];  // [p][c] bf16, stride 132
  __shared__ float part[64 * 81];                 // [p][8r+gg], stride 81 (conflict-free)
  __shared__ __align__(16) float xdblT[8 * 64];   // [r][p] (dt ranks only)
  int tid = threadIdx.x;
  int blk = blockIdx.x;
  int b = blk >> 8;
  int l0 = (blk & 255) << 6;
  int p = tid & 63, gg = tid >> 6;
  int l = l0 + p, hh = l >> 7, ww = l & 127;
  float2 off = ((const float2*)offs)[(((long)((b << 3) + gg)) << 14) + l];
  float px = (float)ww + off.x, py = (float)hh + off.y;
  float x0f = floorf(px), y0f = floorf(py);
  float wx = px - x0f, wy = py - y0f;
  int ix = (int)x0f, iy = (int)y0f;
  int x0c = min(max(ix, 0), 127), x1c = min(max(ix + 1, 0), 127);
  int y0c = min(max(iy, 0), 127), y1c = min(max(iy + 1, 0), 127);
  float vx0 = ((unsigned)ix < 128u) ? 1.f : 0.f;
  float vx1 = ((unsigned)(ix + 1) < 128u) ? 1.f : 0.f;
  float vy0 = ((unsigned)iy < 128u) ? 1.f : 0.f;
  float vy1 = ((unsigned)(iy + 1) < 128u) ? 1.f : 0.f;
  float wt4[4] = {(1.f - wy) * (1.f - wx) * vy0 * vx0,
                  (1.f - wy) * wx * vy0 * vx1,
                  wy * (1.f - wx) * vy1 * vx0,
                  wy * wx * vy1 * vx1};
  const u16* bbase = xc + (((long)(b << 3) + gg) << 18);
  const u16* r0p = bbase + ((((y0c << 7) + x0c)) << 4);
  const u16* r1p = bbase + ((((y1c << 7) + x0c)) << 4);
  // 64B per row-pair: q0,q1 = tap(x0c); q2,q3 = tap(x0c+1) (speculative)
  uint4 q0 = ((const uint4*)r0p)[0];
  uint4 q1 = ((const uint4*)r0p)[1];
  uint4 q2 = ((const uint4*)r0p)[2];
  uint4 q3 = ((const uint4*)r0p)[3];
  uint4 q4 = ((const uint4*)r1p)[0];
  uint4 q5 = ((const uint4*)r1p)[1];
  uint4 q6 = ((const uint4*)r1p)[2];
  uint4 q7 = ((const uint4*)r1p)[3];
  bool adj = (x1c != x0c);
  u32 t0[8] = {q0.x, q0.y, q0.z, q0.w, q1.x, q1.y, q1.z, q1.w};
  u32 t1[8] = {adj ? q2.x : q0.x, adj ? q2.y : q0.y, adj ? q2.z : q0.z, adj ? q2.w : q0.w,
               adj ? q3.x : q1.x, adj ? q3.y : q1.y, adj ? q3.z : q1.z, adj ? q3.w : q1.w};
  u32 t2[8] = {q4.x, q4.y, q4.z, q4.w, q5.x, q5.y, q5.z, q5.w};
  u32 t3[8] = {adj ? q6.x : q4.x, adj ? q6.y : q4.y, adj ? q6.z : q4.z, adj ? q6.w : q4.w,
               adj ? q7.x : q5.x, adj ? q7.y : q5.y, adj ? q7.z : q5.z, adj ? q7.w : q5.w};
  float acc[16];
#pragma unroll
  for (int ch = 0; ch < 16; ++ch) acc[ch] = 0.f;
#pragma unroll
  for (int ch = 0; ch < 16; ++ch) {
    float v0 = (ch & 1) ? hi16(t0[ch >> 1]) : lo16(t0[ch >> 1]);
    float v1 = (ch & 1) ? hi16(t1[ch >> 1]) : lo16(t1[ch >> 1]);
    float v2 = (ch & 1) ? hi16(t2[ch >> 1]) : lo16(t2[ch >> 1]);
    float v3 = (ch & 1) ? hi16(t3[ch >> 1]) : lo16(t3[ch >> 1]);
    float a = fmaf(wt4[0], v0, wt4[1] * v1);
    a = fmaf(wt4[2], v2, a);
    acc[ch] = fmaf(wt4[3], v3, a);
  }
  // bf16 transpose tile (bit-identical to xs output values)
  {
    u32 pk[8];
#pragma unroll
    for (int j = 0; j < 8; ++j)
      pk[j] = (u32)fbf(acc[2 * j]) | ((u32)fbf(acc[2 * j + 1]) << 16);
    u16* row = &xds_bf[p * 132 + (gg << 4)];
#pragma unroll
    for (int q = 0; q < 4; ++q)
      *(uint2*)(row + (q << 2)) = make_uint2(pk[2 * q], pk[2 * q + 1]);
  }
  // x_proj partials from registers; weights via wave-uniform s_load path
  {
    int ggu = __builtin_amdgcn_readfirstlane(gg);
    const float* wb = xpw + (ggu << 4);
    int pbase = p * 81 + gg;
#pragma unroll
    for (int r = 0; r < 10; ++r) {
      const float* wr = wb + (r << 7);
      float s = 0.f;
#pragma unroll
      for (int ch = 0; ch < 16; ++ch) s = fmaf(wr[ch], acc[ch], s);
      part[pbase + (r << 3)] = s;
    }
  }
  __syncthreads();
  // reduce partials over the 8 channel groups: 640 tasks (r, p2)
  {
    int task = tid;
#pragma unroll
    for (int pass = 0; pass < 2; ++pass, task += 512) {
      if (task < 640) {
        int r = task >> 6, p2 = task & 63;
        const float* pp = &part[p2 * 81 + (r << 3)];
        float s = ((pp[0] + pp[1]) + (pp[2] + pp[3])) + ((pp[4] + pp[5]) + (pp[6] + pp[7]));
        if (r < 8) xdblT[(r << 6) + p2] = s;
        else if (r == 8) Bsb[((long)b << 14) + l0 + p2] = s;
        else Csb[((long)b << 14) + l0 + p2] = s;
      }
    }
  }
  // xs pack/store: 1024 tasks (128 c x 8 l-octets); 16B stores, full lines
#pragma unroll
  for (int it = 0; it < 2; ++it) {
    int task = (it << 9) + tid;
    int cc = task >> 3, t = task & 7;
    u32 pk[4];
#pragma unroll
    for (int jj = 0; jj < 4; ++jj) {
      u16 a0 = xds_bf[((t << 3) + 2 * jj + 0) * 132 + cc];
      u16 a1 = xds_bf[((t << 3) + 2 * jj + 1) * 132 + cc];
      pk[jj] = (u32)a0 | ((u32)a1 << 16);
    }
    *(uint4*)&xs[(((long)(b << 7) + cc) << 14) + l0 + (t << 3)] =
        make_uint4(pk[0], pk[1], pk[2], pk[3]);
  }
  __syncthreads();  // xdblT visible
  // dts: thread handles (dd, t) and (dd+64, t); dtw rows from global (cached)
  {
    int dd = tid >> 3, t = tid & 7;
    float4 a0 = *(const float4*)&dtw[dd << 3];
    float4 a1 = *(const float4*)&dtw[(dd << 3) + 4];
    float4 b0 = *(const float4*)&dtw[(dd + 64) << 3];
    float4 b1 = *(const float4*)&dtw[((dd + 64) << 3) + 4];
    float wr0[8] = {a0.x, a0.y, a0.z, a0.w, a1.x, a1.y, a1.z, a1.w};
    float wr1[8] = {b0.x, b0.y, b0.z, b0.w, b1.x, b1.y, b1.z, b1.w};
    float y0[8], y1[8];
#pragma unroll
    for (int j = 0; j < 8; ++j) { y0[j] = 0.f; y1[j] = 0.f; }
#pragma unroll
    for (int rr = 0; rr < 8; ++rr) {
      float w0 = wr0[rr], w1 = wr1[rr];
      const float* xr = &xdblT[(rr << 6) + (t << 3)];
      float4 xa = *(const float4*)xr;
      float4 xb = *(const float4*)(xr + 4);
      float xv[8] = {xa.x, xa.y, xa.z, xa.w, xb.x, xb.y, xb.z, xb.w};
#pragma unroll
      for (int j = 0; j < 8; ++j) {
        y0[j] = fmaf(w0, xv[j], y0[j]);
        y1[j] = fmaf(w1, xv[j], y1[j]);
      }
    }
    u32 pk0[4], pk1[4];
#pragma unroll
    for (int jj = 0; jj < 4; ++jj) {
      pk0[jj] = (u32)fbf(y0[2 * jj]) | ((u32)fbf(y0[2 * jj + 1]) << 16);
      pk1[jj] = (u32)fbf(y1[2 * jj]) | ((u32)fbf(y1[2 * jj + 1]) << 16);
    }
    *(uint4*)&dts[(((long)(b << 7) + dd) << 14) + l0 + (t << 3)] =
        make_uint4(pk0[0], pk0[1], pk0[2], pk0[3]);
    *(uint4*)&dts[(((long)(b << 7) + dd + 64) << 14) + l0 + (t << 3)] =
        make_uint4(pk1[0], pk1[1], pk1[2], pk1[3]);
  }
}

// ---- K5: selective scan, shfl-based block scan, cheap softplus -------------
__global__ __launch_bounds__(1024) void k_scan(u16* __restrict__ xy,
                                               const u16* __restrict__ dts16,
                                               const float* __restrict__ Bsb,
                                               const float* __restrict__ Csb,
                                               const float* __restrict__ A_logs,
                                               const float* __restrict__ Dsv,
                                               const float* __restrict__ dtbv) {
  __shared__ float swp[16], swe[16];
  int bd = blockIdx.x;
  int b = bd >> 7, d = bd & 127;
  float Ad = -__expf(A_logs[d]);
  float dtb = dtbv[d];
  float Dd = Dsv[d];
  int t = threadIdx.x;
  int lane = t & 63, wid = t >> 6;
  long base = ((long)bd << 14) + (t << 4);
  long bb = ((long)b << 14) + (t << 4);
  const uint4* pz4 = (const uint4*)(dts16 + base);
  const uint4* px4 = (const uint4*)(xy + base);
  const float4* pB = (const float4*)(Bsb + bb);
  const float4* pC = (const float4*)(Csb + bb);
  uint4 zA = pz4[0], zB = pz4[1];
  uint4 xA = px4[0], xB = px4[1];
  u32 zw[8] = {zA.x, zA.y, zA.z, zA.w, zB.x, zB.y, zB.z, zB.w};
  u32 xw[8] = {xA.x, xA.y, xA.z, xA.w, xB.x, xB.y, xB.z, xB.w};
  float E = 0.f, P = 1.f;
#pragma unroll
  for (int q = 0; q < 4; ++q) {
    float4 B4 = pB[q];
    float Bq[4] = {B4.x, B4.y, B4.z, B4.w};
#pragma unroll
    for (int j = 0; j < 4; ++j) {
      int k = (q << 2) + j;
      float z = (k & 1) ? hi16(zw[k >> 1]) : lo16(zw[k >> 1]);
      float xv = (k & 1) ? hi16(xw[k >> 1]) : lo16(xw[k >> 1]);
      float delta = softplusf(z + dtb);
      float a = __expf(delta * Ad);
      E = fmaf(a, E, delta * Bq[j] * xv);
      P *= a;
    }
  }
#pragma unroll
  for (int off = 1; off < 64; off <<= 1) {
    float Pp = __shfl_up(P, off);
    float Ep = __shfl_up(E, off);
    if (lane >= off) { E = fmaf(P, Ep, E); P *= Pp; }
  }
  if (lane == 63) { swp[wid] = P; swe[wid] = E; }
  __syncthreads();
  if (t < 16) {
    float p2 = swp[t], e2 = swe[t];
#pragma unroll
    for (int off = 1; off < 16; off <<= 1) {
      float pp = __shfl_up(p2, off);
      float ee = __shfl_up(e2, off);
      if (t >= off) { e2 = fmaf(p2, ee, e2); p2 *= pp; }
    }
    swp[t] = p2; swe[t] = e2;
  }
  __syncthreads();
  float hw = (wid == 0) ? 0.f : swe[wid - 1];
  float Pex = __shfl_up(P, 1);
  float Eex = __shfl_up(E, 1);
  if (lane == 0) { Pex = 1.f; Eex = 0.f; }
  float h = fmaf(Pex, hw, Eex);
  u32 ypk[8];
#pragma unroll
  for (int q = 0; q < 4; ++q) {
    float4 B4 = pB[q];
    float4 C4 = pC[q];
    float Bq[4] = {B4.x, B4.y, B4.z, B4.w};
    float Cq[4] = {C4.x, C4.y, C4.z, C4.w};
#pragma unroll
    for (int j = 0; j < 4; ++j) {
      int k = (q << 2) + j;
      float z = (k & 1) ? hi16(zw[k >> 1]) : lo16(zw[k >> 1]);
      float xv = (k & 1) ? hi16(xw[k >> 1]) : lo16(xw[k >> 1]);
      float delta = softplusf(z + dtb);
      float a = __expf(delta * Ad);
      h = fmaf(a, h, delta * Bq[j] * xv);
      u16 yb = fbf(fmaf(Dd, xv, h * Cq[j]));
      if ((k & 1) == 0) ypk[k >> 1] = yb; else ypk[k >> 1] |= (u32)yb << 16;
    }
  }
  uint4* py = (uint4*)(xy + base);
  py[0] = make_uint4(ypk[0], ypk[1], ypk[2], ypk[3]);
  py[1] = make_uint4(ypk[4], ypk[5], ypk[6], ypk[7]);
}

// ---- K7: out_proj MFMA GEMM + fused LN epilogue (f32 out, [b,o,l]) ---------
__global__ __launch_bounds__(256) void k_outproj(const u16* __restrict__ y,
                                                 const float* __restrict__ W2,
                                                 const float* __restrict__ g,
                                                 const float* __restrict__ s12,
                                                 float* __restrict__ out) {
  __shared__ __align__(16) u16 Ws[128 * 136];  // [o][c] bf16 of W2*gamma
  __shared__ __align__(16) u16 Ys[64 * 136];   // [l][c] bf16 (y^T tile)
  __shared__ float ps[4][64], pss[4][64];
  __shared__ float mean_s[64], rstd_s[64];
  int tid = threadIdx.x;
  int b = blockIdx.x >> 8;
  int l0 = (blockIdx.x & 255) << 6;
  for (int i = 0; i < 16; ++i) {
    int idx = (i << 8) + tid;
    int o = idx >> 5, c4 = (idx & 31) << 2;
    float4 w4 = *(const float4*)&W2[(o << 7) + c4];
    ushort4 s;
    s.x = fbf(w4.x * g[c4]);     s.y = fbf(w4.y * g[c4 + 1]);
    s.z = fbf(w4.z * g[c4 + 2]); s.w = fbf(w4.w * g[c4 + 3]);
    *(ushort4*)&Ws[o * 136 + c4] = s;
  }
  for (int i = 0; i < 4; ++i) {
    int idx = (i << 8) + tid;
    int c = idx >> 3, lq = (idx & 7) << 3;
    uint4 v = *(const uint4*)&y[(((long)(b << 7) + c) << 14) + l0 + lq];
    u32 vv[4] = {v.x, v.y, v.z, v.w};
#pragma unroll
    for (int r = 0; r < 8; ++r)
      Ys[(lq + r) * 136 + c] = (u16)((r & 1) ? (vv[r >> 1] >> 16) : (vv[r >> 1] & 0xffffu));
  }
  __syncthreads();
  {
    int l = tid & 63, q = tid >> 6;
    const u16* row = &Ys[l * 136 + (q << 5)];
    float s = 0.f, ss = 0.f;
#pragma unroll 8
    for (int c = 0; c < 32; ++c) { float v = bfu(row[c]); s += v; ss = fmaf(v, v, ss); }
    ps[q][l] = s; pss[q][l] = ss;
  }
  __syncthreads();
  if (tid < 64) {
    float s = ps[0][tid] + ps[1][tid] + ps[2][tid] + ps[3][tid];
    float ss = pss[0][tid] + pss[1][tid] + pss[2][tid] + pss[3][tid];
    float m = s * (1.f / 128.f);
    mean_s[tid] = m;
    rstd_s[tid] = rsqrtf(ss * (1.f / 128.f) - m * m + 1e-6f);
  }
  __syncthreads();
  int w = tid >> 6, lane = tid & 63;
  int mrow = lane & 15, quad = lane >> 4;
  f32x4 acc[2][4];
#pragma unroll
  for (int ot = 0; ot < 2; ++ot)
#pragma unroll
    for (int lt = 0; lt < 4; ++lt) acc[ot][lt] = (f32x4){0.f, 0.f, 0.f, 0.f};
#pragma unroll
  for (int kb = 0; kb < 4; ++kb) {
    int c0 = (kb << 5) + (quad << 3);
    bf16x8 af[2], bfr[4];
#pragma unroll
    for (int ot = 0; ot < 2; ++ot)
      af[ot] = ld_bf8(&Ws[((w << 5) + (ot << 4) + mrow) * 136 + c0]);
#pragma unroll
    for (int lt = 0; lt < 4; ++lt)
      bfr[lt] = ld_bf8(&Ys[((lt << 4) + mrow) * 136 + c0]);
#pragma unroll
    for (int ot = 0; ot < 2; ++ot)
#pragma unroll
      for (int lt = 0; lt < 4; ++lt)
        acc[ot][lt] = __builtin_amdgcn_mfma_f32_16x16x32_bf16(af[ot], bfr[lt], acc[ot][lt], 0, 0, 0);
  }
  float s1r[2][4], s2r[2][4];
#pragma unroll
  for (int ot = 0; ot < 2; ++ot)
#pragma unroll
    for (int r = 0; r < 4; ++r) {
      int o = (w << 5) + (ot << 4) + (quad << 2) + r;
      s1r[ot][r] = s12[o];
      s2r[ot][r] = s12[128 + o];
    }
#pragma unroll
  for (int ot = 0; ot < 2; ++ot)
#pragma unroll
    for (int lt = 0; lt < 4; ++lt) {
      int lcol = (lt << 4) + mrow;
      float mv = mean_s[lcol], rv = rstd_s[lcol];
      int obase = (w << 5) + (ot << 4) + (quad << 2);
#pragma unroll
      for (int r = 0; r < 4; ++r) {
        float v = fmaf(rv, acc[ot][lt][r] - mv * s2r[ot][r], s1r[ot][r]);
        out[(((long)(b << 7) + obase + r) << 14) + l0 + lcol] = v;
      }
    }
}

extern "C" void kernel_launch(void* const* d_in, const int* in_sizes, int n_in,
                              void* d_out, int out_size, void* d_ws, size_t ws_size,
                              hipStream_t stream) {
  const float* x         = (const float*)d_in[0];
  const float* in_proj_w = (const float*)d_in[1];
  const float* conv2d_w  = (const float*)d_in[2];
  const float* conv2d_b  = (const float*)d_in[3];
  const float* dw_w      = (const float*)d_in[4];
  const float* dw_b      = (const float*)d_in[5];
  const float* dw_ln_g   = (const float*)d_in[6];
  const float* dw_ln_b   = (const float*)d_in[7];
  const float* off_w     = (const float*)d_in[8];
  const float* off_b     = (const float*)d_in[9];
  const float* x_proj_w  = (const float*)d_in[10];
  const float* dt_w      = (const float*)d_in[11];
  const float* dt_b      = (const float*)d_in[12];
  const float* A_logs    = (const float*)d_in[13];
  const float* Ds        = (const float*)d_in[14];
  const float* out_ln_g  = (const float*)d_in[15];
  const float* out_ln_b  = (const float*)d_in[16];
  const float* out_proj_w= (const float*)d_in[17];
  float* out = (float*)d_out;

  u16* A  = (u16*)d_ws;            // xin_cl -> xs[b,c,l] -> y[b,c,l]
  u16* Bx = A + 8388608;           // xc group-blocked [b][g][y][x][c16]
  u16* Dd = Bx + 8388608;          // dts[b,c,l]
  float* offs  = (float*)(Dd + 8388608);  // [b][g][l] float2
  float* Bsb   = offs + 1048576;
  float* Csb   = Bsb + 65536;
  float* s12   = Csb + 65536;

  hipLaunchKernelGGL(k_inproj, dim3(1025), dim3(256), 0, stream, x, in_proj_w, A,
                     out_proj_w, out_ln_g, out_ln_b, s12);
  hipLaunchKernelGGL(k_dwconv, dim3(4096), dim3(256), 0, stream, A, conv2d_w, conv2d_b, Bx);
  hipLaunchKernelGGL(k_dwoff, dim3(4096), dim3(256), 0, stream, Bx, dw_w, dw_b,
                     dw_ln_g, dw_ln_b, off_w, off_b, offs);
  hipLaunchKernelGGL(k_dcn, dim3(1024), dim3(512), 0, stream, Bx, offs, x_proj_w, dt_w, A, Dd, Bsb, Csb);
  hipLaunchKernelGGL(k_scan, dim3(512), dim3(1024), 0, stream, A, Dd, Bsb, Csb, A_logs, Ds, dt_b);
  hipLaunchKernelGGL(k_outproj, dim3(1024), dim3(256), 0, stream, A, out_proj_w, out_ln_g, s12, out);
}

// Round 6
// 209.479 us; speedup vs baseline: 1.1208x; 1.0446x over previous
//
#include <hip/hip_runtime.h>
#include <hip/hip_bf16.h>

typedef unsigned short u16;
typedef unsigned int u32;
typedef __bf16 bf16x8 __attribute__((ext_vector_type(8)));
typedef float f32x4 __attribute__((ext_vector_type(4)));

__device__ __forceinline__ float bfu(u16 u) { return __uint_as_float(((u32)u) << 16); }
__device__ __forceinline__ u16 fbf(float f) {
  __hip_bfloat16 h = __float2bfloat16(f);
  return *reinterpret_cast<u16*>(&h);
}
__device__ __forceinline__ float softplusf(float z) {
  float t = __expf(z);
  return (z > 20.f) ? z : __logf(1.f + t);
}
__device__ __forceinline__ float lo16(u32 p) { return __uint_as_float(p << 16); }
__device__ __forceinline__ float hi16(u32 p) { return __uint_as_float(p & 0xffff0000u); }
__device__ __forceinline__ bf16x8 ld_bf8(const u16* p) {
  union { uint4 u; bf16x8 v; } c;
  c.u = *(const uint4*)p;
  return c.v;
}

// xc layout is GROUP-BLOCKED channels-last: [b][g][y][x][c16] (u16 units:
// base + ((b*8+g)<<18) + ((y*128+x)<<4) + c).

// ---- K1: in_proj MFMA GEMM + (block 1024) k_sums fold ----------------------
__global__ __launch_bounds__(256) void k_inproj(const float* __restrict__ X,
                                                const float* __restrict__ W,
                                                u16* __restrict__ out,
                                                const float* __restrict__ W2,
                                                const float* __restrict__ gO,
                                                const float* __restrict__ bO,
                                                float* __restrict__ s12) {
  __shared__ __align__(16) u16 Ws[128 * 136];  // [o][c] bf16
  __shared__ __align__(16) u16 Xs[64 * 136];   // [l][c] bf16 (X^T tile)
  int tid = threadIdx.x;
  if (blockIdx.x == 1024) {  // folded k_sums
    if (tid < 128) {
      int o = tid;
      float s1 = 0.f, s2 = 0.f;
      for (int c = 0; c < 128; ++c) {
        float w = W2[(o << 7) + c];
        s1 = fmaf(w, bO[c], s1);
        s2 = fmaf(w, gO[c], s2);
      }
      s12[o] = s1;
      s12[128 + o] = s2;
    }
    return;
  }
  int b = blockIdx.x >> 8;
  int l0 = (blockIdx.x & 255) << 6;
  for (int i = 0; i < 16; ++i) {
    int idx = (i << 8) + tid;
    int o = idx >> 5, c4 = (idx & 31) << 2;
    float4 w4 = *(const float4*)&W[(o << 7) + c4];
    ushort4 s;
    s.x = fbf(w4.x); s.y = fbf(w4.y); s.z = fbf(w4.z); s.w = fbf(w4.w);
    *(ushort4*)&Ws[o * 136 + c4] = s;
  }
  for (int i = 0; i < 8; ++i) {
    int idx = (i << 8) + tid;
    int c = idx >> 4, lq = (idx & 15) << 2;
    float4 x4 = *(const float4*)&X[(((long)(b << 7) + c) << 14) + l0 + lq];
    Xs[(lq + 0) * 136 + c] = fbf(x4.x);
    Xs[(lq + 1) * 136 + c] = fbf(x4.y);
    Xs[(lq + 2) * 136 + c] = fbf(x4.z);
    Xs[(lq + 3) * 136 + c] = fbf(x4.w);
  }
  __syncthreads();
  int w = tid >> 6, lane = tid & 63;
  int mrow = lane & 15, quad = lane >> 4;
  f32x4 acc[2][4];
#pragma unroll
  for (int ot = 0; ot < 2; ++ot)
#pragma unroll
    for (int lt = 0; lt < 4; ++lt) acc[ot][lt] = (f32x4){0.f, 0.f, 0.f, 0.f};
#pragma unroll
  for (int kb = 0; kb < 4; ++kb) {
    int c0 = (kb << 5) + (quad << 3);
    bf16x8 af[2], bfr[4];
#pragma unroll
    for (int ot = 0; ot < 2; ++ot)
      af[ot] = ld_bf8(&Ws[((w << 5) + (ot << 4) + mrow) * 136 + c0]);
#pragma unroll
    for (int lt = 0; lt < 4; ++lt)
      bfr[lt] = ld_bf8(&Xs[((lt << 4) + mrow) * 136 + c0]);
#pragma unroll
    for (int ot = 0; ot < 2; ++ot)
#pragma unroll
      for (int lt = 0; lt < 4; ++lt)
        acc[ot][lt] = __builtin_amdgcn_mfma_f32_16x16x32_bf16(af[ot], bfr[lt], acc[ot][lt], 0, 0, 0);
  }
#pragma unroll
  for (int ot = 0; ot < 2; ++ot)
#pragma unroll
    for (int lt = 0; lt < 4; ++lt) {
      int l = l0 + (lt << 4) + mrow;
      int o = (w << 5) + (ot << 4) + (quad << 2);
      ushort4 s;
      s.x = fbf(acc[ot][lt][0]); s.y = fbf(acc[ot][lt][1]);
      s.z = fbf(acc[ot][lt][2]); s.w = fbf(acc[ot][lt][3]);
      *(ushort4*)&out[(((long)(b << 14) + l) << 7) + o] = s;
    }
}

// ---- K2: depthwise 3x3 conv + SiLU; in [l][c128], out group-blocked --------
__global__ __launch_bounds__(256) void k_dwconv(const u16* __restrict__ in,
                                                const float* __restrict__ w9,
                                                const float* __restrict__ bias,
                                                u16* __restrict__ out) {
  __shared__ float wsT[9][128];
  __shared__ float bs[128];
  int tid = threadIdx.x;
  for (int i = 0; i < 5; ++i) {
    int lin = (i << 8) + tid;
    if (lin < 1152) { int c = lin / 9, k = lin - 9 * c; wsT[k][c] = w9[lin]; }
  }
  if (tid < 128) bs[tid] = bias[tid];
  __syncthreads();
  int blk = blockIdx.x;
  int b = blk >> 10;
  int s = blk & 1023;
  int h = s >> 3;
  int w = ((s & 7) << 4) + (tid >> 4);
  int c0 = (tid & 15) << 3;
  const u16* bbase = in + ((long)b << 21);
  float acc[8];
  {
    float4 b0 = *(const float4*)&bs[c0];
    float4 b1 = *(const float4*)&bs[c0 + 4];
    acc[0] = b0.x; acc[1] = b0.y; acc[2] = b0.z; acc[3] = b0.w;
    acc[4] = b1.x; acc[5] = b1.y; acc[6] = b1.z; acc[7] = b1.w;
  }
#pragma unroll
  for (int ky = -1; ky <= 1; ++ky) {
    int y = h + ky;
    if ((unsigned)y >= 128u) continue;
#pragma unroll
    for (int kx = -1; kx <= 1; ++kx) {
      int x = w + kx;
      if ((unsigned)x >= 128u) continue;
      int k = (ky + 1) * 3 + (kx + 1);
      uint4 v = *(const uint4*)(bbase + ((((y << 7) + x)) << 7) + c0);
      float4 w0 = *(const float4*)&wsT[k][c0];
      float4 w1 = *(const float4*)&wsT[k][c0 + 4];
      u32 vv[4] = {v.x, v.y, v.z, v.w};
      float wf[8] = {w0.x, w0.y, w0.z, w0.w, w1.x, w1.y, w1.z, w1.w};
#pragma unroll
      for (int cc = 0; cc < 8; ++cc) {
        float xv = (cc & 1) ? hi16(vv[cc >> 1]) : lo16(vv[cc >> 1]);
        acc[cc] = fmaf(wf[cc], xv, acc[cc]);
      }
    }
  }
#pragma unroll
  for (int cc = 0; cc < 8; ++cc) acc[cc] = acc[cc] / (1.f + __expf(-acc[cc]));
  int g4 = c0 >> 4, sub = c0 & 15;
  uint4 pkst;
  pkst.x = (u32)fbf(acc[0]) | ((u32)fbf(acc[1]) << 16);
  pkst.y = (u32)fbf(acc[2]) | ((u32)fbf(acc[3]) << 16);
  pkst.z = (u32)fbf(acc[4]) | ((u32)fbf(acc[5]) << 16);
  pkst.w = (u32)fbf(acc[6]) | ((u32)fbf(acc[7]) << 16);
  u16* po = out + (((long)(b << 3) + g4) << 18) + ((((h << 7) + w)) << 4) + sub;
  *(uint4*)po = pkst;
}

// ---- K3: FUSED dwconv#2 + LN + GELU + offset MFMA + DCN gather + x_proj ----
// 64-pixel tile (one half-row), 512 threads.  Phase A (p2=tid>>3, g2=tid&7):
// dwconv2 taps on group-blocked Bx, LN via 8-lane shfl reduce, GELU -> Ge
// (bf16 LDS).  Phase B (waves 0-3): verified 16x16x128 offset-projection
// MFMA fragments -> offsets to 4KB LDS.  Phase C (p=tid&63, gg=tid>>6):
// v5's wave-coherent gather + x_proj + xs/dts stores, unchanged.
// LDS phase-overlay: Ge/wsT2/Wos union with later 'part' buffer (~50KB
// total -> 3 blocks/CU).
__global__ __launch_bounds__(512, 6) void k_dcnoff(const u16* __restrict__ xc,
                                                   const float* __restrict__ w9,
                                                   const float* __restrict__ bias,
                                                   const float* __restrict__ g,
                                                   const float* __restrict__ bt,
                                                   const float* __restrict__ offw,
                                                   const float* __restrict__ offb,
                                                   const float* __restrict__ xpw,
                                                   const float* __restrict__ dtw,
                                                   u16* __restrict__ xs,
                                                   u16* __restrict__ dts,
                                                   float* __restrict__ Bsb,
                                                   float* __restrict__ Csb) {
  // overlay region: [0,17408) Ge (64x136 bf16); [17408,22016) wsT2 (9x128 f32);
  // [22016,26368) Wos (16x136 bf16).  'part' (64*81 f32 = 20736B) overlays
  // Ge + head of wsT2 AFTER both are dead (barrier-separated).
  __shared__ __align__(16) char uni[26368];
  __shared__ float bs[128], gs[128], bsh[128];
  __shared__ __align__(16) u16 xds_bf[64 * 132];  // [p][c] bf16
  __shared__ __align__(16) float xdblT[8 * 64];   // [r][p]
  __shared__ __align__(16) float2 offsL[64 * 8];  // [p][g]
  u16* Ge = (u16*)uni;
  float* wsT2 = (float*)(uni + 17408);
  u16* Wos = (u16*)(uni + 22016);
  float* part = (float*)uni;
  int tid = threadIdx.x;
  // stage weights
  for (int i = 0; i < 3; ++i) {
    int lin = (i << 9) + tid;
    if (lin < 1152) wsT2[lin] = w9[lin];  // [c*9+k] -> store linear, index below
  }
  if (tid < 128) { bs[tid] = bias[tid]; gs[tid] = g[tid]; bsh[tid] = bt[tid]; }
  for (int i = 0; i < 4; ++i) {
    int idx = (i << 9) + tid;  // 2048 = 16o x 128c
    int o = idx >> 7, c = idx & 127;
    Wos[o * 136 + c] = fbf(offw[idx]);
  }
  int blk = blockIdx.x;
  int b = blk >> 8;
  int l0 = (blk & 255) << 6;
  __syncthreads();
  // ---- Phase A: dwconv2 + LN + GELU ----
  {
    int p2 = tid >> 3, g2 = tid & 7;
    int l = l0 + p2, hh = l >> 7, ww = l & 127;
    const u16* bb2 = xc + (((long)(b << 3) + g2) << 18);
    float acc[16];
#pragma unroll
    for (int cc = 0; cc < 16; ++cc) acc[cc] = bs[(g2 << 4) + cc];
#pragma unroll
    for (int ky = -1; ky <= 1; ++ky) {
      int y = hh + ky;
      if ((unsigned)y >= 128u) continue;
#pragma unroll
      for (int kx = -1; kx <= 1; ++kx) {
        int x = ww + kx;
        if ((unsigned)x >= 128u) continue;
        int k = (ky + 1) * 3 + (kx + 1);
        const u16* tp = bb2 + ((((y << 7) + x)) << 4);
        uint4 v0 = *(const uint4*)tp;
        uint4 v1 = *(const uint4*)(tp + 8);
        u32 vv[8] = {v0.x, v0.y, v0.z, v0.w, v1.x, v1.y, v1.z, v1.w};
#pragma unroll
        for (int cc = 0; cc < 16; ++cc) {
          float wv = wsT2[((g2 << 4) + cc) * 9 + k];
          float xv = (cc & 1) ? hi16(vv[cc >> 1]) : lo16(vv[cc >> 1]);
          acc[cc] = fmaf(wv, xv, acc[cc]);
        }
      }
    }
    // LN stats: partial over 16 ch, reduce across the 8 lanes sharing pixel
    float sum = 0.f, ssum = 0.f;
#pragma unroll
    for (int cc = 0; cc < 16; ++cc) { sum += acc[cc]; ssum = fmaf(acc[cc], acc[cc], ssum); }
#pragma unroll
    for (int off = 1; off < 8; off <<= 1) {
      sum += __shfl_xor(sum, off);
      ssum += __shfl_xor(ssum, off);
    }
    float m = sum * (1.f / 128.f);
    float r = rsqrtf(ssum * (1.f / 128.f) - m * m + 1e-6f);
    // LN + GELU -> bf16 -> Ge[p2][g2*16..+15]
    u32 pk[8];
#pragma unroll
    for (int jj = 0; jj < 8; ++jj) {
      u16 h2[2];
#pragma unroll
      for (int e = 0; e < 2; ++e) {
        int cc = 2 * jj + e;
        float xn = fmaf((acc[cc] - m) * r, gs[(g2 << 4) + cc], bsh[(g2 << 4) + cc]);
        h2[e] = fbf(0.5f * xn * (1.f + erff(xn * 0.70710678118f)));
      }
      pk[jj] = (u32)h2[0] | ((u32)h2[1] << 16);
    }
    u16* row = &Ge[p2 * 136 + (g2 << 4)];
    *(uint4*)row = make_uint4(pk[0], pk[1], pk[2], pk[3]);
    *(uint4*)(row + 8) = make_uint4(pk[4], pk[5], pk[6], pk[7]);
  }
  __syncthreads();
  // ---- Phase B: offset projection (waves 0-3, 16 pixels each) ----
  {
    int w = tid >> 6, lane = tid & 63;
    if (w < 4) {
      int mrow = lane & 15, quad = lane >> 4;
      f32x4 acc0 = (f32x4){0.f, 0.f, 0.f, 0.f};
#pragma unroll
      for (int kb = 0; kb < 4; ++kb) {
        int cb = (kb << 5) + (quad << 3);
        bf16x8 af = ld_bf8(&Wos[mrow * 136 + cb]);
        bf16x8 bfr = ld_bf8(&Ge[((w << 4) + mrow) * 136 + cb]);
        acc0 = __builtin_amdgcn_mfma_f32_16x16x32_bf16(af, bfr, acc0, 0, 0, 0);
      }
      // D: col(lane&15)=pixel, row(quad*4+reg)=o; groups g0=2q (x,y), g1=2q+1
      int p = (w << 4) + mrow;
      int o0 = quad << 2;
      offsL[(p << 3) + (quad << 1)] = make_float2(acc0[0] + offb[o0], acc0[1] + offb[o0 + 1]);
      offsL[(p << 3) + (quad << 1) + 1] = make_float2(acc0[2] + offb[o0 + 2], acc0[3] + offb[o0 + 3]);
    }
  }
  __syncthreads();
  // ---- Phase C: DCN gather + x_proj + stores (v5 structure) ----
  int p = tid & 63, gg = tid >> 6;
  int l = l0 + p, hh = l >> 7, ww = l & 127;
  float2 off = offsL[(p << 3) + gg];
  float px = (float)ww + off.x, py = (float)hh + off.y;
  float x0f = floorf(px), y0f = floorf(py);
  float wx = px - x0f, wy = py - y0f;
  int ix = (int)x0f, iy = (int)y0f;
  int x0c = min(max(ix, 0), 127), x1c = min(max(ix + 1, 0), 127);
  int y0c = min(max(iy, 0), 127), y1c = min(max(iy + 1, 0), 127);
  float vx0 = ((unsigned)ix < 128u) ? 1.f : 0.f;
  float vx1 = ((unsigned)(ix + 1) < 128u) ? 1.f : 0.f;
  float vy0 = ((unsigned)iy < 128u) ? 1.f : 0.f;
  float vy1 = ((unsigned)(iy + 1) < 128u) ? 1.f : 0.f;
  float wt4[4] = {(1.f - wy) * (1.f - wx) * vy0 * vx0,
                  (1.f - wy) * wx * vy0 * vx1,
                  wy * (1.f - wx) * vy1 * vx0,
                  wy * wx * vy1 * vx1};
  const u16* bbase = xc + (((long)(b << 3) + gg) << 18);
  const u16* r0p = bbase + ((((y0c << 7) + x0c)) << 4);
  const u16* r1p = bbase + ((((y1c << 7) + x0c)) << 4);
  uint4 q0 = ((const uint4*)r0p)[0];
  uint4 q1 = ((const uint4*)r0p)[1];
  uint4 q2 = ((const uint4*)r0p)[2];
  uint4 q3 = ((const uint4*)r0p)[3];
  uint4 q4 = ((const uint4*)r1p)[0];
  uint4 q5 = ((const uint4*)r1p)[1];
  uint4 q6 = ((const uint4*)r1p)[2];
  uint4 q7 = ((const uint4*)r1p)[3];
  bool adj = (x1c != x0c);
  u32 t0[8] = {q0.x, q0.y, q0.z, q0.w, q1.x, q1.y, q1.z, q1.w};
  u32 t1[8] = {adj ? q2.x : q0.x, adj ? q2.y : q0.y, adj ? q2.z : q0.z, adj ? q2.w : q0.w,
               adj ? q3.x : q1.x, adj ? q3.y : q1.y, adj ? q3.z : q1.z, adj ? q3.w : q1.w};
  u32 t2[8] = {q4.x, q4.y, q4.z, q4.w, q5.x, q5.y, q5.z, q5.w};
  u32 t3[8] = {adj ? q6.x : q4.x, adj ? q6.y : q4.y, adj ? q6.z : q4.z, adj ? q6.w : q4.w,
               adj ? q7.x : q5.x, adj ? q7.y : q5.y, adj ? q7.z : q5.z, adj ? q7.w : q5.w};
  float acc[16];
#pragma unroll
  for (int ch = 0; ch < 16; ++ch) {
    float v0 = (ch & 1) ? hi16(t0[ch >> 1]) : lo16(t0[ch >> 1]);
    float v1 = (ch & 1) ? hi16(t1[ch >> 1]) : lo16(t1[ch >> 1]);
    float v2 = (ch & 1) ? hi16(t2[ch >> 1]) : lo16(t2[ch >> 1]);
    float v3 = (ch & 1) ? hi16(t3[ch >> 1]) : lo16(t3[ch >> 1]);
    float a = fmaf(wt4[0], v0, wt4[1] * v1);
    a = fmaf(wt4[2], v2, a);
    acc[ch] = fmaf(wt4[3], v3, a);
  }
  // xds_bf write must not race with 'part' overlay readers/writers; it is a
  // separate static buffer, safe.
  {
    u32 pk[8];
#pragma unroll
    for (int j = 0; j < 8; ++j)
      pk[j] = (u32)fbf(acc[2 * j]) | ((u32)fbf(acc[2 * j + 1]) << 16);
    u16* row = &xds_bf[p * 132 + (gg << 4)];
#pragma unroll
    for (int q = 0; q < 4; ++q)
      *(uint2*)(row + (q << 2)) = make_uint2(pk[2 * q], pk[2 * q + 1]);
  }
  // x_proj partials (part overlays Ge/wsT2 head -- both dead since Phase B)
  {
    int ggu = __builtin_amdgcn_readfirstlane(gg);
    const float* wb = xpw + (ggu << 4);
    int pbase = p * 81 + gg;
#pragma unroll
    for (int r = 0; r < 10; ++r) {
      const float* wr = wb + (r << 7);
      float s = 0.f;
#pragma unroll
      for (int ch = 0; ch < 16; ++ch) s = fmaf(wr[ch], acc[ch], s);
      part[pbase + (r << 3)] = s;
    }
  }
  __syncthreads();
  {
    int task = tid;
#pragma unroll
    for (int pass = 0; pass < 2; ++pass, task += 512) {
      if (task < 640) {
        int r = task >> 6, p2 = task & 63;
        const float* pp = &part[p2 * 81 + (r << 3)];
        float s = ((pp[0] + pp[1]) + (pp[2] + pp[3])) + ((pp[4] + pp[5]) + (pp[6] + pp[7]));
        if (r < 8) xdblT[(r << 6) + p2] = s;
        else if (r == 8) Bsb[((long)b << 14) + l0 + p2] = s;
        else Csb[((long)b << 14) + l0 + p2] = s;
      }
    }
  }
#pragma unroll
  for (int it = 0; it < 2; ++it) {
    int task = (it << 9) + tid;
    int cc = task >> 3, t = task & 7;
    u32 pk[4];
#pragma unroll
    for (int jj = 0; jj < 4; ++jj) {
      u16 a0 = xds_bf[((t << 3) + 2 * jj + 0) * 132 + cc];
      u16 a1 = xds_bf[((t << 3) + 2 * jj + 1) * 132 + cc];
      pk[jj] = (u32)a0 | ((u32)a1 << 16);
    }
    *(uint4*)&xs[(((long)(b << 7) + cc) << 14) + l0 + (t << 3)] =
        make_uint4(pk[0], pk[1], pk[2], pk[3]);
  }
  __syncthreads();  // xdblT visible
  {
    int dd = tid >> 3, t = tid & 7;
    float4 a0 = *(const float4*)&dtw[dd << 3];
    float4 a1 = *(const float4*)&dtw[(dd << 3) + 4];
    float4 b0 = *(const float4*)&dtw[(dd + 64) << 3];
    float4 b1 = *(const float4*)&dtw[((dd + 64) << 3) + 4];
    float wr0[8] = {a0.x, a0.y, a0.z, a0.w, a1.x, a1.y, a1.z, a1.w};
    float wr1[8] = {b0.x, b0.y, b0.z, b0.w, b1.x, b1.y, b1.z, b1.w};
    float y0[8], y1[8];
#pragma unroll
    for (int j = 0; j < 8; ++j) { y0[j] = 0.f; y1[j] = 0.f; }
#pragma unroll
    for (int rr = 0; rr < 8; ++rr) {
      float w0 = wr0[rr], w1 = wr1[rr];
      const float* xr = &xdblT[(rr << 6) + (t << 3)];
      float4 xa = *(const float4*)xr;
      float4 xb = *(const float4*)(xr + 4);
      float xv[8] = {xa.x, xa.y, xa.z, xa.w, xb.x, xb.y, xb.z, xb.w};
#pragma unroll
      for (int j = 0; j < 8; ++j) {
        y0[j] = fmaf(w0, xv[j], y0[j]);
        y1[j] = fmaf(w1, xv[j], y1[j]);
      }
    }
    u32 pk0[4], pk1[4];
#pragma unroll
    for (int jj = 0; jj < 4; ++jj) {
      pk0[jj] = (u32)fbf(y0[2 * jj]) | ((u32)fbf(y0[2 * jj + 1]) << 16);
      pk1[jj] = (u32)fbf(y1[2 * jj]) | ((u32)fbf(y1[2 * jj + 1]) << 16);
    }
    *(uint4*)&dts[(((long)(b << 7) + dd) << 14) + l0 + (t << 3)] =
        make_uint4(pk0[0], pk0[1], pk0[2], pk0[3]);
    *(uint4*)&dts[(((long)(b << 7) + dd + 64) << 14) + l0 + (t << 3)] =
        make_uint4(pk1[0], pk1[1], pk1[2], pk1[3]);
  }
}

// ---- K5: selective scan, shfl-based block scan, cheap softplus -------------
__global__ __launch_bounds__(1024) void k_scan(u16* __restrict__ xy,
                                               const u16* __restrict__ dts16,
                                               const float* __restrict__ Bsb,
                                               const float* __restrict__ Csb,
                                               const float* __restrict__ A_logs,
                                               const float* __restrict__ Dsv,
                                               const float* __restrict__ dtbv) {
  __shared__ float swp[16], swe[16];
  int bd = blockIdx.x;
  int b = bd >> 7, d = bd & 127;
  float Ad = -__expf(A_logs[d]);
  float dtb = dtbv[d];
  float Dd = Dsv[d];
  int t = threadIdx.x;
  int lane = t & 63, wid = t >> 6;
  long base = ((long)bd << 14) + (t << 4);
  long bb = ((long)b << 14) + (t << 4);
  const uint4* pz4 = (const uint4*)(dts16 + base);
  const uint4* px4 = (const uint4*)(xy + base);
  const float4* pB = (const float4*)(Bsb + bb);
  const float4* pC = (const float4*)(Csb + bb);
  uint4 zA = pz4[0], zB = pz4[1];
  uint4 xA = px4[0], xB = px4[1];
  u32 zw[8] = {zA.x, zA.y, zA.z, zA.w, zB.x, zB.y, zB.z, zB.w};
  u32 xw[8] = {xA.x, xA.y, xA.z, xA.w, xB.x, xB.y, xB.z, xB.w};
  float E = 0.f, P = 1.f;
#pragma unroll
  for (int q = 0; q < 4; ++q) {
    float4 B4 = pB[q];
    float Bq[4] = {B4.x, B4.y, B4.z, B4.w};
#pragma unroll
    for (int j = 0; j < 4; ++j) {
      int k = (q << 2) + j;
      float z = (k & 1) ? hi16(zw[k >> 1]) : lo16(zw[k >> 1]);
      float xv = (k & 1) ? hi16(xw[k >> 1]) : lo16(xw[k >> 1]);
      float delta = softplusf(z + dtb);
      float a = __expf(delta * Ad);
      E = fmaf(a, E, delta * Bq[j] * xv);
      P *= a;
    }
  }
#pragma unroll
  for (int off = 1; off < 64; off <<= 1) {
    float Pp = __shfl_up(P, off);
    float Ep = __shfl_up(E, off);
    if (lane >= off) { E = fmaf(P, Ep, E); P *= Pp; }
  }
  if (lane == 63) { swp[wid] = P; swe[wid] = E; }
  __syncthreads();
  if (t < 16) {
    float p2 = swp[t], e2 = swe[t];
#pragma unroll
    for (int off = 1; off < 16; off <<= 1) {
      float pp = __shfl_up(p2, off);
      float ee = __shfl_up(e2, off);
      if (t >= off) { e2 = fmaf(p2, ee, e2); p2 *= pp; }
    }
    swp[t] = p2; swe[t] = e2;
  }
  __syncthreads();
  float hw = (wid == 0) ? 0.f : swe[wid - 1];
  float Pex = __shfl_up(P, 1);
  float Eex = __shfl_up(E, 1);
  if (lane == 0) { Pex = 1.f; Eex = 0.f; }
  float h = fmaf(Pex, hw, Eex);
  u32 ypk[8];
#pragma unroll
  for (int q = 0; q < 4; ++q) {
    float4 B4 = pB[q];
    float4 C4 = pC[q];
    float Bq[4] = {B4.x, B4.y, B4.z, B4.w};
    float Cq[4] = {C4.x, C4.y, C4.z, C4.w};
#pragma unroll
    for (int j = 0; j < 4; ++j) {
      int k = (q << 2) + j;
      float z = (k & 1) ? hi16(zw[k >> 1]) : lo16(zw[k >> 1]);
      float xv = (k & 1) ? hi16(xw[k >> 1]) : lo16(xw[k >> 1]);
      float delta = softplusf(z + dtb);
      float a = __expf(delta * Ad);
      h = fmaf(a, h, delta * Bq[j] * xv);
      u16 yb = fbf(fmaf(Dd, xv, h * Cq[j]));
      if ((k & 1) == 0) ypk[k >> 1] = yb; else ypk[k >> 1] |= (u32)yb << 16;
    }
  }
  uint4* py = (uint4*)(xy + base);
  py[0] = make_uint4(ypk[0], ypk[1], ypk[2], ypk[3]);
  py[1] = make_uint4(ypk[4], ypk[5], ypk[6], ypk[7]);
}

// ---- K7: out_proj MFMA GEMM + fused LN epilogue (f32 out, [b,o,l]) ---------
__global__ __launch_bounds__(256) void k_outproj(const u16* __restrict__ y,
                                                 const float* __restrict__ W2,
                                                 const float* __restrict__ g,
                                                 const float* __restrict__ s12,
                                                 float* __restrict__ out) {
  __shared__ __align__(16) u16 Ws[128 * 136];  // [o][c] bf16 of W2*gamma
  __shared__ __align__(16) u16 Ys[64 * 136];   // [l][c] bf16 (y^T tile)
  __shared__ float ps[4][64], pss[4][64];
  __shared__ float mean_s[64], rstd_s[64];
  int tid = threadIdx.x;
  int b = blockIdx.x >> 8;
  int l0 = (blockIdx.x & 255) << 6;
  for (int i = 0; i < 16; ++i) {
    int idx = (i << 8) + tid;
    int o = idx >> 5, c4 = (idx & 31) << 2;
    float4 w4 = *(const float4*)&W2[(o << 7) + c4];
    ushort4 s;
    s.x = fbf(w4.x * g[c4]);     s.y = fbf(w4.y * g[c4 + 1]);
    s.z = fbf(w4.z * g[c4 + 2]); s.w = fbf(w4.w * g[c4 + 3]);
    *(ushort4*)&Ws[o * 136 + c4] = s;
  }
  for (int i = 0; i < 4; ++i) {
    int idx = (i << 8) + tid;
    int c = idx >> 3, lq = (idx & 7) << 3;
    uint4 v = *(const uint4*)&y[(((long)(b << 7) + c) << 14) + l0 + lq];
    u32 vv[4] = {v.x, v.y, v.z, v.w};
#pragma unroll
    for (int r = 0; r < 8; ++r)
      Ys[(lq + r) * 136 + c] = (u16)((r & 1) ? (vv[r >> 1] >> 16) : (vv[r >> 1] & 0xffffu));
  }
  __syncthreads();
  {
    int l = tid & 63, q = tid >> 6;
    const u16* row = &Ys[l * 136 + (q << 5)];
    float s = 0.f, ss = 0.f;
#pragma unroll 8
    for (int c = 0; c < 32; ++c) { float v = bfu(row[c]); s += v; ss = fmaf(v, v, ss); }
    ps[q][l] = s; pss[q][l] = ss;
  }
  __syncthreads();
  if (tid < 64) {
    float s = ps[0][tid] + ps[1][tid] + ps[2][tid] + ps[3][tid];
    float ss = pss[0][tid] + pss[1][tid] + pss[2][tid] + pss[3][tid];
    float m = s * (1.f / 128.f);
    mean_s[tid] = m;
    rstd_s[tid] = rsqrtf(ss * (1.f / 128.f) - m * m + 1e-6f);
  }
  __syncthreads();
  int w = tid >> 6, lane = tid & 63;
  int mrow = lane & 15, quad = lane >> 4;
  f32x4 acc[2][4];
#pragma unroll
  for (int ot = 0; ot < 2; ++ot)
#pragma unroll
    for (int lt = 0; lt < 4; ++lt) acc[ot][lt] = (f32x4){0.f, 0.f, 0.f, 0.f};
#pragma unroll
  for (int kb = 0; kb < 4; ++kb) {
    int c0 = (kb << 5) + (quad << 3);
    bf16x8 af[2], bfr[4];
#pragma unroll
    for (int ot = 0; ot < 2; ++ot)
      af[ot] = ld_bf8(&Ws[((w << 5) + (ot << 4) + mrow) * 136 + c0]);
#pragma unroll
    for (int lt = 0; lt < 4; ++lt)
      bfr[lt] = ld_bf8(&Ys[((lt << 4) + mrow) * 136 + c0]);
#pragma unroll
    for (int ot = 0; ot < 2; ++ot)
#pragma unroll
      for (int lt = 0; lt < 4; ++lt)
        acc[ot][lt] = __builtin_amdgcn_mfma_f32_16x16x32_bf16(af[ot], bfr[lt], acc[ot][lt], 0, 0, 0);
  }
  float s1r[2][4], s2r[2][4];
#pragma unroll
  for (int ot = 0; ot < 2; ++ot)
#pragma unroll
    for (int r = 0; r < 4; ++r) {
      int o = (w << 5) + (ot << 4) + (quad << 2) + r;
      s1r[ot][r] = s12[o];
      s2r[ot][r] = s12[128 + o];
    }
#pragma unroll
  for (int ot = 0; ot < 2; ++ot)
#pragma unroll
    for (int lt = 0; lt < 4; ++lt) {
      int lcol = (lt << 4) + mrow;
      float mv = mean_s[lcol], rv = rstd_s[lcol];
      int obase = (w << 5) + (ot << 4) + (quad << 2);
#pragma unroll
      for (int r = 0; r < 4; ++r) {
        float v = fmaf(rv, acc[ot][lt][r] - mv * s2r[ot][r], s1r[ot][r]);
        out[(((long)(b << 7) + obase + r) << 14) + l0 + lcol] = v;
      }
    }
}

extern "C" void kernel_launch(void* const* d_in, const int* in_sizes, int n_in,
                              void* d_out, int out_size, void* d_ws, size_t ws_size,
                              hipStream_t stream) {
  const float* x         = (const float*)d_in[0];
  const float* in_proj_w = (const float*)d_in[1];
  const float* conv2d_w  = (const float*)d_in[2];
  const float* conv2d_b  = (const float*)d_in[3];
  const float* dw_w      = (const float*)d_in[4];
  const float* dw_b      = (const float*)d_in[5];
  const float* dw_ln_g   = (const float*)d_in[6];
  const float* dw_ln_b   = (const float*)d_in[7];
  const float* off_w     = (const float*)d_in[8];
  const float* off_b     = (const float*)d_in[9];
  const float* x_proj_w  = (const float*)d_in[10];
  const float* dt_w      = (const float*)d_in[11];
  const float* dt_b      = (const float*)d_in[12];
  const float* A_logs    = (const float*)d_in[13];
  const float* Ds        = (const float*)d_in[14];
  const float* out_ln_g  = (const float*)d_in[15];
  const float* out_ln_b  = (const float*)d_in[16];
  const float* out_proj_w= (const float*)d_in[17];
  float* out = (float*)d_out;

  u16* A  = (u16*)d_ws;            // xin_cl -> xs[b,c,l] -> y[b,c,l]
  u16* Bx = A + 8388608;           // xc group-blocked [b][g][y][x][c16]
  u16* Dd = Bx + 8388608;          // dts[b,c,l]
  float* Bsb   = (float*)(Dd + 8388608);
  float* Csb   = Bsb + 65536;
  float* s12   = Csb + 65536;

  hipLaunchKernelGGL(k_inproj, dim3(1025), dim3(256), 0, stream, x, in_proj_w, A,
                     out_proj_w, out_ln_g, out_ln_b, s12);
  hipLaunchKernelGGL(k_dwconv, dim3(4096), dim3(256), 0, stream, A, conv2d_w, conv2d_b, Bx);
  hipLaunchKernelGGL(k_dcnoff, dim3(1024), dim3(512), 0, stream, Bx, dw_w, dw_b,
                     dw_ln_g, dw_ln_b, off_w, off_b, x_proj_w, dt_w, A, Dd, Bsb, Csb);
  hipLaunchKernelGGL(k_scan, dim3(512), dim3(1024), 0, stream, A, Dd, Bsb, Csb, A_logs, Ds, dt_b);
  hipLaunchKernelGGL(k_outproj, dim3(1024), dim3(256), 0, stream, A, out_proj_w, out_ln_g, s12, out);
}

// Round 7
// 209.362 us; speedup vs baseline: 1.1215x; 1.0006x over previous
//
#include <hip/hip_runtime.h>
#include <hip/hip_bf16.h>

typedef unsigned short u16;
typedef unsigned int u32;
typedef __bf16 bf16x8 __attribute__((ext_vector_type(8)));
typedef float f32x4 __attribute__((ext_vector_type(4)));

__device__ __forceinline__ float bfu(u16 u) { return __uint_as_float(((u32)u) << 16); }
__device__ __forceinline__ u16 fbf(float f) {
  __hip_bfloat16 h = __float2bfloat16(f);
  return *reinterpret_cast<u16*>(&h);
}
__device__ __forceinline__ float softplusf(float z) {
  float t = __expf(z);
  return (z > 20.f) ? z : __logf(1.f + t);
}
__device__ __forceinline__ float lo16(u32 p) { return __uint_as_float(p << 16); }
__device__ __forceinline__ float hi16(u32 p) { return __uint_as_float(p & 0xffff0000u); }
__device__ __forceinline__ bf16x8 ld_bf8(const u16* p) {
  union { uint4 u; bf16x8 v; } c;
  c.u = *(const uint4*)p;
  return c.v;
}

// xc layout is GROUP-BLOCKED channels-last: [b][g][y][x][c16] (u16 units:
// base + ((b*8+g)<<18) + ((y*128+x)<<4) + c).

// ---- K1: in_proj MFMA GEMM + (block 1024) k_sums fold ----------------------
__global__ __launch_bounds__(256) void k_inproj(const float* __restrict__ X,
                                                const float* __restrict__ W,
                                                u16* __restrict__ out,
                                                const float* __restrict__ W2,
                                                const float* __restrict__ gO,
                                                const float* __restrict__ bO,
                                                float* __restrict__ s12) {
  __shared__ __align__(16) u16 Ws[128 * 136];  // [o][c] bf16
  __shared__ __align__(16) u16 Xs[64 * 136];   // [l][c] bf16 (X^T tile)
  int tid = threadIdx.x;
  if (blockIdx.x == 1024) {  // folded k_sums
    if (tid < 128) {
      int o = tid;
      float s1 = 0.f, s2 = 0.f;
      for (int c = 0; c < 128; ++c) {
        float w = W2[(o << 7) + c];
        s1 = fmaf(w, bO[c], s1);
        s2 = fmaf(w, gO[c], s2);
      }
      s12[o] = s1;
      s12[128 + o] = s2;
    }
    return;
  }
  int b = blockIdx.x >> 8;
  int l0 = (blockIdx.x & 255) << 6;
  for (int i = 0; i < 16; ++i) {
    int idx = (i << 8) + tid;
    int o = idx >> 5, c4 = (idx & 31) << 2;
    float4 w4 = *(const float4*)&W[(o << 7) + c4];
    ushort4 s;
    s.x = fbf(w4.x); s.y = fbf(w4.y); s.z = fbf(w4.z); s.w = fbf(w4.w);
    *(ushort4*)&Ws[o * 136 + c4] = s;
  }
  for (int i = 0; i < 8; ++i) {
    int idx = (i << 8) + tid;
    int c = idx >> 4, lq = (idx & 15) << 2;
    float4 x4 = *(const float4*)&X[(((long)(b << 7) + c) << 14) + l0 + lq];
    Xs[(lq + 0) * 136 + c] = fbf(x4.x);
    Xs[(lq + 1) * 136 + c] = fbf(x4.y);
    Xs[(lq + 2) * 136 + c] = fbf(x4.z);
    Xs[(lq + 3) * 136 + c] = fbf(x4.w);
  }
  __syncthreads();
  int w = tid >> 6, lane = tid & 63;
  int mrow = lane & 15, quad = lane >> 4;
  f32x4 acc[2][4];
#pragma unroll
  for (int ot = 0; ot < 2; ++ot)
#pragma unroll
    for (int lt = 0; lt < 4; ++lt) acc[ot][lt] = (f32x4){0.f, 0.f, 0.f, 0.f};
#pragma unroll
  for (int kb = 0; kb < 4; ++kb) {
    int c0 = (kb << 5) + (quad << 3);
    bf16x8 af[2], bfr[4];
#pragma unroll
    for (int ot = 0; ot < 2; ++ot)
      af[ot] = ld_bf8(&Ws[((w << 5) + (ot << 4) + mrow) * 136 + c0]);
#pragma unroll
    for (int lt = 0; lt < 4; ++lt)
      bfr[lt] = ld_bf8(&Xs[((lt << 4) + mrow) * 136 + c0]);
#pragma unroll
    for (int ot = 0; ot < 2; ++ot)
#pragma unroll
      for (int lt = 0; lt < 4; ++lt)
        acc[ot][lt] = __builtin_amdgcn_mfma_f32_16x16x32_bf16(af[ot], bfr[lt], acc[ot][lt], 0, 0, 0);
  }
#pragma unroll
  for (int ot = 0; ot < 2; ++ot)
#pragma unroll
    for (int lt = 0; lt < 4; ++lt) {
      int l = l0 + (lt << 4) + mrow;
      int o = (w << 5) + (ot << 4) + (quad << 2);
      ushort4 s;
      s.x = fbf(acc[ot][lt][0]); s.y = fbf(acc[ot][lt][1]);
      s.z = fbf(acc[ot][lt][2]); s.w = fbf(acc[ot][lt][3]);
      *(ushort4*)&out[(((long)(b << 14) + l) << 7) + o] = s;
    }
}

// ---- K2: depthwise 3x3 conv + SiLU; in [l][c128], out group-blocked --------
__global__ __launch_bounds__(256) void k_dwconv(const u16* __restrict__ in,
                                                const float* __restrict__ w9,
                                                const float* __restrict__ bias,
                                                u16* __restrict__ out) {
  __shared__ float wsT[9][128];
  __shared__ float bs[128];
  int tid = threadIdx.x;
  for (int i = 0; i < 5; ++i) {
    int lin = (i << 8) + tid;
    if (lin < 1152) { int c = lin / 9, k = lin - 9 * c; wsT[k][c] = w9[lin]; }
  }
  if (tid < 128) bs[tid] = bias[tid];
  __syncthreads();
  int blk = blockIdx.x;
  int b = blk >> 10;
  int s = blk & 1023;
  int h = s >> 3;
  int w = ((s & 7) << 4) + (tid >> 4);
  int c0 = (tid & 15) << 3;
  const u16* bbase = in + ((long)b << 21);
  float acc[8];
  {
    float4 b0 = *(const float4*)&bs[c0];
    float4 b1 = *(const float4*)&bs[c0 + 4];
    acc[0] = b0.x; acc[1] = b0.y; acc[2] = b0.z; acc[3] = b0.w;
    acc[4] = b1.x; acc[5] = b1.y; acc[6] = b1.z; acc[7] = b1.w;
  }
#pragma unroll
  for (int ky = -1; ky <= 1; ++ky) {
    int y = h + ky;
    if ((unsigned)y >= 128u) continue;
#pragma unroll
    for (int kx = -1; kx <= 1; ++kx) {
      int x = w + kx;
      if ((unsigned)x >= 128u) continue;
      int k = (ky + 1) * 3 + (kx + 1);
      uint4 v = *(const uint4*)(bbase + ((((y << 7) + x)) << 7) + c0);
      float4 w0 = *(const float4*)&wsT[k][c0];
      float4 w1 = *(const float4*)&wsT[k][c0 + 4];
      u32 vv[4] = {v.x, v.y, v.z, v.w};
      float wf[8] = {w0.x, w0.y, w0.z, w0.w, w1.x, w1.y, w1.z, w1.w};
#pragma unroll
      for (int cc = 0; cc < 8; ++cc) {
        float xv = (cc & 1) ? hi16(vv[cc >> 1]) : lo16(vv[cc >> 1]);
        acc[cc] = fmaf(wf[cc], xv, acc[cc]);
      }
    }
  }
#pragma unroll
  for (int cc = 0; cc < 8; ++cc) acc[cc] = acc[cc] / (1.f + __expf(-acc[cc]));
  int g4 = c0 >> 4, sub = c0 & 15;
  uint4 pkst;
  pkst.x = (u32)fbf(acc[0]) | ((u32)fbf(acc[1]) << 16);
  pkst.y = (u32)fbf(acc[2]) | ((u32)fbf(acc[3]) << 16);
  pkst.z = (u32)fbf(acc[4]) | ((u32)fbf(acc[5]) << 16);
  pkst.w = (u32)fbf(acc[6]) | ((u32)fbf(acc[7]) << 16);
  u16* po = out + (((long)(b << 3) + g4) << 18) + ((((h << 7) + w)) << 4) + sub;
  *(uint4*)po = pkst;
}

// ---- K3: FUSED dwconv#2 + LN + GELU + offset MFMA + DCN gather + x_proj ----
// v7: conflict-free LDS weight layouts for Phase A.  In v6 the per-tap read
// wsT2[((g2*16)+cc)*9+k] had per-lane stride 144 floats (144%32==16 -> the 8
// g2 values map to 2 banks, 4-way conflict on ~144 reads/thread ==
// SQ_LDS_BANK_CONFLICT 1.0e7, ~16us/47us).  New layout wpad[g2*148+k*16+cc]:
// bank base 20*g2%32 = {0,20,8,28,16,4,24,12} all distinct -> each g2's
// float4 read owns its own 4-bank span.  Same trick (stride 20) for
// bias/gamma/beta.  Reads vectorized to float4 (36 b128 instead of 144 b32).
__global__ __launch_bounds__(512, 6) void k_dcnoff(const u16* __restrict__ xc,
                                                   const float* __restrict__ w9,
                                                   const float* __restrict__ bias,
                                                   const float* __restrict__ g,
                                                   const float* __restrict__ bt,
                                                   const float* __restrict__ offw,
                                                   const float* __restrict__ offb,
                                                   const float* __restrict__ xpw,
                                                   const float* __restrict__ dtw,
                                                   u16* __restrict__ xs,
                                                   u16* __restrict__ dts,
                                                   float* __restrict__ Bsb,
                                                   float* __restrict__ Csb) {
  // overlay region: [0,17408) Ge (64x136 bf16); [17408,22144) wpad
  // (8*148 f32); [22144,26496) Wos (16x136 bf16).  'part' (64*81 f32 =
  // 20736B) overlays Ge + head of wpad AFTER both are dead.
  __shared__ __align__(16) char uni[26496];
  __shared__ __align__(16) float bsp[160], gsp[160], bshp[160];  // [g2*20+cc]
  __shared__ __align__(16) u16 xds_bf[64 * 132];  // [p][c] bf16
  __shared__ __align__(16) float xdblT[8 * 64];   // [r][p]
  __shared__ __align__(16) float2 offsL[64 * 8];  // [p][g]
  u16* Ge = (u16*)uni;
  float* wpad = (float*)(uni + 17408);
  u16* Wos = (u16*)(uni + 22144);
  float* part = (float*)uni;
  int tid = threadIdx.x;
  // stage weights into conflict-free layouts
  for (int i = 0; i < 3; ++i) {
    int lin = (i << 9) + tid;
    if (lin < 1152) {
      int c = lin / 9, k = lin - 9 * c;
      wpad[(c >> 4) * 148 + k * 16 + (c & 15)] = w9[lin];
    }
  }
  if (tid < 128) {
    int g2s = tid >> 4, ccs = tid & 15;
    bsp[g2s * 20 + ccs] = bias[tid];
    gsp[g2s * 20 + ccs] = g[tid];
    bshp[g2s * 20 + ccs] = bt[tid];
  }
  for (int i = 0; i < 4; ++i) {
    int idx = (i << 9) + tid;  // 2048 = 16o x 128c
    int o = idx >> 7, c = idx & 127;
    Wos[o * 136 + c] = fbf(offw[idx]);
  }
  int blk = blockIdx.x;
  int b = blk >> 8;
  int l0 = (blk & 255) << 6;
  __syncthreads();
  // ---- Phase A: dwconv2 + LN + GELU ----
  {
    int p2 = tid >> 3, g2 = tid & 7;
    int l = l0 + p2, hh = l >> 7, ww = l & 127;
    const u16* bb2 = xc + (((long)(b << 3) + g2) << 18);
    float acc[16];
    {
      const float* bp = &bsp[g2 * 20];
      float4 b0 = *(const float4*)bp;
      float4 b1 = *(const float4*)(bp + 4);
      float4 b2 = *(const float4*)(bp + 8);
      float4 b3 = *(const float4*)(bp + 12);
      acc[0] = b0.x;  acc[1] = b0.y;  acc[2] = b0.z;  acc[3] = b0.w;
      acc[4] = b1.x;  acc[5] = b1.y;  acc[6] = b1.z;  acc[7] = b1.w;
      acc[8] = b2.x;  acc[9] = b2.y;  acc[10] = b2.z; acc[11] = b2.w;
      acc[12] = b3.x; acc[13] = b3.y; acc[14] = b3.z; acc[15] = b3.w;
    }
#pragma unroll
    for (int ky = -1; ky <= 1; ++ky) {
      int y = hh + ky;
      if ((unsigned)y >= 128u) continue;
#pragma unroll
      for (int kx = -1; kx <= 1; ++kx) {
        int x = ww + kx;
        if ((unsigned)x >= 128u) continue;
        int k = (ky + 1) * 3 + (kx + 1);
        const u16* tp = bb2 + ((((y << 7) + x)) << 4);
        uint4 v0 = *(const uint4*)tp;
        uint4 v1 = *(const uint4*)(tp + 8);
        u32 vv[8] = {v0.x, v0.y, v0.z, v0.w, v1.x, v1.y, v1.z, v1.w};
        const float* wp = &wpad[g2 * 148 + k * 16];
        float4 w0 = *(const float4*)wp;
        float4 w1 = *(const float4*)(wp + 4);
        float4 w2 = *(const float4*)(wp + 8);
        float4 w3 = *(const float4*)(wp + 12);
        float wf[16] = {w0.x, w0.y, w0.z, w0.w, w1.x, w1.y, w1.z, w1.w,
                        w2.x, w2.y, w2.z, w2.w, w3.x, w3.y, w3.z, w3.w};
#pragma unroll
        for (int cc = 0; cc < 16; ++cc) {
          float xv = (cc & 1) ? hi16(vv[cc >> 1]) : lo16(vv[cc >> 1]);
          acc[cc] = fmaf(wf[cc], xv, acc[cc]);
        }
      }
    }
    // LN stats: partial over 16 ch, reduce across the 8 lanes sharing pixel
    float sum = 0.f, ssum = 0.f;
#pragma unroll
    for (int cc = 0; cc < 16; ++cc) { sum += acc[cc]; ssum = fmaf(acc[cc], acc[cc], ssum); }
#pragma unroll
    for (int off = 1; off < 8; off <<= 1) {
      sum += __shfl_xor(sum, off);
      ssum += __shfl_xor(ssum, off);
    }
    float m = sum * (1.f / 128.f);
    float r = rsqrtf(ssum * (1.f / 128.f) - m * m + 1e-6f);
    // LN + GELU -> bf16 -> Ge[p2][g2*16..+15]
    float gf[16], bf_[16];
    {
      const float* gp = &gsp[g2 * 20];
      const float* bp = &bshp[g2 * 20];
#pragma unroll
      for (int q = 0; q < 4; ++q) {
        float4 gq = *(const float4*)(gp + (q << 2));
        float4 bq = *(const float4*)(bp + (q << 2));
        gf[(q << 2) + 0] = gq.x; gf[(q << 2) + 1] = gq.y;
        gf[(q << 2) + 2] = gq.z; gf[(q << 2) + 3] = gq.w;
        bf_[(q << 2) + 0] = bq.x; bf_[(q << 2) + 1] = bq.y;
        bf_[(q << 2) + 2] = bq.z; bf_[(q << 2) + 3] = bq.w;
      }
    }
    u32 pk[8];
#pragma unroll
    for (int jj = 0; jj < 8; ++jj) {
      u16 h2[2];
#pragma unroll
      for (int e = 0; e < 2; ++e) {
        int cc = 2 * jj + e;
        float xn = fmaf((acc[cc] - m) * r, gf[cc], bf_[cc]);
        h2[e] = fbf(0.5f * xn * (1.f + erff(xn * 0.70710678118f)));
      }
      pk[jj] = (u32)h2[0] | ((u32)h2[1] << 16);
    }
    u16* row = &Ge[p2 * 136 + (g2 << 4)];
    *(uint4*)row = make_uint4(pk[0], pk[1], pk[2], pk[3]);
    *(uint4*)(row + 8) = make_uint4(pk[4], pk[5], pk[6], pk[7]);
  }
  __syncthreads();
  // ---- Phase B: offset projection (waves 0-3, 16 pixels each) ----
  {
    int w = tid >> 6, lane = tid & 63;
    if (w < 4) {
      int mrow = lane & 15, quad = lane >> 4;
      f32x4 acc0 = (f32x4){0.f, 0.f, 0.f, 0.f};
#pragma unroll
      for (int kb = 0; kb < 4; ++kb) {
        int cb = (kb << 5) + (quad << 3);
        bf16x8 af = ld_bf8(&Wos[mrow * 136 + cb]);
        bf16x8 bfr = ld_bf8(&Ge[((w << 4) + mrow) * 136 + cb]);
        acc0 = __builtin_amdgcn_mfma_f32_16x16x32_bf16(af, bfr, acc0, 0, 0, 0);
      }
      // D: col(lane&15)=pixel, row(quad*4+reg)=o; groups g0=2q (x,y), g1=2q+1
      int p = (w << 4) + mrow;
      int o0 = quad << 2;
      offsL[(p << 3) + (quad << 1)] = make_float2(acc0[0] + offb[o0], acc0[1] + offb[o0 + 1]);
      offsL[(p << 3) + (quad << 1) + 1] = make_float2(acc0[2] + offb[o0 + 2], acc0[3] + offb[o0 + 3]);
    }
  }
  __syncthreads();
  // ---- Phase C: DCN gather + x_proj + stores (v5 structure) ----
  int p = tid & 63, gg = tid >> 6;
  int l = l0 + p, hh = l >> 7, ww = l & 127;
  float2 off = offsL[(p << 3) + gg];
  float px = (float)ww + off.x, py = (float)hh + off.y;
  float x0f = floorf(px), y0f = floorf(py);
  float wx = px - x0f, wy = py - y0f;
  int ix = (int)x0f, iy = (int)y0f;
  int x0c = min(max(ix, 0), 127), x1c = min(max(ix + 1, 0), 127);
  int y0c = min(max(iy, 0), 127), y1c = min(max(iy + 1, 0), 127);
  float vx0 = ((unsigned)ix < 128u) ? 1.f : 0.f;
  float vx1 = ((unsigned)(ix + 1) < 128u) ? 1.f : 0.f;
  float vy0 = ((unsigned)iy < 128u) ? 1.f : 0.f;
  float vy1 = ((unsigned)(iy + 1) < 128u) ? 1.f : 0.f;
  float wt4[4] = {(1.f - wy) * (1.f - wx) * vy0 * vx0,
                  (1.f - wy) * wx * vy0 * vx1,
                  wy * (1.f - wx) * vy1 * vx0,
                  wy * wx * vy1 * vx1};
  const u16* bbase = xc + (((long)(b << 3) + gg) << 18);
  const u16* r0p = bbase + ((((y0c << 7) + x0c)) << 4);
  const u16* r1p = bbase + ((((y1c << 7) + x0c)) << 4);
  uint4 q0 = ((const uint4*)r0p)[0];
  uint4 q1 = ((const uint4*)r0p)[1];
  uint4 q2 = ((const uint4*)r0p)[2];
  uint4 q3 = ((const uint4*)r0p)[3];
  uint4 q4 = ((const uint4*)r1p)[0];
  uint4 q5 = ((const uint4*)r1p)[1];
  uint4 q6 = ((const uint4*)r1p)[2];
  uint4 q7 = ((const uint4*)r1p)[3];
  bool adj = (x1c != x0c);
  u32 t0[8] = {q0.x, q0.y, q0.z, q0.w, q1.x, q1.y, q1.z, q1.w};
  u32 t1[8] = {adj ? q2.x : q0.x, adj ? q2.y : q0.y, adj ? q2.z : q0.z, adj ? q2.w : q0.w,
               adj ? q3.x : q1.x, adj ? q3.y : q1.y, adj ? q3.z : q1.z, adj ? q3.w : q1.w};
  u32 t2[8] = {q4.x, q4.y, q4.z, q4.w, q5.x, q5.y, q5.z, q5.w};
  u32 t3[8] = {adj ? q6.x : q4.x, adj ? q6.y : q4.y, adj ? q6.z : q4.z, adj ? q6.w : q4.w,
               adj ? q7.x : q5.x, adj ? q7.y : q5.y, adj ? q7.z : q5.z, adj ? q7.w : q5.w};
  float acc[16];
#pragma unroll
  for (int ch = 0; ch < 16; ++ch) {
    float v0 = (ch & 1) ? hi16(t0[ch >> 1]) : lo16(t0[ch >> 1]);
    float v1 = (ch & 1) ? hi16(t1[ch >> 1]) : lo16(t1[ch >> 1]);
    float v2 = (ch & 1) ? hi16(t2[ch >> 1]) : lo16(t2[ch >> 1]);
    float v3 = (ch & 1) ? hi16(t3[ch >> 1]) : lo16(t3[ch >> 1]);
    float a = fmaf(wt4[0], v0, wt4[1] * v1);
    a = fmaf(wt4[2], v2, a);
    acc[ch] = fmaf(wt4[3], v3, a);
  }
  {
    u32 pk[8];
#pragma unroll
    for (int j = 0; j < 8; ++j)
      pk[j] = (u32)fbf(acc[2 * j]) | ((u32)fbf(acc[2 * j + 1]) << 16);
    u16* row = &xds_bf[p * 132 + (gg << 4)];
#pragma unroll
    for (int q = 0; q < 4; ++q)
      *(uint2*)(row + (q << 2)) = make_uint2(pk[2 * q], pk[2 * q + 1]);
  }
  // x_proj partials (part overlays Ge/wpad head -- both dead since Phase B)
  {
    int ggu = __builtin_amdgcn_readfirstlane(gg);
    const float* wb = xpw + (ggu << 4);
    int pbase = p * 81 + gg;
#pragma unroll
    for (int r = 0; r < 10; ++r) {
      const float* wr = wb + (r << 7);
      float s = 0.f;
#pragma unroll
      for (int ch = 0; ch < 16; ++ch) s = fmaf(wr[ch], acc[ch], s);
      part[pbase + (r << 3)] = s;
    }
  }
  __syncthreads();
  {
    int task = tid;
#pragma unroll
    for (int pass = 0; pass < 2; ++pass, task += 512) {
      if (task < 640) {
        int r = task >> 6, p2 = task & 63;
        const float* pp = &part[p2 * 81 + (r << 3)];
        float s = ((pp[0] + pp[1]) + (pp[2] + pp[3])) + ((pp[4] + pp[5]) + (pp[6] + pp[7]));
        if (r < 8) xdblT[(r << 6) + p2] = s;
        else if (r == 8) Bsb[((long)b << 14) + l0 + p2] = s;
        else Csb[((long)b << 14) + l0 + p2] = s;
      }
    }
  }
#pragma unroll
  for (int it = 0; it < 2; ++it) {
    int task = (it << 9) + tid;
    int cc = task >> 3, t = task & 7;
    u32 pk[4];
#pragma unroll
    for (int jj = 0; jj < 4; ++jj) {
      u16 a0 = xds_bf[((t << 3) + 2 * jj + 0) * 132 + cc];
      u16 a1 = xds_bf[((t << 3) + 2 * jj + 1) * 132 + cc];
      pk[jj] = (u32)a0 | ((u32)a1 << 16);
    }
    *(uint4*)&xs[(((long)(b << 7) + cc) << 14) + l0 + (t << 3)] =
        make_uint4(pk[0], pk[1], pk[2], pk[3]);
  }
  __syncthreads();  // xdblT visible
  {
    int dd = tid >> 3, t = tid & 7;
    float4 a0 = *(const float4*)&dtw[dd << 3];
    float4 a1 = *(const float4*)&dtw[(dd << 3) + 4];
    float4 b0 = *(const float4*)&dtw[(dd + 64) << 3];
    float4 b1 = *(const float4*)&dtw[((dd + 64) << 3) + 4];
    float wr0[8] = {a0.x, a0.y, a0.z, a0.w, a1.x, a1.y, a1.z, a1.w};
    float wr1[8] = {b0.x, b0.y, b0.z, b0.w, b1.x, b1.y, b1.z, b1.w};
    float y0[8], y1[8];
#pragma unroll
    for (int j = 0; j < 8; ++j) { y0[j] = 0.f; y1[j] = 0.f; }
#pragma unroll
    for (int rr = 0; rr < 8; ++rr) {
      float w0 = wr0[rr], w1 = wr1[rr];
      const float* xr = &xdblT[(rr << 6) + (t << 3)];
      float4 xa = *(const float4*)xr;
      float4 xb = *(const float4*)(xr + 4);
      float xv[8] = {xa.x, xa.y, xa.z, xa.w, xb.x, xb.y, xb.z, xb.w};
#pragma unroll
      for (int j = 0; j < 8; ++j) {
        y0[j] = fmaf(w0, xv[j], y0[j]);
        y1[j] = fmaf(w1, xv[j], y1[j]);
      }
    }
    u32 pk0[4], pk1[4];
#pragma unroll
    for (int jj = 0; jj < 4; ++jj) {
      pk0[jj] = (u32)fbf(y0[2 * jj]) | ((u32)fbf(y0[2 * jj + 1]) << 16);
      pk1[jj] = (u32)fbf(y1[2 * jj]) | ((u32)fbf(y1[2 * jj + 1]) << 16);
    }
    *(uint4*)&dts[(((long)(b << 7) + dd) << 14) + l0 + (t << 3)] =
        make_uint4(pk0[0], pk0[1], pk0[2], pk0[3]);
    *(uint4*)&dts[(((long)(b << 7) + dd + 64) << 14) + l0 + (t << 3)] =
        make_uint4(pk1[0], pk1[1], pk1[2], pk1[3]);
  }
}

// ---- K5: selective scan, shfl-based block scan, cheap softplus -------------
__global__ __launch_bounds__(1024) void k_scan(u16* __restrict__ xy,
                                               const u16* __restrict__ dts16,
                                               const float* __restrict__ Bsb,
                                               const float* __restrict__ Csb,
                                               const float* __restrict__ A_logs,
                                               const float* __restrict__ Dsv,
                                               const float* __restrict__ dtbv) {
  __shared__ float swp[16], swe[16];
  int bd = blockIdx.x;
  int b = bd >> 7, d = bd & 127;
  float Ad = -__expf(A_logs[d]);
  float dtb = dtbv[d];
  float Dd = Dsv[d];
  int t = threadIdx.x;
  int lane = t & 63, wid = t >> 6;
  long base = ((long)bd << 14) + (t << 4);
  long bb = ((long)b << 14) + (t << 4);
  const uint4* pz4 = (const uint4*)(dts16 + base);
  const uint4* px4 = (const uint4*)(xy + base);
  const float4* pB = (const float4*)(Bsb + bb);
  const float4* pC = (const float4*)(Csb + bb);
  uint4 zA = pz4[0], zB = pz4[1];
  uint4 xA = px4[0], xB = px4[1];
  u32 zw[8] = {zA.x, zA.y, zA.z, zA.w, zB.x, zB.y, zB.z, zB.w};
  u32 xw[8] = {xA.x, xA.y, xA.z, xA.w, xB.x, xB.y, xB.z, xB.w};
  float E = 0.f, P = 1.f;
#pragma unroll
  for (int q = 0; q < 4; ++q) {
    float4 B4 = pB[q];
    float Bq[4] = {B4.x, B4.y, B4.z, B4.w};
#pragma unroll
    for (int j = 0; j < 4; ++j) {
      int k = (q << 2) + j;
      float z = (k & 1) ? hi16(zw[k >> 1]) : lo16(zw[k >> 1]);
      float xv = (k & 1) ? hi16(xw[k >> 1]) : lo16(xw[k >> 1]);
      float delta = softplusf(z + dtb);
      float a = __expf(delta * Ad);
      E = fmaf(a, E, delta * Bq[j] * xv);
      P *= a;
    }
  }
#pragma unroll
  for (int off = 1; off < 64; off <<= 1) {
    float Pp = __shfl_up(P, off);
    float Ep = __shfl_up(E, off);
    if (lane >= off) { E = fmaf(P, Ep, E); P *= Pp; }
  }
  if (lane == 63) { swp[wid] = P; swe[wid] = E; }
  __syncthreads();
  if (t < 16) {
    float p2 = swp[t], e2 = swe[t];
#pragma unroll
    for (int off = 1; off < 16; off <<= 1) {
      float pp = __shfl_up(p2, off);
      float ee = __shfl_up(e2, off);
      if (t >= off) { e2 = fmaf(p2, ee, e2); p2 *= pp; }
    }
    swp[t] = p2; swe[t] = e2;
  }
  __syncthreads();
  float hw = (wid == 0) ? 0.f : swe[wid - 1];
  float Pex = __shfl_up(P, 1);
  float Eex = __shfl_up(E, 1);
  if (lane == 0) { Pex = 1.f; Eex = 0.f; }
  float h = fmaf(Pex, hw, Eex);
  u32 ypk[8];
#pragma unroll
  for (int q = 0; q < 4; ++q) {
    float4 B4 = pB[q];
    float4 C4 = pC[q];
    float Bq[4] = {B4.x, B4.y, B4.z, B4.w};
    float Cq[4] = {C4.x, C4.y, C4.z, C4.w};
#pragma unroll
    for (int j = 0; j < 4; ++j) {
      int k = (q << 2) + j;
      float z = (k & 1) ? hi16(zw[k >> 1]) : lo16(zw[k >> 1]);
      float xv = (k & 1) ? hi16(xw[k >> 1]) : lo16(xw[k >> 1]);
      float delta = softplusf(z + dtb);
      float a = __expf(delta * Ad);
      h = fmaf(a, h, delta * Bq[j] * xv);
      u16 yb = fbf(fmaf(Dd, xv, h * Cq[j]));
      if ((k & 1) == 0) ypk[k >> 1] = yb; else ypk[k >> 1] |= (u32)yb << 16;
    }
  }
  uint4* py = (uint4*)(xy + base);
  py[0] = make_uint4(ypk[0], ypk[1], ypk[2], ypk[3]);
  py[1] = make_uint4(ypk[4], ypk[5], ypk[6], ypk[7]);
}

// ---- K7: out_proj MFMA GEMM + fused LN epilogue (f32 out, [b,o,l]) ---------
__global__ __launch_bounds__(256) void k_outproj(const u16* __restrict__ y,
                                                 const float* __restrict__ W2,
                                                 const float* __restrict__ g,
                                                 const float* __restrict__ s12,
                                                 float* __restrict__ out) {
  __shared__ __align__(16) u16 Ws[128 * 136];  // [o][c] bf16 of W2*gamma
  __shared__ __align__(16) u16 Ys[64 * 136];   // [l][c] bf16 (y^T tile)
  __shared__ float ps[4][64], pss[4][64];
  __shared__ float mean_s[64], rstd_s[64];
  int tid = threadIdx.x;
  int b = blockIdx.x >> 8;
  int l0 = (blockIdx.x & 255) << 6;
  for (int i = 0; i < 16; ++i) {
    int idx = (i << 8) + tid;
    int o = idx >> 5, c4 = (idx & 31) << 2;
    float4 w4 = *(const float4*)&W2[(o << 7) + c4];
    ushort4 s;
    s.x = fbf(w4.x * g[c4]);     s.y = fbf(w4.y * g[c4 + 1]);
    s.z = fbf(w4.z * g[c4 + 2]); s.w = fbf(w4.w * g[c4 + 3]);
    *(ushort4*)&Ws[o * 136 + c4] = s;
  }
  for (int i = 0; i < 4; ++i) {
    int idx = (i << 8) + tid;
    int c = idx >> 3, lq = (idx & 7) << 3;
    uint4 v = *(const uint4*)&y[(((long)(b << 7) + c) << 14) + l0 + lq];
    u32 vv[4] = {v.x, v.y, v.z, v.w};
#pragma unroll
    for (int r = 0; r < 8; ++r)
      Ys[(lq + r) * 136 + c] = (u16)((r & 1) ? (vv[r >> 1] >> 16) : (vv[r >> 1] & 0xffffu));
  }
  __syncthreads();
  {
    int l = tid & 63, q = tid >> 6;
    const u16* row = &Ys[l * 136 + (q << 5)];
    float s = 0.f, ss = 0.f;
#pragma unroll 8
    for (int c = 0; c < 32; ++c) { float v = bfu(row[c]); s += v; ss = fmaf(v, v, ss); }
    ps[q][l] = s; pss[q][l] = ss;
  }
  __syncthreads();
  if (tid < 64) {
    float s = ps[0][tid] + ps[1][tid] + ps[2][tid] + ps[3][tid];
    float ss = pss[0][tid] + pss[1][tid] + pss[2][tid] + pss[3][tid];
    float m = s * (1.f / 128.f);
    mean_s[tid] = m;
    rstd_s[tid] = rsqrtf(ss * (1.f / 128.f) - m * m + 1e-6f);
  }
  __syncthreads();
  int w = tid >> 6, lane = tid & 63;
  int mrow = lane & 15, quad = lane >> 4;
  f32x4 acc[2][4];
#pragma unroll
  for (int ot = 0; ot < 2; ++ot)
#pragma unroll
    for (int lt = 0; lt < 4; ++lt) acc[ot][lt] = (f32x4){0.f, 0.f, 0.f, 0.f};
#pragma unroll
  for (int kb = 0; kb < 4; ++kb) {
    int c0 = (kb << 5) + (quad << 3);
    bf16x8 af[2], bfr[4];
#pragma unroll
    for (int ot = 0; ot < 2; ++ot)
      af[ot] = ld_bf8(&Ws[((w << 5) + (ot << 4) + mrow) * 136 + c0]);
#pragma unroll
    for (int lt = 0; lt < 4; ++lt)
      bfr[lt] = ld_bf8(&Ys[((lt << 4) + mrow) * 136 + c0]);
#pragma unroll
    for (int ot = 0; ot < 2; ++ot)
#pragma unroll
      for (int lt = 0; lt < 4; ++lt)
        acc[ot][lt] = __builtin_amdgcn_mfma_f32_16x16x32_bf16(af[ot], bfr[lt], acc[ot][lt], 0, 0, 0);
  }
  float s1r[2][4], s2r[2][4];
#pragma unroll
  for (int ot = 0; ot < 2; ++ot)
#pragma unroll
    for (int r = 0; r < 4; ++r) {
      int o = (w << 5) + (ot << 4) + (quad << 2) + r;
      s1r[ot][r] = s12[o];
      s2r[ot][r] = s12[128 + o];
    }
#pragma unroll
  for (int ot = 0; ot < 2; ++ot)
#pragma unroll
    for (int lt = 0; lt < 4; ++lt) {
      int lcol = (lt << 4) + mrow;
      float mv = mean_s[lcol], rv = rstd_s[lcol];
      int obase = (w << 5) + (ot << 4) + (quad << 2);
#pragma unroll
      for (int r = 0; r < 4; ++r) {
        float v = fmaf(rv, acc[ot][lt][r] - mv * s2r[ot][r], s1r[ot][r]);
        out[(((long)(b << 7) + obase + r) << 14) + l0 + lcol] = v;
      }
    }
}

extern "C" void kernel_launch(void* const* d_in, const int* in_sizes, int n_in,
                              void* d_out, int out_size, void* d_ws, size_t ws_size,
                              hipStream_t stream) {
  const float* x         = (const float*)d_in[0];
  const float* in_proj_w = (const float*)d_in[1];
  const float* conv2d_w  = (const float*)d_in[2];
  const float* conv2d_b  = (const float*)d_in[3];
  const float* dw_w      = (const float*)d_in[4];
  const float* dw_b      = (const float*)d_in[5];
  const float* dw_ln_g   = (const float*)d_in[6];
  const float* dw_ln_b   = (const float*)d_in[7];
  const float* off_w     = (const float*)d_in[8];
  const float* off_b     = (const float*)d_in[9];
  const float* x_proj_w  = (const float*)d_in[10];
  const float* dt_w      = (const float*)d_in[11];
  const float* dt_b      = (const float*)d_in[12];
  const float* A_logs    = (const float*)d_in[13];
  const float* Ds        = (const float*)d_in[14];
  const float* out_ln_g  = (const float*)d_in[15];
  const float* out_ln_b  = (const float*)d_in[16];
  const float* out_proj_w= (const float*)d_in[17];
  float* out = (float*)d_out;

  u16* A  = (u16*)d_ws;            // xin_cl -> xs[b,c,l] -> y[b,c,l]
  u16* Bx = A + 8388608;           // xc group-blocked [b][g][y][x][c16]
  u16* Dd = Bx + 8388608;          // dts[b,c,l]
  float* Bsb   = (float*)(Dd + 8388608);
  float* Csb   = Bsb + 65536;
  float* s12   = Csb + 65536;

  hipLaunchKernelGGL(k_inproj, dim3(1025), dim3(256), 0, stream, x, in_proj_w, A,
                     out_proj_w, out_ln_g, out_ln_b, s12);
  hipLaunchKernelGGL(k_dwconv, dim3(4096), dim3(256), 0, stream, A, conv2d_w, conv2d_b, Bx);
  hipLaunchKernelGGL(k_dcnoff, dim3(1024), dim3(512), 0, stream, Bx, dw_w, dw_b,
                     dw_ln_g, dw_ln_b, off_w, off_b, x_proj_w, dt_w, A, Dd, Bsb, Csb);
  hipLaunchKernelGGL(k_scan, dim3(512), dim3(1024), 0, stream, A, Dd, Bsb, Csb, A_logs, Ds, dt_b);
  hipLaunchKernelGGL(k_outproj, dim3(1024), dim3(256), 0, stream, A, out_proj_w, out_ln_g, s12, out);
}